// Round 2
// baseline (11760.695 us; speedup 1.0000x reference)
//
#include <hip/hip_runtime.h>
#include <hip/hip_bf16.h>
#include <math.h>

// Problem constants
#define TBINS 8
#define BATCH 4
#define CIN 3
#define HIMG 128
#define WIMG 128
#define PC 48        // 4*4*3
#define NVOX 8192    // 32*32*8
#define ID 435
#define LD 512
#define INNER 600
#define FFD 2048
#define NL 128
#define OC 64
#define DEPTH 5
#define HEADS 8
#define DH 75

// ---------------------------------------------------------------------------
__global__ __launch_bounds__(256) void mask_kernel(const float* __restrict__ input,
                                                   unsigned char* __restrict__ mask) {
    int idx = blockIdx.x * 256 + threadIdx.x;
    if (idx >= BATCH * NVOX) return;
    int b = idx >> 13, i = idx & (NVOX - 1);
    int tt = i & 7, wx = (i >> 3) & 31, hy = i >> 8;
    float mx = -3.4e38f;
    for (int ch = 0; ch < PC; ++ch) {
        int py = ch / 12, px = (ch / 3) & 3, cc = ch % 3;
        float v = input[((size_t)((tt * BATCH + b) * CIN + cc) << 14) +
                        (hy * 4 + py) * WIMG + (wx * 4 + px)];
        mx = fmaxf(mx, v);
    }
    mask[idx] = (fabsf(mx) > 0.3f) ? 1 : 0;
}

// stable kept-first compaction, one wave per batch
__global__ __launch_bounds__(64) void compact_kernel(const unsigned char* __restrict__ mask,
                                                     int* __restrict__ perm,
                                                     int* __restrict__ Kc) {
    int b = blockIdx.x, lane = threadIdx.x;
    int offs = 0;
    for (int c = 0; c < NVOX / 64; ++c) {
        int i = c * 64 + lane;
        int m = mask[(b << 13) + i];
        unsigned long long bal = __ballot(m != 0);
        int excl = __popcll(bal & ((1ull << lane) - 1ull));
        if (m) perm[(b << 13) + offs + excl] = i;
        offs += __popcll(bal);
    }
    if (lane == 0) Kc[b] = offs;
}

// build normalized data row for ONE batch into normed[r*ID]; zero for dropped slots
__global__ __launch_bounds__(256) void build_data(const float* __restrict__ input,
                                                  const int* __restrict__ perm,
                                                  const int* __restrict__ Kc,
                                                  float* __restrict__ normed, int b) {
    int r = blockIdx.x;
    int tid = threadIdx.x;
    float* out = normed + (size_t)r * ID;
    int Kb = Kc[b];
    if (r >= Kb) {
        for (int e = tid; e < ID; e += 256) out[e] = 0.f;
        return;
    }
    __shared__ float row[448];
    __shared__ float red[256];
    int i = perm[(b << 13) + r];
    int tt = i & 7, wx = (i >> 3) & 31, hy = i >> 8;
    float pos0 = 2.f * hy / 32.f - 1.f;
    float pos1 = 2.f * wx / 32.f - 1.f;
    float pos2 = 2.f * tt / 8.f - 1.f;
    for (int e = tid; e < ID; e += 256) {
        float v;
        if (e < PC) {
            int py = e / 12, px = (e / 3) & 3, cc = e % 3;
            v = input[((size_t)((tt * BATCH + b) * CIN + cc) << 14) +
                      (hy * 4 + py) * WIMG + (wx * 4 + px)];
        } else {
            int e2 = e - PC;
            int dim = e2 / 129, rem = e2 - dim * 129;
            float pp = (dim == 0) ? pos0 : (dim == 1 ? pos1 : pos2);
            if (rem < 64)       v = sinf(ldexpf(pp, -rem));
            else if (rem < 128) v = cosf(ldexpf(pp, -(rem - 64)));
            else                v = pp;
        }
        row[e] = v;
    }
    __syncthreads();
    float ss = 0.f;
    for (int e = tid; e < ID; e += 256) ss += row[e] * row[e];
    red[tid] = ss; __syncthreads();
    for (int s = 128; s > 0; s >>= 1) { if (tid < s) red[tid] += red[tid + s]; __syncthreads(); }
    float scale = 1.f / fmaxf(sqrtf(red[0]), 1e-5f);
    for (int e = tid; e < ID; e += 256) out[e] = row[e] * scale;
}

__global__ __launch_bounds__(256) void lat_init(const float* __restrict__ latents,
                                                const float* __restrict__ pos_emb,
                                                float* __restrict__ lat) {
    int idx = blockIdx.x * 256 + threadIdx.x;
    if (idx >= BATCH * NL * LD) return;
    int rem = idx & (NL * LD - 1);
    lat[idx] = latents[rem] + pos_emb[rem];
}

__global__ __launch_bounds__(256) void scale_norm_k(const float* __restrict__ x,
                                                    float* __restrict__ o,
                                                    const float* __restrict__ g, int gi,
                                                    int cols) {
    int rowi = blockIdx.x, tid = threadIdx.x;
    const float* xr = x + (size_t)rowi * cols;
    float* orow = o + (size_t)rowi * cols;
    __shared__ float red[256];
    float ss = 0.f;
    for (int c = tid; c < cols; c += 256) { float v = xr[c]; ss += v * v; }
    red[tid] = ss; __syncthreads();
    for (int s = 128; s > 0; s >>= 1) { if (tid < s) red[tid] += red[tid + s]; __syncthreads(); }
    float scale = g[gi] / fmaxf(sqrtf(red[0]), 1e-5f);
    for (int c = tid; c < cols; c += 256) orow[c] = xr[c] * scale;
}

__global__ __launch_bounds__(256) void fill_kernel(float* __restrict__ p, long long n, float v) {
    long long idx = (long long)blockIdx.x * 256 + threadIdx.x;
    if (idx < n) p[idx] = v;
}

__global__ __launch_bounds__(256) void addbias_kernel(float* __restrict__ d,
                                                      const float* __restrict__ bias,
                                                      long long total, int n) {
    long long idx = (long long)blockIdx.x * 256 + threadIdx.x;
    if (idx < total) d[idx] += bias[idx % n];
}

__global__ __launch_bounds__(256) void biasgelu_kernel(float* __restrict__ d,
                                                       const float* __restrict__ bias,
                                                       long long total, int n) {
    long long idx = (long long)blockIdx.x * 256 + threadIdx.x;
    if (idx < total) {
        float v = d[idx] + bias[idx % n];
        d[idx] = 0.5f * v * (1.f + erff(v * 0.70710678118654752f));
    }
}

// masked row softmax in-place; kidx>=0 selects Kc[kidx] as valid length
__global__ __launch_bounds__(256) void softmax_rows(float* __restrict__ S, int cols,
                                                    const int* __restrict__ Kc, int kidx) {
    int rowi = blockIdx.x, tid = threadIdx.x;
    float* p = S + (size_t)rowi * cols;
    int lim = (kidx >= 0) ? Kc[kidx] : cols;
    __shared__ float red[256];
    if (lim <= 0) { for (int j = tid; j < cols; j += 256) p[j] = 0.f; return; }
    float mx = -3.4e38f;
    for (int j = tid; j < lim; j += 256) mx = fmaxf(mx, p[j]);
    red[tid] = mx; __syncthreads();
    for (int s = 128; s > 0; s >>= 1) { if (tid < s) red[tid] = fmaxf(red[tid], red[tid + s]); __syncthreads(); }
    mx = red[0]; __syncthreads();
    float sum = 0.f;
    for (int j = tid; j < lim; j += 256) { float e = expf(p[j] - mx); p[j] = e; sum += e; }
    red[tid] = sum; __syncthreads();
    for (int s = 128; s > 0; s >>= 1) { if (tid < s) red[tid] += red[tid + s]; __syncthreads(); }
    float inv = 1.f / red[0];
    for (int j = tid; j < lim; j += 256) p[j] *= inv;
    for (int j = lim + tid; j < cols; j += 256) p[j] = 0.f;
}

// generic tiled fp32 GEMM. D = alpha * A@B (optionally atomicAdd).
// A: MxK row-major (lda). B row-major KxN (ldb) if opB==0, else B is NxK (B^T).
// batched over blockIdx.z = (zo*nh+zi)*splitK + kc with composite strides.
__global__ __launch_bounds__(256) void gemm_f32(
    const float* __restrict__ A, const float* __restrict__ B, float* __restrict__ D,
    const float* __restrict__ alphaPtr, int alphaIdx, float alphaConst,
    int M, int N, int K, int lda, int ldb, int ldd, int opB, int nh,
    long long sAo, long long sAi, long long sBo, long long sBi,
    long long sDo, long long sDi, int splitK, int atomic) {
    const int tid = threadIdx.x;
    int zb = blockIdx.z / splitK;
    int kc = blockIdx.z - zb * splitK;
    int zo = zb / nh, zi = zb - zo * nh;
    const float* Ab = A + (size_t)zo * sAo + (size_t)zi * sAi;
    const float* Bb = B + (size_t)zo * sBo + (size_t)zi * sBi;
    float* Db = D + (size_t)zo * sDo + (size_t)zi * sDi;
    int bm = blockIdx.x * 64, bn = blockIdx.y * 64;
    int kLen = (K + splitK - 1) / splitK;
    int k0 = kc * kLen, k1 = min(K, k0 + kLen);

    __shared__ float As[16][68];
    __shared__ float Bs[16][68];
    float acc[4][4] = {};
    int tm = (tid >> 4) << 2;
    int tn = (tid & 15) << 2;

    for (int kb = k0; kb < k1; kb += 16) {
        {
            int kk = tid & 15, mm = tid >> 4;
#pragma unroll
            for (int p = 0; p < 4; ++p) {
                int m = mm + p * 16;
                int gm = bm + m, gk = kb + kk;
                As[kk][m] = (gm < M && gk < k1) ? Ab[(size_t)gm * lda + gk] : 0.f;
            }
        }
        if (opB == 0) {
            int nn = tid & 63, kk4 = tid >> 6;
#pragma unroll
            for (int p = 0; p < 4; ++p) {
                int kk = kk4 + p * 4;
                int gk = kb + kk, gn = bn + nn;
                Bs[kk][nn] = (gk < k1 && gn < N) ? Bb[(size_t)gk * ldb + gn] : 0.f;
            }
        } else {
            int kk = tid & 15, nn0 = tid >> 4;
#pragma unroll
            for (int p = 0; p < 4; ++p) {
                int nn = nn0 + p * 16;
                int gk = kb + kk, gn = bn + nn;
                Bs[kk][nn] = (gk < k1 && gn < N) ? Bb[(size_t)gn * ldb + gk] : 0.f;
            }
        }
        __syncthreads();
#pragma unroll
        for (int kk = 0; kk < 16; ++kk) {
            float a0 = As[kk][tm], a1 = As[kk][tm + 1], a2 = As[kk][tm + 2], a3 = As[kk][tm + 3];
            float b0 = Bs[kk][tn], b1 = Bs[kk][tn + 1], b2 = Bs[kk][tn + 2], b3 = Bs[kk][tn + 3];
            acc[0][0] += a0 * b0; acc[0][1] += a0 * b1; acc[0][2] += a0 * b2; acc[0][3] += a0 * b3;
            acc[1][0] += a1 * b0; acc[1][1] += a1 * b1; acc[1][2] += a1 * b2; acc[1][3] += a1 * b3;
            acc[2][0] += a2 * b0; acc[2][1] += a2 * b1; acc[2][2] += a2 * b2; acc[2][3] += a2 * b3;
            acc[3][0] += a3 * b0; acc[3][1] += a3 * b1; acc[3][2] += a3 * b2; acc[3][3] += a3 * b3;
        }
        __syncthreads();
    }
    float alpha = alphaConst * (alphaPtr ? alphaPtr[alphaIdx] : 1.f);
#pragma unroll
    for (int i = 0; i < 4; ++i) {
        int gm = bm + tm + i;
        if (gm >= M) continue;
#pragma unroll
        for (int j = 0; j < 4; ++j) {
            int gn = bn + tn + j;
            if (gn >= N) continue;
            float v = acc[i][j] * alpha;
            size_t di = (size_t)gm * ldd + gn;
            if (atomic) atomicAdd(&Db[di], v);
            else Db[di] = v;
        }
    }
}

// final permute: outtmp (b,128,64) -> d_out (t,b,n,64), latent = n*8 + t
__global__ __launch_bounds__(256) void reorder_kernel(const float* __restrict__ outtmp,
                                                      float* __restrict__ out) {
    int idx = blockIdx.x * 256 + threadIdx.x;
    if (idx >= TBINS * BATCH * (NL / TBINS) * OC) return;
    int oc = idx & 63, n = (idx >> 6) & 15, b = (idx >> 10) & 3, t = idx >> 12;
    out[idx] = outtmp[((size_t)(b * NL + n * TBINS + t)) * OC + oc];
}

// ---------------------------------------------------------------------------
static inline void launch_gemm(hipStream_t s, const float* A, const float* B, float* D,
                               const float* aPtr, int aIdx, float aConst,
                               int M, int N, int K, int lda, int ldb, int ldd,
                               int opB, int nbatch, int nh,
                               long long sAo, long long sAi, long long sBo, long long sBi,
                               long long sDo, long long sDi, int splitK, int atomic) {
    dim3 g((M + 63) / 64, (N + 63) / 64, nbatch * splitK);
    hipLaunchKernelGGL(gemm_f32, g, dim3(256), 0, s, A, B, D, aPtr, aIdx, aConst,
                       M, N, K, lda, ldb, ldd, opB, nh, sAo, sAi, sBo, sBi, sDo, sDi,
                       splitK, atomic);
}

extern "C" void kernel_launch(void* const* d_in, const int* in_sizes, int n_in,
                              void* d_out, int out_size, void* d_ws, size_t ws_size,
                              hipStream_t stream) {
    const float* input    = (const float*)d_in[0];
    const float* latents  = (const float*)d_in[1];
    const float* pos_emb  = (const float*)d_in[2];
    const float* ca_g     = (const float*)d_in[3];
    const float* ca_ctx_g = (const float*)d_in[4];
    const float* ca_q     = (const float*)d_in[5];
    const float* ca_kv    = (const float*)d_in[6];
    const float* ca_ow    = (const float*)d_in[7];
    const float* ca_ob    = (const float*)d_in[8];
    const float* cf_g     = (const float*)d_in[9];
    const float* cf_w1    = (const float*)d_in[10];
    const float* cf_b1    = (const float*)d_in[11];
    const float* cf_w2    = (const float*)d_in[12];
    const float* cf_b2    = (const float*)d_in[13];
    const float* la_g     = (const float*)d_in[14];
    const float* la_q     = (const float*)d_in[15];
    const float* la_kv    = (const float*)d_in[16];
    const float* la_ow    = (const float*)d_in[17];
    const float* la_ob    = (const float*)d_in[18];
    const float* lf_g     = (const float*)d_in[19];
    const float* lf_w1    = (const float*)d_in[20];
    const float* lf_b1    = (const float*)d_in[21];
    const float* lf_w2    = (const float*)d_in[22];
    const float* lf_b2    = (const float*)d_in[23];
    const float* logits_w = (const float*)d_in[24];
    const float* logits_b = (const float*)d_in[25];
    float* out = (float*)d_out;

    // compact workspace carve (~84 MB)
    char* w = (char*)d_ws;
    auto alloc = [&](size_t bytes) { void* p = (void*)w; w += (bytes + 255) & ~(size_t)255; return p; };
    int* perm            = (int*)alloc((size_t)BATCH * NVOX * 4);
    int* Kc              = (int*)alloc(64);
    unsigned char* mask  = (unsigned char*)alloc((size_t)BATCH * NVOX);
    float* lat           = (float*)alloc((size_t)BATCH * NL * LD * 4);
    float* latn          = (float*)alloc((size_t)BATCH * NL * LD * 4);
    float* q             = (float*)alloc((size_t)BATCH * NL * INNER * 4);
    float* attn          = (float*)alloc((size_t)BATCH * NL * INNER * 4);
    float* ffb           = (float*)alloc((size_t)BATCH * NL * FFD * 4);
    float* kvself        = (float*)alloc((size_t)BATCH * NL * 2 * INNER * 4);
    float* outtmp        = (float*)alloc((size_t)BATCH * NL * OC * 4);
    float* kv_b          = (float*)alloc((size_t)NVOX * 2 * INNER * 4);        // 39.3 MB
    // union: normed_b (NVOX*ID = 14.3 MB) then S_b (HEADS*NL*NVOX = 33.6 MB)
    float* SN            = (float*)alloc((size_t)HEADS * NL * NVOX * 4);        // 33.6 MB
    float* normed_b      = SN;
    (void)ws_size; (void)n_in; (void)in_sizes; (void)out_size;

    const float scaleS = 1.0f / sqrtf((float)DH);
    const int M4 = BATCH * NL;                       // 512
    const long long qStrideB = (long long)NL * INNER;

    hipLaunchKernelGGL(mask_kernel, dim3((BATCH * NVOX + 255) / 256), dim3(256), 0, stream, input, mask);
    hipLaunchKernelGGL(compact_kernel, dim3(BATCH), dim3(64), 0, stream, mask, perm, Kc);
    hipLaunchKernelGGL(lat_init, dim3((BATCH * NL * LD + 255) / 256), dim3(256), 0, stream, latents, pos_emb, lat);

    for (int d = 0; d < DEPTH; ++d) {
        // ---- cross attention ----
        hipLaunchKernelGGL(scale_norm_k, dim3(M4), dim3(256), 0, stream, lat, latn, ca_g, d, LD);
        hipLaunchKernelGGL(fill_kernel, dim3((M4 * INNER + 255) / 256), dim3(256), 0, stream, q, (long long)M4 * INNER, 0.f);
        launch_gemm(stream, latn, ca_q + (size_t)d * LD * INNER, q, nullptr, 0, 1.f,
                    M4, INNER, LD, LD, INNER, INNER, 0, 1, 1, 0, 0, 0, 0, 0, 0, 4, 1);
        hipLaunchKernelGGL(fill_kernel, dim3((M4 * INNER + 255) / 256), dim3(256), 0, stream, attn, (long long)M4 * INNER, 0.f);
        for (int b = 0; b < BATCH; ++b) {
            hipLaunchKernelGGL(build_data, dim3(NVOX), dim3(256), 0, stream, input, perm, Kc, normed_b, b);
            // kv_b = (normed_b * ctx_g) @ ca_kv[d]   (8192 x 1200)
            launch_gemm(stream, normed_b, ca_kv + (size_t)d * ID * 2 * INNER, kv_b, ca_ctx_g, d, 1.f,
                        NVOX, 2 * INNER, ID, ID, 2 * INNER, 2 * INNER, 0, 1, 1, 0, 0, 0, 0, 0, 0, 1, 0);
            // S_b = q_b k_b^T * scale   (8 heads x 128 x 8192)
            launch_gemm(stream, q + (size_t)b * qStrideB, kv_b, SN, nullptr, 0, scaleS,
                        NL, NVOX, DH, INNER, 2 * INNER, NVOX, 1, HEADS, HEADS,
                        0, DH, 0, DH, 0, (long long)NL * NVOX, 1, 0);
            hipLaunchKernelGGL(softmax_rows, dim3(HEADS * NL), dim3(256), 0, stream, SN, NVOX, Kc, b);
            // attn_b += S_b @ V_b
            launch_gemm(stream, SN, kv_b + INNER, attn + (size_t)b * qStrideB, nullptr, 0, 1.f,
                        NL, DH, NVOX, NVOX, 2 * INNER, INNER, 0, HEADS, HEADS,
                        0, (long long)NL * NVOX, 0, DH, 0, DH, 8, 1);
        }
        hipLaunchKernelGGL(addbias_kernel, dim3((M4 * LD + 255) / 256), dim3(256), 0, stream, lat, ca_ob + (size_t)d * LD, (long long)M4 * LD, LD);
        launch_gemm(stream, attn, ca_ow + (size_t)d * INNER * LD, lat, nullptr, 0, 1.f,
                    M4, LD, INNER, INNER, LD, LD, 0, 1, 1, 0, 0, 0, 0, 0, 0, 4, 1);
        // ---- FF (cf) ----
        hipLaunchKernelGGL(scale_norm_k, dim3(M4), dim3(256), 0, stream, lat, latn, cf_g, d, LD);
        hipLaunchKernelGGL(fill_kernel, dim3((M4 * FFD + 255) / 256), dim3(256), 0, stream, ffb, (long long)M4 * FFD, 0.f);
        launch_gemm(stream, latn, cf_w1 + (size_t)d * LD * FFD, ffb, nullptr, 0, 1.f,
                    M4, FFD, LD, LD, FFD, FFD, 0, 1, 1, 0, 0, 0, 0, 0, 0, 2, 1);
        hipLaunchKernelGGL(biasgelu_kernel, dim3((M4 * FFD + 255) / 256), dim3(256), 0, stream, ffb, cf_b1 + (size_t)d * FFD, (long long)M4 * FFD, FFD);
        hipLaunchKernelGGL(addbias_kernel, dim3((M4 * LD + 255) / 256), dim3(256), 0, stream, lat, cf_b2 + (size_t)d * LD, (long long)M4 * LD, LD);
        launch_gemm(stream, ffb, cf_w2 + (size_t)d * FFD * LD, lat, nullptr, 0, 1.f,
                    M4, LD, FFD, FFD, LD, LD, 0, 1, 1, 0, 0, 0, 0, 0, 0, 8, 1);
        // ---- latent self attention ----
        hipLaunchKernelGGL(scale_norm_k, dim3(M4), dim3(256), 0, stream, lat, latn, la_g, d, LD);
        hipLaunchKernelGGL(fill_kernel, dim3((M4 * INNER + 255) / 256), dim3(256), 0, stream, q, (long long)M4 * INNER, 0.f);
        launch_gemm(stream, latn, la_q + (size_t)d * LD * INNER, q, nullptr, 0, 1.f,
                    M4, INNER, LD, LD, INNER, INNER, 0, 1, 1, 0, 0, 0, 0, 0, 0, 4, 1);
        hipLaunchKernelGGL(fill_kernel, dim3((M4 * 2 * INNER + 255) / 256), dim3(256), 0, stream, kvself, (long long)M4 * 2 * INNER, 0.f);
        launch_gemm(stream, latn, la_kv + (size_t)d * LD * 2 * INNER, kvself, nullptr, 0, 1.f,
                    M4, 2 * INNER, LD, LD, 2 * INNER, 2 * INNER, 0, 1, 1, 0, 0, 0, 0, 0, 0, 2, 1);
        // S_self (b*h x 128 x 128) fits easily in SN
        launch_gemm(stream, q, kvself, SN, nullptr, 0, scaleS,
                    NL, NL, DH, INNER, 2 * INNER, NL, 1, BATCH * HEADS, HEADS,
                    qStrideB, DH, (long long)NL * 2 * INNER, DH, (long long)HEADS * NL * NL, (long long)NL * NL, 1, 0);
        hipLaunchKernelGGL(softmax_rows, dim3(BATCH * HEADS * NL), dim3(256), 0, stream, SN, NL, (const int*)nullptr, -1);
        launch_gemm(stream, SN, kvself + INNER, attn, nullptr, 0, 1.f,
                    NL, DH, NL, NL, 2 * INNER, INNER, 0, BATCH * HEADS, HEADS,
                    (long long)HEADS * NL * NL, (long long)NL * NL, (long long)NL * 2 * INNER, DH, qStrideB, DH, 1, 0);
        hipLaunchKernelGGL(addbias_kernel, dim3((M4 * LD + 255) / 256), dim3(256), 0, stream, lat, la_ob + (size_t)d * LD, (long long)M4 * LD, LD);
        launch_gemm(stream, attn, la_ow + (size_t)d * INNER * LD, lat, nullptr, 0, 1.f,
                    M4, LD, INNER, INNER, LD, LD, 0, 1, 1, 0, 0, 0, 0, 0, 0, 4, 1);
        // ---- FF (lf) ----
        hipLaunchKernelGGL(scale_norm_k, dim3(M4), dim3(256), 0, stream, lat, latn, lf_g, d, LD);
        hipLaunchKernelGGL(fill_kernel, dim3((M4 * FFD + 255) / 256), dim3(256), 0, stream, ffb, (long long)M4 * FFD, 0.f);
        launch_gemm(stream, latn, lf_w1 + (size_t)d * LD * FFD, ffb, nullptr, 0, 1.f,
                    M4, FFD, LD, LD, FFD, FFD, 0, 1, 1, 0, 0, 0, 0, 0, 0, 2, 1);
        hipLaunchKernelGGL(biasgelu_kernel, dim3((M4 * FFD + 255) / 256), dim3(256), 0, stream, ffb, lf_b1 + (size_t)d * FFD, (long long)M4 * FFD, FFD);
        hipLaunchKernelGGL(addbias_kernel, dim3((M4 * LD + 255) / 256), dim3(256), 0, stream, lat, lf_b2 + (size_t)d * LD, (long long)M4 * LD, LD);
        launch_gemm(stream, ffb, lf_w2 + (size_t)d * FFD * LD, lat, nullptr, 0, 1.f,
                    M4, LD, FFD, FFD, LD, LD, 0, 1, 1, 0, 0, 0, 0, 0, 0, 8, 1);
    }

    // logits + reorder
    hipLaunchKernelGGL(fill_kernel, dim3((M4 * OC + 255) / 256), dim3(256), 0, stream, outtmp, (long long)M4 * OC, 0.f);
    launch_gemm(stream, lat, logits_w, outtmp, nullptr, 0, 1.f,
                M4, OC, LD, LD, OC, OC, 0, 1, 1, 0, 0, 0, 0, 0, 0, 4, 1);
    hipLaunchKernelGGL(addbias_kernel, dim3((M4 * OC + 255) / 256), dim3(256), 0, stream, outtmp, logits_b, (long long)M4 * OC, OC);
    hipLaunchKernelGGL(reorder_kernel, dim3((TBINS * BATCH * (NL / TBINS) * OC + 255) / 256), dim3(256), 0, stream, outtmp, out);
}

// Round 3
// 4275.378 us; speedup vs baseline: 2.7508x; 2.7508x over previous
//
#include <hip/hip_runtime.h>
#include <math.h>

typedef unsigned short u16;
typedef __attribute__((ext_vector_type(8))) short short8;
typedef __attribute__((ext_vector_type(4))) float f32x4;

// Problem constants
#define TBINS 8
#define BATCH 4
#define CIN 3
#define WIMG 128
#define PC 48
#define NVOX 8192
#define ID 435
#define IDP 448      // ceil32(435)
#define LD 512
#define INNER 600
#define INNERP 608   // ceil32(600)
#define FFD 2048
#define NL 128
#define OC 64
#define DEPTH 5
#define HEADS 8
#define DH 75
#define DHP 96       // ceil32(75)

static __device__ __forceinline__ u16 f2bf(float f) {
    unsigned x = __float_as_uint(f);
    unsigned r = (x + 0x7fffu + ((x >> 16) & 1u)) >> 16;
    return (u16)r;
}

// ---------------------------------------------------------------------------
__global__ __launch_bounds__(256) void mask_kernel(const float* __restrict__ input,
                                                   unsigned char* __restrict__ mask) {
    int idx = blockIdx.x * 256 + threadIdx.x;
    if (idx >= BATCH * NVOX) return;
    int b = idx >> 13, i = idx & (NVOX - 1);
    int tt = i & 7, wx = (i >> 3) & 31, hy = i >> 8;
    float mx = -3.4e38f;
    for (int ch = 0; ch < PC; ++ch) {
        int py = ch / 12, px = (ch / 3) & 3, cc = ch % 3;
        float v = input[((size_t)((tt * BATCH + b) * CIN + cc) << 14) +
                        (hy * 4 + py) * WIMG + (wx * 4 + px)];
        mx = fmaxf(mx, v);
    }
    mask[idx] = (fabsf(mx) > 0.3f) ? 1 : 0;
}

__global__ __launch_bounds__(64) void compact_kernel(const unsigned char* __restrict__ mask,
                                                     int* __restrict__ perm,
                                                     int* __restrict__ Kc) {
    int b = blockIdx.x, lane = threadIdx.x;
    int offs = 0;
    for (int c = 0; c < NVOX / 64; ++c) {
        int i = c * 64 + lane;
        int m = mask[(b << 13) + i];
        unsigned long long bal = __ballot(m != 0);
        int excl = __popcll(bal & ((1ull << lane) - 1ull));
        if (m) perm[(b << 13) + offs + excl] = i;
        offs += __popcll(bal);
    }
    if (lane == 0) Kc[b] = offs;
}

// build normalized data row (bf16, ld IDP, zero-padded) for one batch
__global__ __launch_bounds__(256) void build_data_bf(const float* __restrict__ input,
                                                     const int* __restrict__ perm,
                                                     const int* __restrict__ Kc,
                                                     u16* __restrict__ normed, int b) {
    int r = blockIdx.x, tid = threadIdx.x;
    u16* out = normed + (size_t)r * IDP;
    int Kb = Kc[b];
    if (r >= Kb) {
        for (int e = tid; e < IDP; e += 256) out[e] = 0;
        return;
    }
    __shared__ float row[IDP];
    __shared__ float red[256];
    int i = perm[(b << 13) + r];
    int tt = i & 7, wx = (i >> 3) & 31, hy = i >> 8;
    float pos0 = 2.f * hy / 32.f - 1.f;
    float pos1 = 2.f * wx / 32.f - 1.f;
    float pos2 = 2.f * tt / 8.f - 1.f;
    for (int e = tid; e < IDP; e += 256) {
        float v = 0.f;
        if (e < PC) {
            int py = e / 12, px = (e / 3) & 3, cc = e % 3;
            v = input[((size_t)((tt * BATCH + b) * CIN + cc) << 14) +
                      (hy * 4 + py) * WIMG + (wx * 4 + px)];
        } else if (e < ID) {
            int e2 = e - PC;
            int dim = e2 / 129, rem = e2 - dim * 129;
            float pp = (dim == 0) ? pos0 : (dim == 1 ? pos1 : pos2);
            if (rem < 64)       v = sinf(ldexpf(pp, -rem));
            else if (rem < 128) v = cosf(ldexpf(pp, -(rem - 64)));
            else                v = pp;
        }
        row[e] = v;
    }
    __syncthreads();
    float ss = 0.f;
    for (int e = tid; e < ID; e += 256) ss += row[e] * row[e];
    red[tid] = ss; __syncthreads();
    for (int s = 128; s > 0; s >>= 1) { if (tid < s) red[tid] += red[tid + s]; __syncthreads(); }
    float scale = 1.f / fmaxf(sqrtf(red[0]), 1e-5f);
    for (int e = tid; e < IDP; e += 256) out[e] = f2bf(row[e] * scale);
}

__global__ __launch_bounds__(256) void lat_init(const float* __restrict__ latents,
                                                const float* __restrict__ pos_emb,
                                                float* __restrict__ lat) {
    int idx = blockIdx.x * 256 + threadIdx.x;
    if (idx >= BATCH * NL * LD) return;
    int rem = idx & (NL * LD - 1);
    lat[idx] = latents[rem] + pos_emb[rem];
}

// scale_norm, bf16 output
__global__ __launch_bounds__(256) void scale_norm_bf(const float* __restrict__ x,
                                                     u16* __restrict__ o,
                                                     const float* __restrict__ g, int gi,
                                                     int cols) {
    int rowi = blockIdx.x, tid = threadIdx.x;
    const float* xr = x + (size_t)rowi * cols;
    u16* orow = o + (size_t)rowi * cols;
    __shared__ float red[256];
    float ss = 0.f;
    for (int c = tid; c < cols; c += 256) { float v = xr[c]; ss += v * v; }
    red[tid] = ss; __syncthreads();
    for (int s = 128; s > 0; s >>= 1) { if (tid < s) red[tid] += red[tid + s]; __syncthreads(); }
    float scale = g[gi] / fmaxf(sqrtf(red[0]), 1e-5f);
    for (int c = tid; c < cols; c += 256) orow[c] = f2bf(xr[c] * scale);
}

__global__ __launch_bounds__(256) void fill_kernel(float* __restrict__ p, long long n, float v) {
    long long idx = (long long)blockIdx.x * 256 + threadIdx.x;
    if (idx < n) p[idx] = v;
}

__global__ __launch_bounds__(256) void addbias_kernel(float* __restrict__ d,
                                                      const float* __restrict__ bias,
                                                      long long total, int n) {
    long long idx = (long long)blockIdx.x * 256 + threadIdx.x;
    if (idx < total) d[idx] += bias[idx % n];
}

// gelu(src+bias) -> bf16 dst
__global__ __launch_bounds__(256) void biasgelu_bf(const float* __restrict__ src,
                                                   const float* __restrict__ bias,
                                                   u16* __restrict__ dst,
                                                   long long total, int n) {
    long long idx = (long long)blockIdx.x * 256 + threadIdx.x;
    if (idx < total) {
        float v = src[idx] + bias[idx % n];
        dst[idx] = f2bf(0.5f * v * (1.f + erff(v * 0.70710678118654752f)));
    }
}

// fp32 (rows x sc) -> bf16 (rows x dc), zero pad cols
__global__ __launch_bounds__(256) void pad_conv(const float* __restrict__ src, u16* __restrict__ dst,
                                                int rows, int sc, int dc) {
    int idx = blockIdx.x * 256 + threadIdx.x;
    if (idx >= rows * dc) return;
    int r = idx / dc, c = idx - r * dc;
    dst[idx] = f2bf(c < sc ? src[(size_t)r * sc + c] : 0.f);
}

__global__ __launch_bounds__(256) void conv_bf(const float* __restrict__ src, u16* __restrict__ dst, int n) {
    int idx = blockIdx.x * 256 + threadIdx.x;
    if (idx < n) dst[idx] = f2bf(src[idx]);
}

// transpose fp32 (R x C) -> bf16 (C x Rp), Rp=ceil32(R), zero pad
__global__ __launch_bounds__(256) void transpose_conv(const float* __restrict__ src, u16* __restrict__ dst,
                                                      int R, int C, int Rp) {
    __shared__ float t[32][33];
    int bx = blockIdx.x * 32, by = blockIdx.y * 32;
    int tx = threadIdx.x & 31, ty = threadIdx.x >> 5;
#pragma unroll
    for (int p = 0; p < 4; ++p) {
        int r = bx + ty + p * 8, c = by + tx;
        t[ty + p * 8][tx] = (r < R && c < C) ? src[(size_t)r * C + c] : 0.f;
    }
    __syncthreads();
#pragma unroll
    for (int p = 0; p < 4; ++p) {
        int c = by + ty + p * 8, r = bx + tx;
        if (c < C && r < Rp) dst[(size_t)c * Rp + r] = f2bf(t[tx][ty + p * 8]);
    }
}

// kv_bf (8192 x 1200 bf16) -> k_bf (h, 8192, DHP) zero-padded
__global__ __launch_bounds__(256) void pack_k_ctx(const u16* __restrict__ kv, u16* __restrict__ kbf) {
    int idx = blockIdx.x * 256 + threadIdx.x;
    if (idx >= HEADS * NVOX * DHP) return;
    int dd = idx % DHP;
    int vox = (idx / DHP) & (NVOX - 1);
    int h = idx / (DHP * NVOX);
    kbf[idx] = (dd < DH) ? kv[(size_t)vox * (2 * INNER) + h * DH + dd] : 0;
}

// kv_bf -> v_t (h, DH, 8192) transposed
__global__ __launch_bounds__(256) void pack_vt_ctx(const u16* __restrict__ kv, u16* __restrict__ vt) {
    __shared__ float t[32][33];
    int h = blockIdx.z;
    int bx = blockIdx.x * 32, by = blockIdx.y * 32;
    int tx = threadIdx.x & 31, ty = threadIdx.x >> 5;
#pragma unroll
    for (int p = 0; p < 4; ++p) {
        int vox = bx + ty + p * 8, dd = by + tx;
        float v = 0.f;
        if (dd < DH) { u16 raw = kv[(size_t)vox * (2 * INNER) + INNER + h * DH + dd];
                       unsigned u = ((unsigned)raw) << 16; v = __uint_as_float(u); }
        t[ty + p * 8][tx] = v;
    }
    __syncthreads();
#pragma unroll
    for (int p = 0; p < 4; ++p) {
        int dd = by + ty + p * 8, vox = bx + tx;
        if (dd < DH) vt[((size_t)h * DH + dd) * NVOX + vox] = f2bf(t[tx][ty + p * 8]);
    }
}

// fp32 (BATCH*128 x srcld) head-split -> bf16 (b*8+h, 128, DHP) zero-padded
__global__ __launch_bounds__(256) void pack_heads(const float* __restrict__ src, u16* __restrict__ dst,
                                                  int srcld) {
    int idx = blockIdx.x * 256 + threadIdx.x;
    if (idx >= BATCH * HEADS * NL * DHP) return;
    int dd = idx % DHP;
    int l = (idx / DHP) & (NL - 1);
    int bh = idx / (DHP * NL);
    int b = bh >> 3, h = bh & 7;
    float v = (dd < DH) ? src[(size_t)(b * NL + l) * srcld + h * DH + dd] : 0.f;
    dst[idx] = f2bf(v);
}

// kvself fp32 -> vs_t (b*8+h, DH, 128)
__global__ __launch_bounds__(256) void pack_vt_self(const float* __restrict__ kvs, u16* __restrict__ vt) {
    int idx = blockIdx.x * 256 + threadIdx.x;
    if (idx >= BATCH * HEADS * DH * NL) return;
    int l = idx & (NL - 1);
    int dd = (idx >> 7) % DH;
    int bh = idx / (DH * NL);
    int b = bh >> 3, h = bh & 7;
    vt[idx] = f2bf(kvs[(size_t)(b * NL + l) * (2 * INNER) + INNER + h * DH + dd]);
}

// masked softmax, fp32 in, bf16 out; row kept in registers (cols<=8192)
__global__ __launch_bounds__(256) void softmax_bf(const float* __restrict__ S, u16* __restrict__ Sb,
                                                  int cols, const int* __restrict__ Kc, int kidx) {
    int rowi = blockIdx.x, tid = threadIdx.x;
    const float* p = S + (size_t)rowi * cols;
    u16* ob = Sb + (size_t)rowi * cols;
    int lim = (kidx >= 0) ? Kc[kidx] : cols;
    __shared__ float red[256];
    float v[32];
    int nit = (lim + 255) >> 8;
    float mx = -3.4e38f;
    for (int s = 0; s < nit; ++s) {
        int j = s * 256 + tid;
        float x = (j < lim) ? p[j] : -3.4e38f;
        v[s] = x;
        mx = fmaxf(mx, x);
    }
    red[tid] = mx; __syncthreads();
    for (int s = 128; s > 0; s >>= 1) { if (tid < s) red[tid] = fmaxf(red[tid], red[tid + s]); __syncthreads(); }
    mx = red[0]; __syncthreads();
    float sum = 0.f;
    for (int s = 0; s < nit; ++s) {
        int j = s * 256 + tid;
        float e = (j < lim) ? expf(v[s] - mx) : 0.f;
        v[s] = e; sum += e;
    }
    red[tid] = sum; __syncthreads();
    for (int s = 128; s > 0; s >>= 1) { if (tid < s) red[tid] += red[tid + s]; __syncthreads(); }
    float inv = (red[0] > 0.f) ? 1.f / red[0] : 0.f;
    int nco = (cols + 255) >> 8;
    for (int s = 0; s < nco; ++s) {
        int j = s * 256 + tid;
        float val = (s < nit) ? v[s] * inv : 0.f;
        if (j < cols) ob[j] = f2bf(val);
    }
}

// ---------------------------------------------------------------------------
// bf16 MFMA GEMM: D = alpha * A @ B^T_layout
// A: M x K bf16 row-major (lda). B: N x K bf16 row-major (ldb). K % 32 == 0.
// D: fp32 (or bf16 if dbf) M x N (ldd). Batched z=(zo*nh+zi)*splitK+kc.
#define LDT 40
__global__ __launch_bounds__(256) void gemm_bf16(
    const u16* __restrict__ A, const u16* __restrict__ B, float* __restrict__ D,
    const float* __restrict__ alphaPtr, int alphaIdx, float alphaConst,
    int M, int N, int K, int lda, int ldb, int ldd, int nh,
    long long sAo, long long sAi, long long sBo, long long sBi,
    long long sDo, long long sDi, int splitK, int atomic, int dbf) {
    __shared__ u16 As[128 * LDT];
    __shared__ u16 Bs[128 * LDT];
    const int tid = threadIdx.x;
    int zb = blockIdx.z / splitK, kc = blockIdx.z - zb * splitK;
    int zo = zb / nh, zi = zb - zo * nh;
    const u16* Ab = A + (size_t)zo * sAo + (size_t)zi * sAi;
    const u16* Bb = B + (size_t)zo * sBo + (size_t)zi * sBi;
    float* Db = D + (size_t)zo * sDo + (size_t)zi * sDi;
    const int bm = blockIdx.x * 128, bn = blockIdx.y * 128;
    int nk = K >> 5;
    int per = (nk + splitK - 1) / splitK;
    int k0 = kc * per * 32;
    int k1 = min(K, k0 + per * 32);

    const int wv = tid >> 6, lane = tid & 63;
    const int wm = (wv & 1) << 6, wn = (wv >> 1) << 6;
    const int fr = lane & 15, fc = lane >> 4;
    f32x4 acc[4][4] = {};

    const int srow = tid >> 2, scol = (tid & 3) << 3;
    for (int kb = k0; kb < k1; kb += 32) {
#pragma unroll
        for (int p = 0; p < 2; ++p) {
            int row = srow + p * 64;
            short8 av = {0, 0, 0, 0, 0, 0, 0, 0};
            if (bm + row < M) av = *(const short8*)(Ab + (size_t)(bm + row) * lda + kb + scol);
            *(short8*)(As + row * LDT + scol) = av;
            short8 bv = {0, 0, 0, 0, 0, 0, 0, 0};
            if (bn + row < N) bv = *(const short8*)(Bb + (size_t)(bn + row) * ldb + kb + scol);
            *(short8*)(Bs + row * LDT + scol) = bv;
        }
        __syncthreads();
        short8 af[4], bfr[4];
#pragma unroll
        for (int i = 0; i < 4; ++i)
            af[i] = *(const short8*)(As + (wm + i * 16 + fr) * LDT + fc * 8);
#pragma unroll
        for (int j = 0; j < 4; ++j)
            bfr[j] = *(const short8*)(Bs + (wn + j * 16 + fr) * LDT + fc * 8);
#pragma unroll
        for (int i = 0; i < 4; ++i)
#pragma unroll
            for (int j = 0; j < 4; ++j)
                acc[i][j] = __builtin_amdgcn_mfma_f32_16x16x32_bf16(af[i], bfr[j], acc[i][j], 0, 0, 0);
        __syncthreads();
    }
    float alpha = alphaConst * (alphaPtr ? alphaPtr[alphaIdx] : 1.f);
    u16* Du = (u16*)Db;
#pragma unroll
    for (int i = 0; i < 4; ++i) {
#pragma unroll
        for (int j = 0; j < 4; ++j) {
            int gn = bn + wn + j * 16 + fr;
            if (gn >= N) continue;
            int gm0 = bm + wm + i * 16 + fc * 4;
#pragma unroll
            for (int r = 0; r < 4; ++r) {
                int gm = gm0 + r;
                if (gm >= M) continue;
                float v = acc[i][j][r] * alpha;
                size_t di = (size_t)gm * ldd + gn;
                if (dbf) Du[di] = f2bf(v);
                else if (atomic) atomicAdd(&Db[di], v);
                else Db[di] = v;
            }
        }
    }
}

// final permute: outtmp (b,128,64) -> d_out (t,b,n,64), latent = n*8 + t
__global__ __launch_bounds__(256) void reorder_kernel(const float* __restrict__ outtmp,
                                                      float* __restrict__ out) {
    int idx = blockIdx.x * 256 + threadIdx.x;
    if (idx >= TBINS * BATCH * (NL / TBINS) * OC) return;
    int oc = idx & 63, n = (idx >> 6) & 15, b = (idx >> 10) & 3, t = idx >> 12;
    out[idx] = outtmp[((size_t)(b * NL + n * TBINS + t)) * OC + oc];
}

// ---------------------------------------------------------------------------
extern "C" void kernel_launch(void* const* d_in, const int* in_sizes, int n_in,
                              void* d_out, int out_size, void* d_ws, size_t ws_size,
                              hipStream_t stream) {
    const float* input    = (const float*)d_in[0];
    const float* latents  = (const float*)d_in[1];
    const float* pos_emb  = (const float*)d_in[2];
    const float* ca_g     = (const float*)d_in[3];
    const float* ca_ctx_g = (const float*)d_in[4];
    const float* ca_q     = (const float*)d_in[5];
    const float* ca_kv    = (const float*)d_in[6];
    const float* ca_ow    = (const float*)d_in[7];
    const float* ca_ob    = (const float*)d_in[8];
    const float* cf_g     = (const float*)d_in[9];
    const float* cf_w1    = (const float*)d_in[10];
    const float* cf_b1    = (const float*)d_in[11];
    const float* cf_w2    = (const float*)d_in[12];
    const float* cf_b2    = (const float*)d_in[13];
    const float* la_g     = (const float*)d_in[14];
    const float* la_q     = (const float*)d_in[15];
    const float* la_kv    = (const float*)d_in[16];
    const float* la_ow    = (const float*)d_in[17];
    const float* la_ob    = (const float*)d_in[18];
    const float* lf_g     = (const float*)d_in[19];
    const float* lf_w1    = (const float*)d_in[20];
    const float* lf_b1    = (const float*)d_in[21];
    const float* lf_w2    = (const float*)d_in[22];
    const float* lf_b2    = (const float*)d_in[23];
    const float* logits_w = (const float*)d_in[24];
    const float* logits_b = (const float*)d_in[25];
    float* out = (float*)d_out;
    (void)ws_size; (void)n_in; (void)in_sizes; (void)out_size;

    // workspace carve (~101 MB)
    char* w = (char*)d_ws;
    auto alloc = [&](size_t bytes) { void* p = (void*)w; w += (bytes + 255) & ~(size_t)255; return p; };
    int* perm      = (int*)alloc((size_t)BATCH * NVOX * 4);
    int* Kc        = (int*)alloc(64);
    unsigned char* mask = (unsigned char*)alloc((size_t)BATCH * NVOX);
    float* lat     = (float*)alloc((size_t)BATCH * NL * LD * 4);
    u16* latn_bf   = (u16*)alloc((size_t)BATCH * NL * LD * 2);
    float* q       = (float*)alloc((size_t)BATCH * NL * INNER * 4);
    float* attn    = (float*)alloc((size_t)BATCH * NL * INNER * 4);
    u16* attn_bf   = (u16*)alloc((size_t)BATCH * NL * INNERP * 2);
    float* ffb     = (float*)alloc((size_t)BATCH * NL * FFD * 4);
    u16* ffb_bf    = (u16*)alloc((size_t)BATCH * NL * FFD * 2);
    float* kvself  = (float*)alloc((size_t)BATCH * NL * 2 * INNER * 4);
    float* outtmp  = (float*)alloc((size_t)BATCH * NL * OC * 4);
    u16* q_bf      = (u16*)alloc((size_t)BATCH * HEADS * NL * DHP * 2);
    u16* ks_bf     = (u16*)alloc((size_t)BATCH * HEADS * NL * DHP * 2);
    u16* vs_t      = (u16*)alloc((size_t)BATCH * HEADS * DH * NL * 2);
    u16* k_bf      = (u16*)alloc((size_t)HEADS * NVOX * DHP * 2);     // 12.6 MB
    u16* v_t       = (u16*)alloc((size_t)HEADS * DH * NVOX * 2);      // 9.8 MB
    // union region: kv_bf (8192x1200 bf16 = 19.7MB) OR SN fp32 (8x128x8192 = 33.6MB; self 2MB)
    float* SN      = (float*)alloc((size_t)HEADS * NL * NVOX * 4);    // 33.6 MB
    u16* kv_bf     = (u16*)SN;
    // union region: S_bf (8x128x8192 bf16 = 16.8MB) OR normed_bf (8192x448 bf16 = 7.3MB)
    u16* S_bf      = (u16*)alloc((size_t)HEADS * NL * NVOX * 2);      // 16.8 MB
    u16* normed_bf = S_bf;
    // per-layer transposed bf16 weights (13.2 MB)
    u16* wq_t   = (u16*)alloc((size_t)INNER * LD * 2);
    u16* wkv_t  = (u16*)alloc((size_t)2 * INNER * IDP * 2);
    u16* wow_t  = (u16*)alloc((size_t)LD * INNERP * 2);
    u16* wf1_t  = (u16*)alloc((size_t)FFD * LD * 2);
    u16* wf2_t  = (u16*)alloc((size_t)LD * FFD * 2);
    u16* wlq_t  = (u16*)alloc((size_t)INNER * LD * 2);
    u16* wlkv_t = (u16*)alloc((size_t)2 * INNER * LD * 2);
    u16* wlow_t = (u16*)alloc((size_t)LD * INNERP * 2);
    u16* wlf1_t = (u16*)alloc((size_t)FFD * LD * 2);
    u16* wlf2_t = (u16*)alloc((size_t)LD * FFD * 2);
    u16* wlog_t = (u16*)alloc((size_t)OC * LD * 2);

    const float scaleS = 1.0f / sqrtf((float)DH);
    const int M4 = BATCH * NL;

    auto G = [&](const u16* A, const u16* B, float* D, const float* aP, int aI, float aC,
                 int M, int N, int K, int lda, int ldb, int ldd, int nh, int nb,
                 long long sAo, long long sAi, long long sBo, long long sBi,
                 long long sDo, long long sDi, int splitK, int atomic, int dbf) {
        dim3 g((M + 127) / 128, (N + 127) / 128, nb * splitK);
        hipLaunchKernelGGL(gemm_bf16, g, dim3(256), 0, stream, A, B, D, aP, aI, aC,
                           M, N, K, lda, ldb, ldd, nh, sAo, sAi, sBo, sBi, sDo, sDi,
                           splitK, atomic, dbf);
    };
    auto TT = [&](const float* src, u16* dst, int R, int C, int Rp) {
        hipLaunchKernelGGL(transpose_conv, dim3(Rp / 32, (C + 31) / 32), dim3(256), 0, stream,
                           src, dst, R, C, Rp);
    };

    hipLaunchKernelGGL(mask_kernel, dim3((BATCH * NVOX + 255) / 256), dim3(256), 0, stream, input, mask);
    hipLaunchKernelGGL(compact_kernel, dim3(BATCH), dim3(64), 0, stream, mask, perm, Kc);
    hipLaunchKernelGGL(lat_init, dim3((BATCH * NL * LD + 255) / 256), dim3(256), 0, stream, latents, pos_emb, lat);

    for (int d = 0; d < DEPTH; ++d) {
        // per-layer weight transposes
        TT(ca_q  + (size_t)d * LD * INNER,      wq_t,   LD, INNER, LD);
        TT(ca_kv + (size_t)d * ID * 2 * INNER,  wkv_t,  ID, 2 * INNER, IDP);
        TT(ca_ow + (size_t)d * INNER * LD,      wow_t,  INNER, LD, INNERP);
        TT(cf_w1 + (size_t)d * LD * FFD,        wf1_t,  LD, FFD, LD);
        TT(cf_w2 + (size_t)d * FFD * LD,        wf2_t,  FFD, LD, FFD);
        TT(la_q  + (size_t)d * LD * INNER,      wlq_t,  LD, INNER, LD);
        TT(la_kv + (size_t)d * LD * 2 * INNER,  wlkv_t, LD, 2 * INNER, LD);
        TT(la_ow + (size_t)d * INNER * LD,      wlow_t, INNER, LD, INNERP);
        TT(lf_w1 + (size_t)d * LD * FFD,        wlf1_t, LD, FFD, LD);
        TT(lf_w2 + (size_t)d * FFD * LD,        wlf2_t, FFD, LD, FFD);

        // ---- cross attention ----
        hipLaunchKernelGGL(scale_norm_bf, dim3(M4), dim3(256), 0, stream, lat, latn_bf, ca_g, d, LD);
        G(latn_bf, wq_t, q, nullptr, 0, 1.f, M4, INNER, LD, LD, LD, INNER, 1, 1,
          0, 0, 0, 0, 0, 0, 1, 0, 0);
        hipLaunchKernelGGL(pack_heads, dim3((BATCH * HEADS * NL * DHP + 255) / 256), dim3(256), 0, stream,
                           q, q_bf, INNER);
        hipLaunchKernelGGL(fill_kernel, dim3((M4 * INNER + 255) / 256), dim3(256), 0, stream,
                           attn, (long long)M4 * INNER, 0.f);
        for (int b = 0; b < BATCH; ++b) {
            hipLaunchKernelGGL(build_data_bf, dim3(NVOX), dim3(256), 0, stream, input, perm, Kc, normed_bf, b);
            // kv_bf = (normed * ctx_g) @ ca_kv[d]  (8192 x 1200, bf16 out)
            G(normed_bf, wkv_t, (float*)kv_bf, ca_ctx_g, d, 1.f, NVOX, 2 * INNER, IDP,
              IDP, IDP, 2 * INNER, 1, 1, 0, 0, 0, 0, 0, 0, 1, 0, 1);
            hipLaunchKernelGGL(pack_k_ctx, dim3((HEADS * NVOX * DHP + 255) / 256), dim3(256), 0, stream,
                               kv_bf, k_bf);
            hipLaunchKernelGGL(pack_vt_ctx, dim3(NVOX / 32, (DH + 31) / 32, HEADS), dim3(256), 0, stream,
                               kv_bf, v_t);
            // S = q k^T * scale (8 heads, 128 x 8192)
            G(q_bf + (size_t)b * HEADS * NL * DHP, k_bf, SN, nullptr, 0, scaleS,
              NL, NVOX, DHP, DHP, DHP, NVOX, 8, 8,
              0, (long long)NL * DHP, 0, (long long)NVOX * DHP, 0, (long long)NL * NVOX, 1, 0, 0);
            hipLaunchKernelGGL(softmax_bf, dim3(HEADS * NL), dim3(256), 0, stream, SN, S_bf, NVOX, Kc, b);
            // attn_b += S @ V  (per head, atomic fp32, splitK=16)
            G(S_bf, v_t, attn + (size_t)b * NL * INNER, nullptr, 0, 1.f,
              NL, DH, NVOX, NVOX, NVOX, INNER, 8, 8,
              0, (long long)NL * NVOX, 0, (long long)DH * NVOX, 0, DH, 16, 1, 0);
        }
        hipLaunchKernelGGL(addbias_kernel, dim3((M4 * LD + 255) / 256), dim3(256), 0, stream,
                           lat, ca_ob + (size_t)d * LD, (long long)M4 * LD, LD);
        hipLaunchKernelGGL(pad_conv, dim3((M4 * INNERP + 255) / 256), dim3(256), 0, stream,
                           attn, attn_bf, M4, INNER, INNERP);
        G(attn_bf, wow_t, lat, nullptr, 0, 1.f, M4, LD, INNERP, INNERP, INNERP, LD, 1, 1,
          0, 0, 0, 0, 0, 0, 2, 1, 0);

        // ---- FF (cf) ----
        hipLaunchKernelGGL(scale_norm_bf, dim3(M4), dim3(256), 0, stream, lat, latn_bf, cf_g, d, LD);
        G(latn_bf, wf1_t, ffb, nullptr, 0, 1.f, M4, FFD, LD, LD, LD, FFD, 1, 1,
          0, 0, 0, 0, 0, 0, 1, 0, 0);
        hipLaunchKernelGGL(biasgelu_bf, dim3((M4 * FFD + 255) / 256), dim3(256), 0, stream,
                           ffb, cf_b1 + (size_t)d * FFD, ffb_bf, (long long)M4 * FFD, FFD);
        hipLaunchKernelGGL(addbias_kernel, dim3((M4 * LD + 255) / 256), dim3(256), 0, stream,
                           lat, cf_b2 + (size_t)d * LD, (long long)M4 * LD, LD);
        G(ffb_bf, wf2_t, lat, nullptr, 0, 1.f, M4, LD, FFD, FFD, FFD, LD, 1, 1,
          0, 0, 0, 0, 0, 0, 8, 1, 0);

        // ---- latent self attention ----
        hipLaunchKernelGGL(scale_norm_bf, dim3(M4), dim3(256), 0, stream, lat, latn_bf, la_g, d, LD);
        G(latn_bf, wlq_t, q, nullptr, 0, 1.f, M4, INNER, LD, LD, LD, INNER, 1, 1,
          0, 0, 0, 0, 0, 0, 1, 0, 0);
        G(latn_bf, wlkv_t, kvself, nullptr, 0, 1.f, M4, 2 * INNER, LD, LD, LD, 2 * INNER, 1, 1,
          0, 0, 0, 0, 0, 0, 1, 0, 0);
        hipLaunchKernelGGL(pack_heads, dim3((BATCH * HEADS * NL * DHP + 255) / 256), dim3(256), 0, stream,
                           q, q_bf, INNER);
        hipLaunchKernelGGL(pack_heads, dim3((BATCH * HEADS * NL * DHP + 255) / 256), dim3(256), 0, stream,
                           kvself, ks_bf, 2 * INNER);
        hipLaunchKernelGGL(pack_vt_self, dim3((BATCH * HEADS * DH * NL + 255) / 256), dim3(256), 0, stream,
                           kvself, vs_t);
        // S_self (32 bh, 128 x 128)
        G(q_bf, ks_bf, SN, nullptr, 0, scaleS, NL, NL, DHP, DHP, DHP, NL, 32, 32,
          0, (long long)NL * DHP, 0, (long long)NL * DHP, 0, (long long)NL * NL, 1, 0, 0);
        hipLaunchKernelGGL(softmax_bf, dim3(BATCH * HEADS * NL), dim3(256), 0, stream,
                           SN, S_bf, NL, (const int*)nullptr, -1);
        // attn = S_self @ V_self (non-atomic, full overwrite)
        G(S_bf, vs_t, attn, nullptr, 0, 1.f, NL, DH, NL, NL, NL, INNER, 8, 32,
          (long long)HEADS * NL * NL, (long long)NL * NL,
          (long long)HEADS * DH * NL, (long long)DH * NL,
          (long long)NL * INNER, DH, 1, 0, 0);
        hipLaunchKernelGGL(addbias_kernel, dim3((M4 * LD + 255) / 256), dim3(256), 0, stream,
                           lat, la_ob + (size_t)d * LD, (long long)M4 * LD, LD);
        hipLaunchKernelGGL(pad_conv, dim3((M4 * INNERP + 255) / 256), dim3(256), 0, stream,
                           attn, attn_bf, M4, INNER, INNERP);
        G(attn_bf, wlow_t, lat, nullptr, 0, 1.f, M4, LD, INNERP, INNERP, INNERP, LD, 1, 1,
          0, 0, 0, 0, 0, 0, 2, 1, 0);

        // ---- FF (lf) ----
        hipLaunchKernelGGL(scale_norm_bf, dim3(M4), dim3(256), 0, stream, lat, latn_bf, lf_g, d, LD);
        G(latn_bf, wlf1_t, ffb, nullptr, 0, 1.f, M4, FFD, LD, LD, LD, FFD, 1, 1,
          0, 0, 0, 0, 0, 0, 1, 0, 0);
        hipLaunchKernelGGL(biasgelu_bf, dim3((M4 * FFD + 255) / 256), dim3(256), 0, stream,
                           ffb, lf_b1 + (size_t)d * FFD, ffb_bf, (long long)M4 * FFD, FFD);
        hipLaunchKernelGGL(addbias_kernel, dim3((M4 * LD + 255) / 256), dim3(256), 0, stream,
                           lat, lf_b2 + (size_t)d * LD, (long long)M4 * LD, LD);
        G(ffb_bf, wlf2_t, lat, nullptr, 0, 1.f, M4, LD, FFD, FFD, FFD, LD, 1, 1,
          0, 0, 0, 0, 0, 0, 8, 1, 0);
    }

    // logits + reorder
    TT(logits_w, wlog_t, LD, OC, LD);
    hipLaunchKernelGGL(conv_bf, dim3((M4 * LD + 255) / 256), dim3(256), 0, stream, lat, latn_bf, M4 * LD);
    hipLaunchKernelGGL(fill_kernel, dim3((M4 * OC + 255) / 256), dim3(256), 0, stream,
                       outtmp, (long long)M4 * OC, 0.f);
    G(latn_bf, wlog_t, outtmp, nullptr, 0, 1.f, M4, OC, LD, LD, LD, OC, 1, 1,
      0, 0, 0, 0, 0, 0, 4, 1, 0);
    hipLaunchKernelGGL(addbias_kernel, dim3((M4 * OC + 255) / 256), dim3(256), 0, stream,
                       outtmp, logits_b, (long long)M4 * OC, OC);
    hipLaunchKernelGGL(reorder_kernel, dim3((TBINS * BATCH * (NL / TBINS) * OC + 255) / 256), dim3(256), 0,
                       stream, outtmp, out);
}

// Round 4
// 3263.327 us; speedup vs baseline: 3.6039x; 1.3101x over previous
//
#include <hip/hip_runtime.h>
#include <math.h>

typedef unsigned short u16;
typedef long long ll;
typedef __attribute__((ext_vector_type(8))) short short8;
typedef __attribute__((ext_vector_type(4))) float f32x4;

// Problem constants
#define TBINS 8
#define BATCH 4
#define CIN 3
#define WIMG 128
#define PC 48
#define NVOX 8192
#define ID 435
#define IDP 448      // ceil32(435)
#define LD 512
#define INNER 600
#define INNERP 608   // ceil32(600)
#define FFD 2048
#define NL 128
#define OC 64
#define DEPTH 5
#define HEADS 8
#define DH 75
#define DHP 96       // ceil32(75)
#define BK 32

static __device__ __forceinline__ u16 f2bf(float f) {
    unsigned x = __float_as_uint(f);
    unsigned r = (x + 0x7fffu + ((x >> 16) & 1u)) >> 16;
    return (u16)r;
}
static __device__ __forceinline__ float bf2f(u16 v) {
    return __uint_as_float(((unsigned)v) << 16);
}
static __device__ __forceinline__ void gload_lds16(const u16* g, u16* l) {
    __builtin_amdgcn_global_load_lds(
        (const __attribute__((address_space(1))) unsigned int*)g,
        (__attribute__((address_space(3))) unsigned int*)l, 16, 0, 0);
}

// ---------------------------------------------------------------------------
__global__ __launch_bounds__(256) void mask_kernel(const float* __restrict__ input,
                                                   unsigned char* __restrict__ mask) {
    int idx = blockIdx.x * 256 + threadIdx.x;
    if (idx >= BATCH * NVOX) return;
    int b = idx >> 13, i = idx & (NVOX - 1);
    int tt = i & 7, wx = (i >> 3) & 31, hy = i >> 8;
    float mx = -3.4e38f;
    for (int ch = 0; ch < PC; ++ch) {
        int py = ch / 12, px = (ch / 3) & 3, cc = ch % 3;
        float v = input[((size_t)((tt * BATCH + b) * CIN + cc) << 14) +
                        (hy * 4 + py) * WIMG + (wx * 4 + px)];
        mx = fmaxf(mx, v);
    }
    mask[idx] = (fabsf(mx) > 0.3f) ? 1 : 0;
}

__global__ __launch_bounds__(64) void compact_kernel(const unsigned char* __restrict__ mask,
                                                     int* __restrict__ perm,
                                                     int* __restrict__ Kc) {
    int b = blockIdx.x, lane = threadIdx.x;
    int offs = 0;
    for (int c = 0; c < NVOX / 64; ++c) {
        int i = c * 64 + lane;
        int m = mask[(b << 13) + i];
        unsigned long long bal = __ballot(m != 0);
        int excl = __popcll(bal & ((1ull << lane) - 1ull));
        if (m) perm[(b << 13) + offs + excl] = i;
        offs += __popcll(bal);
    }
    if (lane == 0) Kc[b] = offs;
}

// build normalized data rows (bf16, ld IDP) for 2 batches b0,b0+1
__global__ __launch_bounds__(256) void build_data2(const float* __restrict__ input,
                                                   const int* __restrict__ perm,
                                                   const int* __restrict__ Kc,
                                                   u16* __restrict__ normed, int b0) {
    int blk = blockIdx.x;
    int b2 = blk >> 13, r = blk & (NVOX - 1);
    int b = b0 + b2;
    int tid = threadIdx.x;
    u16* out = normed + (size_t)blk * IDP;
    int Kb = Kc[b];
    if (r >= Kb) {
        for (int e = tid; e < IDP; e += 256) out[e] = 0;
        return;
    }
    __shared__ float row[IDP];
    __shared__ float red[256];
    int i = perm[(b << 13) + r];
    int tt = i & 7, wx = (i >> 3) & 31, hy = i >> 8;
    float pos0 = 2.f * hy / 32.f - 1.f;
    float pos1 = 2.f * wx / 32.f - 1.f;
    float pos2 = 2.f * tt / 8.f - 1.f;
    for (int e = tid; e < IDP; e += 256) {
        float v = 0.f;
        if (e < PC) {
            int py = e / 12, px = (e / 3) & 3, cc = e % 3;
            v = input[((size_t)((tt * BATCH + b) * CIN + cc) << 14) +
                      (hy * 4 + py) * WIMG + (wx * 4 + px)];
        } else if (e < ID) {
            int e2 = e - PC;
            int dim = e2 / 129, rem = e2 - dim * 129;
            float pp = (dim == 0) ? pos0 : (dim == 1 ? pos1 : pos2);
            if (rem < 64)       v = sinf(ldexpf(pp, -rem));
            else if (rem < 128) v = cosf(ldexpf(pp, -(rem - 64)));
            else                v = pp;
        }
        row[e] = v;
    }
    __syncthreads();
    float ss = 0.f;
    for (int e = tid; e < ID; e += 256) ss += row[e] * row[e];
    red[tid] = ss; __syncthreads();
    for (int s = 128; s > 0; s >>= 1) { if (tid < s) red[tid] += red[tid + s]; __syncthreads(); }
    float scale = 1.f / fmaxf(sqrtf(red[0]), 1e-5f);
    for (int e = tid; e < IDP; e += 256) out[e] = f2bf(row[e] * scale);
}

__global__ __launch_bounds__(256) void lat_init(const float* __restrict__ latents,
                                                const float* __restrict__ pos_emb,
                                                float* __restrict__ lat) {
    int idx = blockIdx.x * 256 + threadIdx.x;
    if (idx >= BATCH * NL * LD) return;
    int rem = idx & (NL * LD - 1);
    lat[idx] = latents[rem] + pos_emb[rem];
}

__global__ __launch_bounds__(256) void scale_norm_bf(const float* __restrict__ x,
                                                     u16* __restrict__ o,
                                                     const float* __restrict__ g, int gi,
                                                     int cols) {
    int rowi = blockIdx.x, tid = threadIdx.x;
    const float* xr = x + (size_t)rowi * cols;
    u16* orow = o + (size_t)rowi * cols;
    __shared__ float red[256];
    float ss = 0.f;
    for (int c = tid; c < cols; c += 256) { float v = xr[c]; ss += v * v; }
    red[tid] = ss; __syncthreads();
    for (int s = 128; s > 0; s >>= 1) { if (tid < s) red[tid] += red[tid + s]; __syncthreads(); }
    float scale = g[gi] / fmaxf(sqrtf(red[0]), 1e-5f);
    for (int c = tid; c < cols; c += 256) orow[c] = f2bf(xr[c] * scale);
}

__global__ __launch_bounds__(256) void fill_kernel(float* __restrict__ p, long long n, float v) {
    long long idx = (long long)blockIdx.x * 256 + threadIdx.x;
    if (idx < n) p[idx] = v;
}

__global__ __launch_bounds__(256) void addbias_kernel(float* __restrict__ d,
                                                      const float* __restrict__ bias,
                                                      long long total, int n) {
    long long idx = (long long)blockIdx.x * 256 + threadIdx.x;
    if (idx < total) d[idx] += bias[idx % n];
}

// gelu(bf16 + bias) in place
__global__ __launch_bounds__(256) void biasgelu_u16(u16* __restrict__ d,
                                                    const float* __restrict__ bias,
                                                    long long total, int n) {
    long long idx = (long long)blockIdx.x * 256 + threadIdx.x;
    if (idx < total) {
        float v = bf2f(d[idx]) + bias[idx % n];
        d[idx] = f2bf(0.5f * v * (1.f + erff(v * 0.70710678118654752f)));
    }
}

// fp32 (rows x sc) -> bf16 (rows x dc), zero pad cols
__global__ __launch_bounds__(256) void pad_conv(const float* __restrict__ src, u16* __restrict__ dst,
                                                int rows, int sc, int dc) {
    int idx = blockIdx.x * 256 + threadIdx.x;
    if (idx >= rows * dc) return;
    int r = idx / dc, c = idx - r * dc;
    dst[idx] = f2bf(c < sc ? src[(size_t)r * sc + c] : 0.f);
}

__global__ __launch_bounds__(256) void conv_bf(const float* __restrict__ src, u16* __restrict__ dst, int n) {
    int idx = blockIdx.x * 256 + threadIdx.x;
    if (idx < n) dst[idx] = f2bf(src[idx]);
}

// transpose fp32 (R x C) -> bf16 (C x Rp), Rp=ceil32(R), zero pad
__global__ __launch_bounds__(256) void transpose_conv(const float* __restrict__ src, u16* __restrict__ dst,
                                                      int R, int C, int Rp) {
    __shared__ float t[32][33];
    int bx = blockIdx.x * 32, by = blockIdx.y * 32;
    int tx = threadIdx.x & 31, ty = threadIdx.x >> 5;
#pragma unroll
    for (int p = 0; p < 4; ++p) {
        int r = bx + ty + p * 8, c = by + tx;
        t[ty + p * 8][tx] = (r < R && c < C) ? src[(size_t)r * C + c] : 0.f;
    }
    __syncthreads();
#pragma unroll
    for (int p = 0; p < 4; ++p) {
        int c = by + ty + p * 8, r = bx + tx;
        if (c < C && r < Rp) dst[(size_t)c * Rp + r] = f2bf(t[tx][ty + p * 8]);
    }
}

// u16 (BATCH*128 x srcld) head-split -> bf16 (b*8+h, 128, DHP) zero-padded
__global__ __launch_bounds__(256) void pack_heads_u16(const u16* __restrict__ src, u16* __restrict__ dst,
                                                      int srcld) {
    int idx = blockIdx.x * 256 + threadIdx.x;
    if (idx >= BATCH * HEADS * NL * DHP) return;
    int dd = idx % DHP;
    int l = (idx / DHP) & (NL - 1);
    int bh = idx / (DHP * NL);
    int b = bh >> 3, h = bh & 7;
    dst[idx] = (dd < DH) ? src[(size_t)(b * NL + l) * srcld + h * DH + dd] : 0;
}

// kvself_bf u16 -> vs_t (b*8+h, DH, 128)
__global__ __launch_bounds__(256) void pack_vt_self(const u16* __restrict__ kvs, u16* __restrict__ vt) {
    int idx = blockIdx.x * 256 + threadIdx.x;
    if (idx >= BATCH * HEADS * DH * NL) return;
    int l = idx & (NL - 1);
    int dd = (idx >> 7) % DH;
    int bh = idx / (DH * NL);
    int b = bh >> 3, h = bh & 7;
    vt[idx] = kvs[(size_t)(b * NL + l) * (2 * INNER) + INNER + h * DH + dd];
}

// masked softmax on bf16 in place
__global__ __launch_bounds__(256) void softmax_u16(u16* __restrict__ S, int cols,
                                                   const int* __restrict__ Kc, int b0,
                                                   int rows_per_b) {
    int rowi = blockIdx.x, tid = threadIdx.x;
    u16* p = S + (size_t)rowi * cols;
    int lim = Kc ? Kc[b0 + rowi / rows_per_b] : cols;
    __shared__ float red[256];
    if (lim <= 0) { for (int j = tid; j < cols; j += 256) p[j] = 0; return; }
    float v[32];
    int nit = (lim + 255) >> 8;
    float mx = -3.4e38f;
    for (int s = 0; s < nit; ++s) {
        int j = s * 256 + tid;
        float x = (j < lim) ? bf2f(p[j]) : -3.4e38f;
        v[s] = x;
        mx = fmaxf(mx, x);
    }
    red[tid] = mx; __syncthreads();
    for (int s = 128; s > 0; s >>= 1) { if (tid < s) red[tid] = fmaxf(red[tid], red[tid + s]); __syncthreads(); }
    mx = red[0]; __syncthreads();
    float sum = 0.f;
    for (int s = 0; s < nit; ++s) {
        int j = s * 256 + tid;
        float e = (j < lim) ? expf(v[s] - mx) : 0.f;
        v[s] = e; sum += e;
    }
    red[tid] = sum; __syncthreads();
    for (int s = 128; s > 0; s >>= 1) { if (tid < s) red[tid] += red[tid + s]; __syncthreads(); }
    float inv = (red[0] > 0.f) ? 1.f / red[0] : 0.f;
    int nco = (cols + 255) >> 8;
    for (int s = 0; s < nco; ++s) {
        int j = s * 256 + tid;
        if (j < cols) p[j] = f2bf((s < nit && j < lim) ? v[s] * inv : 0.f);
    }
}

// ---------------------------------------------------------------------------
// bf16 MFMA GEMM with global_load_lds staging. D = alpha * A @ B^T_layout.
// A: M x K bf16 (lda), M % 128 == 0. B: N x K bf16 (ldb); rows past N must be
// readable (garbage ok, columns discarded). K % 32 == 0, all bases/lds 16B ok.
// modes: 0 = f32 store, 1 = f32 atomicAdd, 2 = bf16 store,
//        3 = ctx-KV scatter (kdst (b2*8+h,vox,DHP), vdst (b2*8+h,dd,vox))
__global__ __launch_bounds__(256) void gemm_bf16(
    const u16* __restrict__ A, const u16* __restrict__ B, void* __restrict__ Dv,
    const float* __restrict__ alphaPtr, int alphaIdx, float alphaConst,
    int M, int N, int K, int lda, int ldb, int ldd, int nh,
    ll sAo, ll sAi, ll sBo, ll sBi, ll sDo, ll sDi,
    int splitK, int mode, u16* __restrict__ kdst, u16* __restrict__ vdst) {
    __shared__ __align__(16) u16 As[128 * BK];
    __shared__ __align__(16) u16 Bs[128 * BK];
    const int tid = threadIdx.x;
    int zb = blockIdx.z / splitK, kc = blockIdx.z - zb * splitK;
    int zo = zb / nh, zi = zb - zo * nh;
    const u16* Ab = A + (size_t)zo * sAo + (size_t)zi * sAi;
    const u16* Bb = B + (size_t)zo * sBo + (size_t)zi * sBi;
    const int bm = blockIdx.x * 128, bn = blockIdx.y * 128;
    int nk = K >> 5;
    int per = (nk + splitK - 1) / splitK;
    int k0 = kc * per * BK;
    int k1 = min(K, k0 + per * BK);

    const int wv = tid >> 6, lane = tid & 63;
    const int wm = (wv & 1) << 6, wn = (wv >> 1) << 6;
    const int fr = lane & 15, fc = lane >> 4;
    f32x4 acc[4][4] = {};

    const int lr = lane >> 2, lc = (lane & 3) << 3;
    const u16* ga0 = Ab + (size_t)(bm + wv * 16 + lr) * lda + k0 + lc;
    const u16* ga1 = ga0 + (size_t)64 * lda;
    const u16* gb0 = Bb + (size_t)(bn + wv * 16 + lr) * ldb + k0 + lc;
    const u16* gb1 = gb0 + (size_t)64 * ldb;
    u16* la0 = As + (wv * 16) * BK;
    u16* la1 = As + (wv * 16 + 64) * BK;
    u16* lb0 = Bs + (wv * 16) * BK;
    u16* lb1 = Bs + (wv * 16 + 64) * BK;

    for (int kb = k0; kb < k1; kb += BK) {
        gload_lds16(ga0, la0);
        gload_lds16(ga1, la1);
        gload_lds16(gb0, lb0);
        gload_lds16(gb1, lb1);
        ga0 += BK; ga1 += BK; gb0 += BK; gb1 += BK;
        __syncthreads();
        short8 af[4], bfr[4];
#pragma unroll
        for (int i = 0; i < 4; ++i)
            af[i] = *(const short8*)(As + (wm + i * 16 + fr) * BK + fc * 8);
#pragma unroll
        for (int j = 0; j < 4; ++j)
            bfr[j] = *(const short8*)(Bs + (wn + j * 16 + fr) * BK + fc * 8);
#pragma unroll
        for (int i = 0; i < 4; ++i)
#pragma unroll
            for (int j = 0; j < 4; ++j)
                acc[i][j] = __builtin_amdgcn_mfma_f32_16x16x32_bf16(af[i], bfr[j], acc[i][j], 0, 0, 0);
        __syncthreads();
    }
    float alpha = alphaConst * (alphaPtr ? alphaPtr[alphaIdx] : 1.f);
    if (mode == 3) {
#pragma unroll
        for (int i = 0; i < 4; ++i) {
#pragma unroll
            for (int j = 0; j < 4; ++j) {
                int gn = bn + wn + j * 16 + fr;
                if (gn >= 2 * INNER) continue;
                int isV = gn >= INNER;
                int gnn = isV ? gn - INNER : gn;
                int h = gnn / DH, dd = gnn - h * DH;
                int gm0 = bm + wm + i * 16 + fc * 4;
#pragma unroll
                for (int r = 0; r < 4; ++r) {
                    int gm = gm0 + r;
                    int b2 = gm >> 13, vox = gm & (NVOX - 1);
                    u16 v = f2bf(acc[i][j][r] * alpha);
                    if (!isV) kdst[(((size_t)(b2 * 8 + h)) * NVOX + vox) * DHP + dd] = v;
                    else      vdst[((size_t)(b2 * 8 + h) * DH + dd) * NVOX + vox] = v;
                }
            }
        }
        return;
    }
    float* Db = (float*)Dv + (size_t)zo * sDo + (size_t)zi * sDi;
    u16* Du = (u16*)Dv + (size_t)zo * sDo + (size_t)zi * sDi;
#pragma unroll
    for (int i = 0; i < 4; ++i) {
#pragma unroll
        for (int j = 0; j < 4; ++j) {
            int gn = bn + wn + j * 16 + fr;
            if (gn >= N) continue;
            int gm0 = bm + wm + i * 16 + fc * 4;
#pragma unroll
            for (int r = 0; r < 4; ++r) {
                int gm = gm0 + r;
                if (gm >= M) continue;
                float v = acc[i][j][r] * alpha;
                size_t di = (size_t)gm * ldd + gn;
                if (mode == 2)      Du[di] = f2bf(v);
                else if (mode == 1) atomicAdd(&Db[di], v);
                else                Db[di] = v;
            }
        }
    }
}

// final permute: outtmp (b,128,64) -> d_out (t,b,n,64), latent = n*8 + t
__global__ __launch_bounds__(256) void reorder_kernel(const float* __restrict__ outtmp,
                                                      float* __restrict__ out) {
    int idx = blockIdx.x * 256 + threadIdx.x;
    if (idx >= TBINS * BATCH * (NL / TBINS) * OC) return;
    int oc = idx & 63, n = (idx >> 6) & 15, b = (idx >> 10) & 3, t = idx >> 12;
    out[idx] = outtmp[((size_t)(b * NL + n * TBINS + t)) * OC + oc];
}

// ---------------------------------------------------------------------------
extern "C" void kernel_launch(void* const* d_in, const int* in_sizes, int n_in,
                              void* d_out, int out_size, void* d_ws, size_t ws_size,
                              hipStream_t stream) {
    const float* input    = (const float*)d_in[0];
    const float* latents  = (const float*)d_in[1];
    const float* pos_emb  = (const float*)d_in[2];
    const float* ca_g     = (const float*)d_in[3];
    const float* ca_ctx_g = (const float*)d_in[4];
    const float* ca_q     = (const float*)d_in[5];
    const float* ca_kv    = (const float*)d_in[6];
    const float* ca_ow    = (const float*)d_in[7];
    const float* ca_ob    = (const float*)d_in[8];
    const float* cf_g     = (const float*)d_in[9];
    const float* cf_w1    = (const float*)d_in[10];
    const float* cf_b1    = (const float*)d_in[11];
    const float* cf_w2    = (const float*)d_in[12];
    const float* cf_b2    = (const float*)d_in[13];
    const float* la_g     = (const float*)d_in[14];
    const float* la_q     = (const float*)d_in[15];
    const float* la_kv    = (const float*)d_in[16];
    const float* la_ow    = (const float*)d_in[17];
    const float* la_ob    = (const float*)d_in[18];
    const float* lf_g     = (const float*)d_in[19];
    const float* lf_w1    = (const float*)d_in[20];
    const float* lf_b1    = (const float*)d_in[21];
    const float* lf_w2    = (const float*)d_in[22];
    const float* lf_b2    = (const float*)d_in[23];
    const float* logits_w = (const float*)d_in[24];
    const float* logits_b = (const float*)d_in[25];
    float* out = (float*)d_out;
    (void)ws_size; (void)n_in; (void)in_sizes; (void)out_size;

    // workspace carve (~105 MB)
    char* w = (char*)d_ws;
    auto alloc = [&](size_t bytes) { void* p = (void*)w; w += (bytes + 255) & ~(size_t)255; return p; };
    int* perm        = (int*)alloc((size_t)BATCH * NVOX * 4);
    int* Kc          = (int*)alloc(64);
    unsigned char* mask = (unsigned char*)alloc((size_t)BATCH * NVOX);
    float* lat       = (float*)alloc((size_t)BATCH * NL * LD * 4);
    u16* latn_bf     = (u16*)alloc((size_t)BATCH * NL * LD * 2);
    u16* qg_bf       = (u16*)alloc((size_t)BATCH * NL * INNER * 2);
    float* attn      = (float*)alloc((size_t)BATCH * NL * INNER * 4);
    u16* attn_bf     = (u16*)alloc((size_t)BATCH * NL * INNERP * 2);
    u16* ffb_bf      = (u16*)alloc((size_t)BATCH * NL * FFD * 2);
    u16* kvself_bf   = (u16*)alloc((size_t)BATCH * NL * 2 * INNER * 2);
    float* outtmp    = (float*)alloc((size_t)BATCH * NL * OC * 4);
    u16* q_bf        = (u16*)alloc((size_t)BATCH * HEADS * NL * DHP * 2);
    u16* ks_bf       = (u16*)alloc((size_t)BATCH * HEADS * NL * DHP * 2);
    u16* vs_t        = (u16*)alloc((size_t)BATCH * HEADS * DH * NL * 2);
    alloc(64 * 1024);  // pad: B over-read slack behind vs_t
    // per-layer transposed bf16 weights
    u16* wq_t   = (u16*)alloc((size_t)INNER * LD * 2);
    u16* wkv_t  = (u16*)alloc((size_t)2 * INNER * IDP * 2);
    u16* wow_t  = (u16*)alloc((size_t)LD * INNERP * 2);
    u16* wf1_t  = (u16*)alloc((size_t)FFD * LD * 2);
    u16* wf2_t  = (u16*)alloc((size_t)LD * FFD * 2);
    u16* wlq_t  = (u16*)alloc((size_t)INNER * LD * 2);
    u16* wlkv_t = (u16*)alloc((size_t)2 * INNER * LD * 2);
    u16* wlow_t = (u16*)alloc((size_t)LD * INNERP * 2);
    u16* wlf1_t = (u16*)alloc((size_t)FFD * LD * 2);
    u16* wlf2_t = (u16*)alloc((size_t)LD * FFD * 2);
    u16* wlog_t = (u16*)alloc((size_t)OC * LD * 2);
    // E: union region — normed2 (2*8192*448 bf16 = 14.7 MB) / ctx S (16*128*8192 bf16 = 33.6 MB) / self S (1 MB)
    u16* E      = (u16*)alloc((size_t)16 * NL * NVOX * 2);            // 33.6 MB
    u16* k_bf   = (u16*)alloc((size_t)16 * NVOX * DHP * 2);           // 25.2 MB
    u16* v_t    = (u16*)alloc((size_t)16 * DH * NVOX * 2);            // 19.7 MB
    alloc((size_t)1 * 1024 * 1024);  // pad: v_t N=75 over-read slack

    const float scaleS = 1.0f / sqrtf((float)DH);
    const int M4 = BATCH * NL;

    auto G = [&](const u16* A, const u16* B, void* D, const float* aP, int aI, float aC,
                 int M, int N, int K, int lda, int ldb, int ldd, int nh, int nb,
                 ll sAo, ll sAi, ll sBo, ll sBi, ll sDo, ll sDi,
                 int splitK, int mode, u16* kd = nullptr, u16* vd = nullptr) {
        dim3 g((M + 127) / 128, (N + 127) / 128, nb * splitK);
        hipLaunchKernelGGL(gemm_bf16, g, dim3(256), 0, stream, A, B, D, aP, aI, aC,
                           M, N, K, lda, ldb, ldd, nh, sAo, sAi, sBo, sBi, sDo, sDi,
                           splitK, mode, kd, vd);
    };
    auto TT = [&](const float* src, u16* dst, int R, int C, int Rp) {
        hipLaunchKernelGGL(transpose_conv, dim3(Rp / 32, (C + 31) / 32), dim3(256), 0, stream,
                           src, dst, R, C, Rp);
    };

    hipLaunchKernelGGL(mask_kernel, dim3((BATCH * NVOX + 255) / 256), dim3(256), 0, stream, input, mask);
    hipLaunchKernelGGL(compact_kernel, dim3(BATCH), dim3(64), 0, stream, mask, perm, Kc);
    hipLaunchKernelGGL(lat_init, dim3((BATCH * NL * LD + 255) / 256), dim3(256), 0, stream, latents, pos_emb, lat);
    // zero k_bf once (pads dd in [75,96) stay zero; dd<75 rewritten every stage)
    hipLaunchKernelGGL(fill_kernel, dim3(((16 * NVOX * DHP / 2) + 255) / 256), dim3(256), 0, stream,
                       (float*)k_bf, (long long)(16 * NVOX * DHP / 2), 0.f);

    for (int d = 0; d < DEPTH; ++d) {
        TT(ca_q  + (size_t)d * LD * INNER,      wq_t,   LD, INNER, LD);
        TT(ca_kv + (size_t)d * ID * 2 * INNER,  wkv_t,  ID, 2 * INNER, IDP);
        TT(ca_ow + (size_t)d * INNER * LD,      wow_t,  INNER, LD, INNERP);
        TT(cf_w1 + (size_t)d * LD * FFD,        wf1_t,  LD, FFD, LD);
        TT(cf_w2 + (size_t)d * FFD * LD,        wf2_t,  FFD, LD, FFD);
        TT(la_q  + (size_t)d * LD * INNER,      wlq_t,  LD, INNER, LD);
        TT(la_kv + (size_t)d * LD * 2 * INNER,  wlkv_t, LD, 2 * INNER, LD);
        TT(la_ow + (size_t)d * INNER * LD,      wlow_t, INNER, LD, INNERP);
        TT(lf_w1 + (size_t)d * LD * FFD,        wlf1_t, LD, FFD, LD);
        TT(lf_w2 + (size_t)d * FFD * LD,        wlf2_t, FFD, LD, FFD);

        // ---- cross attention ----
        hipLaunchKernelGGL(scale_norm_bf, dim3(M4), dim3(256), 0, stream, lat, latn_bf, ca_g, d, LD);
        G(latn_bf, wq_t, qg_bf, nullptr, 0, 1.f, M4, INNER, LD, LD, LD, INNER, 1, 1,
          0, 0, 0, 0, 0, 0, 1, 2);
        hipLaunchKernelGGL(pack_heads_u16, dim3((BATCH * HEADS * NL * DHP + 255) / 256), dim3(256), 0, stream,
                           qg_bf, q_bf, INNER);
        hipLaunchKernelGGL(fill_kernel, dim3((M4 * INNER + 255) / 256), dim3(256), 0, stream,
                           attn, (long long)M4 * INNER, 0.f);
        for (int hf = 0; hf < 2; ++hf) {
            hipLaunchKernelGGL(build_data2, dim3(2 * NVOX), dim3(256), 0, stream, input, perm, Kc, E, hf * 2);
            // KV projection: 16384 x 1200, scatter into k_bf / v_t
            G(E, wkv_t, nullptr, ca_ctx_g, d, 1.f, 2 * NVOX, 2 * INNER, IDP, IDP, IDP, 0, 1, 1,
              0, 0, 0, 0, 0, 0, 1, 3, k_bf, v_t);
            // S = q k^T * scale -> bf16 into E   (z = b2*8+h, 16)
            G(q_bf + (size_t)hf * 2 * HEADS * NL * DHP, k_bf, E, nullptr, 0, scaleS,
              NL, NVOX, DHP, DHP, DHP, NVOX, 16, 16,
              0, (ll)NL * DHP, 0, (ll)NVOX * DHP, 0, (ll)NL * NVOX, 1, 2);
            hipLaunchKernelGGL(softmax_u16, dim3(16 * NL), dim3(256), 0, stream,
                               E, NVOX, Kc, hf * 2, HEADS * NL);
            // attn += S @ V   (z = (b2, h), atomic fp32, splitK 8)
            G(E, v_t, attn + (size_t)hf * 2 * NL * INNER, nullptr, 0, 1.f,
              NL, DH, NVOX, NVOX, NVOX, INNER, 8, 16,
              (ll)HEADS * NL * NVOX, (ll)NL * NVOX, (ll)HEADS * DH * NVOX, (ll)DH * NVOX,
              (ll)NL * INNER, DH, 8, 1);
        }
        hipLaunchKernelGGL(addbias_kernel, dim3((M4 * LD + 255) / 256), dim3(256), 0, stream,
                           lat, ca_ob + (size_t)d * LD, (long long)M4 * LD, LD);
        hipLaunchKernelGGL(pad_conv, dim3((M4 * INNERP + 255) / 256), dim3(256), 0, stream,
                           attn, attn_bf, M4, INNER, INNERP);
        G(attn_bf, wow_t, lat, nullptr, 0, 1.f, M4, LD, INNERP, INNERP, INNERP, LD, 1, 1,
          0, 0, 0, 0, 0, 0, 2, 1);

        // ---- FF (cf) ----
        hipLaunchKernelGGL(scale_norm_bf, dim3(M4), dim3(256), 0, stream, lat, latn_bf, cf_g, d, LD);
        G(latn_bf, wf1_t, ffb_bf, nullptr, 0, 1.f, M4, FFD, LD, LD, LD, FFD, 1, 1,
          0, 0, 0, 0, 0, 0, 1, 2);
        hipLaunchKernelGGL(biasgelu_u16, dim3((M4 * FFD + 255) / 256), dim3(256), 0, stream,
                           ffb_bf, cf_b1 + (size_t)d * FFD, (long long)M4 * FFD, FFD);
        hipLaunchKernelGGL(addbias_kernel, dim3((M4 * LD + 255) / 256), dim3(256), 0, stream,
                           lat, cf_b2 + (size_t)d * LD, (long long)M4 * LD, LD);
        G(ffb_bf, wf2_t, lat, nullptr, 0, 1.f, M4, LD, FFD, FFD, FFD, LD, 1, 1,
          0, 0, 0, 0, 0, 0, 8, 1);

        // ---- latent self attention ----
        hipLaunchKernelGGL(scale_norm_bf, dim3(M4), dim3(256), 0, stream, lat, latn_bf, la_g, d, LD);
        G(latn_bf, wlq_t, qg_bf, nullptr, 0, 1.f, M4, INNER, LD, LD, LD, INNER, 1, 1,
          0, 0, 0, 0, 0, 0, 1, 2);
        G(latn_bf, wlkv_t, kvself_bf, nullptr, 0, 1.f, M4, 2 * INNER, LD, LD, LD, 2 * INNER, 1, 1,
          0, 0, 0, 0, 0, 0, 1, 2);
        hipLaunchKernelGGL(pack_heads_u16, dim3((BATCH * HEADS * NL * DHP + 255) / 256), dim3(256), 0, stream,
                           qg_bf, q_bf, INNER);
        hipLaunchKernelGGL(pack_heads_u16, dim3((BATCH * HEADS * NL * DHP + 255) / 256), dim3(256), 0, stream,
                           kvself_bf, ks_bf, 2 * INNER);
        hipLaunchKernelGGL(pack_vt_self, dim3((BATCH * HEADS * DH * NL + 255) / 256), dim3(256), 0, stream,
                           kvself_bf, vs_t);
        G(q_bf, ks_bf, E, nullptr, 0, scaleS, NL, NL, DHP, DHP, DHP, NL, 32, 32,
          0, (ll)NL * DHP, 0, (ll)NL * DHP, 0, (ll)NL * NL, 1, 2);
        hipLaunchKernelGGL(softmax_u16, dim3(BATCH * HEADS * NL), dim3(256), 0, stream,
                           E, NL, (const int*)nullptr, 0, HEADS * NL);
        G(E, vs_t, attn, nullptr, 0, 1.f, NL, DH, NL, NL, NL, INNER, 8, 32,
          (ll)HEADS * NL * NL, (ll)NL * NL, (ll)HEADS * DH * NL, (ll)DH * NL,
          (ll)NL * INNER, DH, 1, 0);
        hipLaunchKernelGGL(addbias_kernel, dim3((M4 * LD + 255) / 256), dim3(256), 0, stream,
                           lat, la_ob + (size_t)d * LD, (long long)M4 * LD, LD);
        hipLaunchKernelGGL(pad_conv, dim3((M4 * INNERP + 255) / 256), dim3(256), 0, stream,
                           attn, attn_bf, M4, INNER, INNERP);
        G(attn_bf, wlow_t, lat, nullptr, 0, 1.f, M4, LD, INNERP, INNERP, INNERP, LD, 1, 1,
          0, 0, 0, 0, 0, 0, 2, 1);

        // ---- FF (lf) ----
        hipLaunchKernelGGL(scale_norm_bf, dim3(M4), dim3(256), 0, stream, lat, latn_bf, lf_g, d, LD);
        G(latn_bf, wlf1_t, ffb_bf, nullptr, 0, 1.f, M4, FFD, LD, LD, LD, FFD, 1, 1,
          0, 0, 0, 0, 0, 0, 1, 2);
        hipLaunchKernelGGL(biasgelu_u16, dim3((M4 * FFD + 255) / 256), dim3(256), 0, stream,
                           ffb_bf, lf_b1 + (size_t)d * FFD, (long long)M4 * FFD, FFD);
        hipLaunchKernelGGL(addbias_kernel, dim3((M4 * LD + 255) / 256), dim3(256), 0, stream,
                           lat, lf_b2 + (size_t)d * LD, (long long)M4 * LD, LD);
        G(ffb_bf, wlf2_t, lat, nullptr, 0, 1.f, M4, LD, FFD, FFD, FFD, LD, 1, 1,
          0, 0, 0, 0, 0, 0, 8, 1);
    }

    // logits + reorder
    TT(logits_w, wlog_t, LD, OC, LD);
    hipLaunchKernelGGL(conv_bf, dim3((M4 * LD + 255) / 256), dim3(256), 0, stream, lat, latn_bf, M4 * LD);
    hipLaunchKernelGGL(fill_kernel, dim3((M4 * OC + 255) / 256), dim3(256), 0, stream,
                       outtmp, (long long)M4 * OC, 0.f);
    G(latn_bf, wlog_t, outtmp, nullptr, 0, 1.f, M4, OC, LD, LD, LD, OC, 1, 1,
      0, 0, 0, 0, 0, 0, 4, 1);
    hipLaunchKernelGGL(addbias_kernel, dim3((M4 * OC + 255) / 256), dim3(256), 0, stream,
                       outtmp, logits_b, (long long)M4 * OC, OC);
    hipLaunchKernelGGL(reorder_kernel, dim3((TBINS * BATCH * (NL / TBINS) * OC + 255) / 256), dim3(256), 0,
                       stream, outtmp, out);
}

// Round 5
// 2836.360 us; speedup vs baseline: 4.1464x; 1.1505x over previous
//
#include <hip/hip_runtime.h>
#include <math.h>

typedef unsigned short u16;
typedef long long ll;
typedef __attribute__((ext_vector_type(8))) short short8;
typedef __attribute__((ext_vector_type(4))) float f32x4;

// Problem constants
#define TBINS 8
#define BATCH 4
#define CIN 3
#define WIMG 128
#define PC 48
#define NVOX 8192
#define ID 435
#define IDP 448      // ceil32(435)
#define LD 512
#define INNER 600
#define INNERP 608   // ceil32(600)
#define FFD 2048
#define NL 128
#define OC 64
#define DEPTH 5
#define HEADS 8
#define DH 75
#define DHP 96       // ceil32(75)
#define BK 32
#define SVSPLIT 16   // cross S@V split-K chunks

static __device__ __forceinline__ u16 f2bf(float f) {
    unsigned x = __float_as_uint(f);
    unsigned r = (x + 0x7fffu + ((x >> 16) & 1u)) >> 16;
    return (u16)r;
}
static __device__ __forceinline__ float bf2f(u16 v) {
    return __uint_as_float(((unsigned)v) << 16);
}
static __device__ __forceinline__ void gload_lds16(const u16* g, u16* l) {
    __builtin_amdgcn_global_load_lds(
        (const __attribute__((address_space(1))) unsigned int*)g,
        (__attribute__((address_space(3))) unsigned int*)l, 16, 0, 0);
}

// ---------------------------------------------------------------------------
__global__ __launch_bounds__(256) void mask_kernel(const float* __restrict__ input,
                                                   unsigned char* __restrict__ mask) {
    int idx = blockIdx.x * 256 + threadIdx.x;
    if (idx >= BATCH * NVOX) return;
    int b = idx >> 13, i = idx & (NVOX - 1);
    int tt = i & 7, wx = (i >> 3) & 31, hy = i >> 8;
    float mx = -3.4e38f;
    for (int ch = 0; ch < PC; ++ch) {
        int py = ch / 12, px = (ch / 3) & 3, cc = ch % 3;
        float v = input[((size_t)((tt * BATCH + b) * CIN + cc) << 14) +
                        (hy * 4 + py) * WIMG + (wx * 4 + px)];
        mx = fmaxf(mx, v);
    }
    mask[idx] = (fabsf(mx) > 0.3f) ? 1 : 0;
}

__global__ __launch_bounds__(64) void compact_kernel(const unsigned char* __restrict__ mask,
                                                     int* __restrict__ perm,
                                                     int* __restrict__ Kc) {
    int b = blockIdx.x, lane = threadIdx.x;
    int offs = 0;
    for (int c = 0; c < NVOX / 64; ++c) {
        int i = c * 64 + lane;
        int m = mask[(b << 13) + i];
        unsigned long long bal = __ballot(m != 0);
        int excl = __popcll(bal & ((1ull << lane) - 1ull));
        if (m) perm[(b << 13) + offs + excl] = i;
        offs += __popcll(bal);
    }
    if (lane == 0) Kc[b] = offs;
}

// build normalized data rows (bf16, ld IDP) for ALL batches, one launch
__global__ __launch_bounds__(256) void build_all(const float* __restrict__ input,
                                                 const int* __restrict__ perm,
                                                 const int* __restrict__ Kc,
                                                 u16* __restrict__ normed) {
    int blk = blockIdx.x;             // b*8192 + r
    int b = blk >> 13, r = blk & (NVOX - 1);
    int tid = threadIdx.x;
    u16* out = normed + (size_t)blk * IDP;
    int Kb = Kc[b];
    if (r >= Kb) {
        for (int e = tid; e < IDP; e += 256) out[e] = 0;
        return;
    }
    __shared__ float row[IDP];
    __shared__ float red[256];
    int i = perm[(b << 13) + r];
    int tt = i & 7, wx = (i >> 3) & 31, hy = i >> 8;
    float pos0 = 2.f * hy / 32.f - 1.f;
    float pos1 = 2.f * wx / 32.f - 1.f;
    float pos2 = 2.f * tt / 8.f - 1.f;
    for (int e = tid; e < IDP; e += 256) {
        float v = 0.f;
        if (e < PC) {
            int py = e / 12, px = (e / 3) & 3, cc = e % 3;
            v = input[((size_t)((tt * BATCH + b) * CIN + cc) << 14) +
                      (hy * 4 + py) * WIMG + (wx * 4 + px)];
        } else if (e < ID) {
            int e2 = e - PC;
            int dim = e2 / 129, rem = e2 - dim * 129;
            float pp = (dim == 0) ? pos0 : (dim == 1 ? pos1 : pos2);
            if (rem < 64)       v = sinf(ldexpf(pp, -rem));
            else if (rem < 128) v = cosf(ldexpf(pp, -(rem - 64)));
            else                v = pp;
        }
        row[e] = v;
    }
    __syncthreads();
    float ss = 0.f;
    for (int e = tid; e < ID; e += 256) ss += row[e] * row[e];
    red[tid] = ss; __syncthreads();
    for (int s = 128; s > 0; s >>= 1) { if (tid < s) red[tid] += red[tid + s]; __syncthreads(); }
    float scale = 1.f / fmaxf(sqrtf(red[0]), 1e-5f);
    for (int e = tid; e < IDP; e += 256) out[e] = f2bf(row[e] * scale);
}

__global__ __launch_bounds__(256) void lat_init(const float* __restrict__ latents,
                                                const float* __restrict__ pos_emb,
                                                float* __restrict__ lat) {
    int idx = blockIdx.x * 256 + threadIdx.x;
    if (idx >= BATCH * NL * LD) return;
    int rem = idx & (NL * LD - 1);
    lat[idx] = latents[rem] + pos_emb[rem];
}

__global__ __launch_bounds__(256) void scale_norm_bf(const float* __restrict__ x,
                                                     u16* __restrict__ o,
                                                     const float* __restrict__ g, int gi,
                                                     int cols) {
    int rowi = blockIdx.x, tid = threadIdx.x;
    const float* xr = x + (size_t)rowi * cols;
    u16* orow = o + (size_t)rowi * cols;
    __shared__ float red[256];
    float ss = 0.f;
    for (int c = tid; c < cols; c += 256) { float v = xr[c]; ss += v * v; }
    red[tid] = ss; __syncthreads();
    for (int s = 128; s > 0; s >>= 1) { if (tid < s) red[tid] += red[tid + s]; __syncthreads(); }
    float scale = g[gi] / fmaxf(sqrtf(red[0]), 1e-5f);
    for (int c = tid; c < cols; c += 256) orow[c] = f2bf(xr[c] * scale);
}

__global__ __launch_bounds__(256) void fill_kernel(float* __restrict__ p, long long n, float v) {
    long long idx = (long long)blockIdx.x * 256 + threadIdx.x;
    if (idx < n) p[idx] = v;
}

__global__ __launch_bounds__(256) void conv_bf(const float* __restrict__ src, u16* __restrict__ dst, int n) {
    int idx = blockIdx.x * 256 + threadIdx.x;
    if (idx < n) dst[idx] = f2bf(src[idx]);
}

// batched transpose: fp32 (R x C) -> bf16 (C x Rp) per job; one launch
struct TJobs {
    const float* src[11];
    u16* dst[11];
    int R[11], C[11], Rp[11];
    int tstart[12];
    int njobs;
};
__global__ __launch_bounds__(256) void transpose_multi(TJobs J) {
    int bx = blockIdx.x;
    int j = 0;
    while (j + 1 < J.njobs && bx >= J.tstart[j + 1]) ++j;
    int lt = bx - J.tstart[j];
    int tilesX = J.Rp[j] >> 5;
    int tx = lt % tilesX, ty = lt / tilesX;
    const float* src = J.src[j];
    u16* dst = J.dst[j];
    int R = J.R[j], C = J.C[j], Rp = J.Rp[j];
    __shared__ float t[32][33];
    int bx0 = tx * 32, by0 = ty * 32;
    int ttx = threadIdx.x & 31, tty = threadIdx.x >> 5;
#pragma unroll
    for (int p = 0; p < 4; ++p) {
        int r = bx0 + tty + p * 8, c = by0 + ttx;
        t[tty + p * 8][ttx] = (r < R && c < C) ? src[(size_t)r * C + c] : 0.f;
    }
    __syncthreads();
#pragma unroll
    for (int p = 0; p < 4; ++p) {
        int c = by0 + tty + p * 8, r = bx0 + ttx;
        if (c < C && r < Rp) dst[(size_t)c * Rp + r] = f2bf(t[ttx][tty + p * 8]);
    }
}

// u16 (BATCH*128 x srcld) head-split -> bf16 (b*8+h, 128, DHP) zero-padded
__global__ __launch_bounds__(256) void pack_heads_u16(const u16* __restrict__ src, u16* __restrict__ dst,
                                                      int srcld) {
    int idx = blockIdx.x * 256 + threadIdx.x;
    if (idx >= BATCH * HEADS * NL * DHP) return;
    int dd = idx % DHP;
    int l = (idx / DHP) & (NL - 1);
    int bh = idx / (DHP * NL);
    int b = bh >> 3, h = bh & 7;
    dst[idx] = (dd < DH) ? src[(size_t)(b * NL + l) * srcld + h * DH + dd] : 0;
}

// split fused qkv (512 x 1800) into q_bf, ks_bf (bh,128,DHP) and vs_t (bh,DH,128)
__global__ __launch_bounds__(256) void pack3_self(const u16* __restrict__ qkv,
                                                  u16* __restrict__ qd, u16* __restrict__ kd,
                                                  u16* __restrict__ vd) {
    const int R0 = BATCH * HEADS * NL * DHP;          // 393216
    const int R2 = BATCH * HEADS * DH * NL;           // 307200
    int idx = blockIdx.x * 256 + threadIdx.x;
    if (idx < 2 * R0) {
        int which = idx >= R0;
        int k = which ? idx - R0 : idx;
        int dd = k % DHP;
        int l = (k / DHP) & (NL - 1);
        int bh = k / (DHP * NL);
        int b = bh >> 3, h = bh & 7;
        u16 v = 0;
        if (dd < DH) v = qkv[(size_t)(b * NL + l) * (3 * INNER) + which * INNER + h * DH + dd];
        (which ? kd : qd)[k] = v;
    } else if (idx < 2 * R0 + R2) {
        int k = idx - 2 * R0;
        int l = k & (NL - 1);
        int dd = (k >> 7) % DH;
        int bh = k / (DH * NL);
        int b = bh >> 3, h = bh & 7;
        vd[k] = qkv[(size_t)(b * NL + l) * (3 * INNER) + 2 * INNER + h * DH + dd];
    }
}

// masked softmax on bf16 in place
__global__ __launch_bounds__(256) void softmax_u16(u16* __restrict__ S, int cols,
                                                   const int* __restrict__ Kc, int b0,
                                                   int rows_per_b) {
    int rowi = blockIdx.x, tid = threadIdx.x;
    u16* p = S + (size_t)rowi * cols;
    int lim = Kc ? Kc[b0 + rowi / rows_per_b] : cols;
    __shared__ float red[256];
    if (lim <= 0) { for (int j = tid; j < cols; j += 256) p[j] = 0; return; }
    float v[32];
    int nit = (lim + 255) >> 8;
    float mx = -3.4e38f;
    for (int s = 0; s < nit; ++s) {
        int j = s * 256 + tid;
        float x = (j < lim) ? bf2f(p[j]) : -3.4e38f;
        v[s] = x;
        mx = fmaxf(mx, x);
    }
    red[tid] = mx; __syncthreads();
    for (int s = 128; s > 0; s >>= 1) { if (tid < s) red[tid] = fmaxf(red[tid], red[tid + s]); __syncthreads(); }
    mx = red[0]; __syncthreads();
    float sum = 0.f;
    for (int s = 0; s < nit; ++s) {
        int j = s * 256 + tid;
        float e = (j < lim) ? expf(v[s] - mx) : 0.f;
        v[s] = e; sum += e;
    }
    red[tid] = sum; __syncthreads();
    for (int s = 128; s > 0; s >>= 1) { if (tid < s) red[tid] += red[tid + s]; __syncthreads(); }
    float inv = (red[0] > 0.f) ? 1.f / red[0] : 0.f;
    int nco = (cols + 255) >> 8;
    for (int s = 0; s < nco; ++s) {
        int j = s * 256 + tid;
        if (j < cols) p[j] = f2bf((s < nit && j < lim) ? v[s] * inv : 0.f);
    }
}

// reduce cross S@V splitK partials -> attn_bf (512 x INNERP, bf16, pad-zeroed)
__global__ __launch_bounds__(256) void reduce_attn(const float* __restrict__ part,
                                                   u16* __restrict__ attn_bf) {
    int idx = blockIdx.x * 256 + threadIdx.x;
    if (idx >= BATCH * NL * INNERP) return;
    int c = idx % INNERP;
    int row = idx / INNERP;           // b*128 + l
    if (c >= INNER) { attn_bf[idx] = 0; return; }
    int b = row >> 7, l = row & 127;
    int h = c / DH, dd = c - h * DH;
    int hf = b >> 1, b2 = b & 1;
    const float* p = part + (size_t)hf * (SVSPLIT * 16 * NL * DH)
                   + (size_t)(b2 * 8 + h) * (NL * DH) + l * DH + dd;
    float s = 0.f;
    for (int kc = 0; kc < SVSPLIT; ++kc) s += p[(size_t)kc * (16 * NL * DH)];
    attn_bf[idx] = f2bf(s);
}

// ---------------------------------------------------------------------------
// bf16 MFMA GEMM with global_load_lds staging. D = alpha * A @ B^T_layout (+bias, act).
// A: M x K bf16 (lda), M % 128 == 0. B: N x K bf16 (ldb); rows past N must be readable.
// K % 32 == 0. modes: 0 = f32 store (Db += kc*sKp), 1 = f32 atomicAdd, 2 = bf16 store,
// 3 = ctx-KV scatter (kdst (b2*8+h,vox,DHP), vdst (b2*8+h,dd,vox)).
__global__ __launch_bounds__(256) void gemm_bf16(
    const u16* __restrict__ A, const u16* __restrict__ B, void* __restrict__ Dv,
    const float* __restrict__ alphaPtr, int alphaIdx, float alphaConst,
    int M, int N, int K, int lda, int ldb, int ldd, int nh,
    ll sAo, ll sAi, ll sBo, ll sBi, ll sDo, ll sDi,
    int splitK, int mode, const float* __restrict__ bias, float biasScale, int act,
    ll sKp, u16* __restrict__ kdst, u16* __restrict__ vdst) {
    __shared__ __align__(16) u16 As[128 * BK];
    __shared__ __align__(16) u16 Bs[128 * BK];
    const int tid = threadIdx.x;
    int zb = blockIdx.z / splitK, kc = blockIdx.z - zb * splitK;
    int zo = zb / nh, zi = zb - zo * nh;
    const u16* Ab = A + (size_t)zo * sAo + (size_t)zi * sAi;
    const u16* Bb = B + (size_t)zo * sBo + (size_t)zi * sBi;
    const int bm = blockIdx.x * 128, bn = blockIdx.y * 128;
    int nk = K >> 5;
    int per = (nk + splitK - 1) / splitK;
    int k0 = kc * per * BK;
    int k1 = min(K, k0 + per * BK);

    const int wv = tid >> 6, lane = tid & 63;
    const int wm = (wv & 1) << 6, wn = (wv >> 1) << 6;
    const int fr = lane & 15, fc = lane >> 4;
    f32x4 acc[4][4] = {};

    const int lr = lane >> 2, lc = (lane & 3) << 3;
    const u16* ga0 = Ab + (size_t)(bm + wv * 16 + lr) * lda + k0 + lc;
    const u16* ga1 = ga0 + (size_t)64 * lda;
    const u16* gb0 = Bb + (size_t)(bn + wv * 16 + lr) * ldb + k0 + lc;
    const u16* gb1 = gb0 + (size_t)64 * ldb;
    u16* la0 = As + (wv * 16) * BK;
    u16* la1 = As + (wv * 16 + 64) * BK;
    u16* lb0 = Bs + (wv * 16) * BK;
    u16* lb1 = Bs + (wv * 16 + 64) * BK;

    for (int kb = k0; kb < k1; kb += BK) {
        gload_lds16(ga0, la0);
        gload_lds16(ga1, la1);
        gload_lds16(gb0, lb0);
        gload_lds16(gb1, lb1);
        ga0 += BK; ga1 += BK; gb0 += BK; gb1 += BK;
        __syncthreads();
        short8 af[4], bfr[4];
#pragma unroll
        for (int i = 0; i < 4; ++i)
            af[i] = *(const short8*)(As + (wm + i * 16 + fr) * BK + fc * 8);
#pragma unroll
        for (int j = 0; j < 4; ++j)
            bfr[j] = *(const short8*)(Bs + (wn + j * 16 + fr) * BK + fc * 8);
#pragma unroll
        for (int i = 0; i < 4; ++i)
#pragma unroll
            for (int j = 0; j < 4; ++j)
                acc[i][j] = __builtin_amdgcn_mfma_f32_16x16x32_bf16(af[i], bfr[j], acc[i][j], 0, 0, 0);
        __syncthreads();
    }
    float alpha = alphaConst * (alphaPtr ? alphaPtr[alphaIdx] : 1.f);
    if (mode == 3) {
#pragma unroll
        for (int i = 0; i < 4; ++i) {
#pragma unroll
            for (int j = 0; j < 4; ++j) {
                int gn = bn + wn + j * 16 + fr;
                if (gn >= 2 * INNER) continue;
                int isV = gn >= INNER;
                int gnn = isV ? gn - INNER : gn;
                int h = gnn / DH, dd = gnn - h * DH;
                int gm0 = bm + wm + i * 16 + fc * 4;
#pragma unroll
                for (int r = 0; r < 4; ++r) {
                    int gm = gm0 + r;
                    int b2 = gm >> 13, vox = gm & (NVOX - 1);
                    u16 v = f2bf(acc[i][j][r] * alpha);
                    if (!isV) kdst[(((size_t)(b2 * 8 + h)) * NVOX + vox) * DHP + dd] = v;
                    else      vdst[((size_t)(b2 * 8 + h) * DH + dd) * NVOX + vox] = v;
                }
            }
        }
        return;
    }
    float* Db = (float*)Dv + (size_t)zo * sDo + (size_t)zi * sDi;
    u16* Du = (u16*)Dv + (size_t)zo * sDo + (size_t)zi * sDi;
    if (mode == 0) Db += (size_t)kc * sKp;
#pragma unroll
    for (int i = 0; i < 4; ++i) {
#pragma unroll
        for (int j = 0; j < 4; ++j) {
            int gn = bn + wn + j * 16 + fr;
            if (gn >= N) continue;
            float bv = bias ? bias[gn] * biasScale : 0.f;
            int gm0 = bm + wm + i * 16 + fc * 4;
#pragma unroll
            for (int r = 0; r < 4; ++r) {
                int gm = gm0 + r;
                if (gm >= M) continue;
                float v = acc[i][j][r] * alpha + bv;
                if (act) v = 0.5f * v * (1.f + erff(v * 0.70710678118654752f));
                size_t di = (size_t)gm * ldd + gn;
                if (mode == 2)      Du[di] = f2bf(v);
                else if (mode == 1) atomicAdd(&Db[di], v);
                else                Db[di] = v;
            }
        }
    }
}

// final permute: outtmp (b,128,64) -> d_out (t,b,n,64), latent = n*8 + t
__global__ __launch_bounds__(256) void reorder_kernel(const float* __restrict__ outtmp,
                                                      float* __restrict__ out) {
    int idx = blockIdx.x * 256 + threadIdx.x;
    if (idx >= TBINS * BATCH * (NL / TBINS) * OC) return;
    int oc = idx & 63, n = (idx >> 6) & 15, b = (idx >> 10) & 3, t = idx >> 12;
    out[idx] = outtmp[((size_t)(b * NL + n * TBINS + t)) * OC + oc];
}

// ---------------------------------------------------------------------------
extern "C" void kernel_launch(void* const* d_in, const int* in_sizes, int n_in,
                              void* d_out, int out_size, void* d_ws, size_t ws_size,
                              hipStream_t stream) {
    const float* input    = (const float*)d_in[0];
    const float* latents  = (const float*)d_in[1];
    const float* pos_emb  = (const float*)d_in[2];
    const float* ca_g     = (const float*)d_in[3];
    const float* ca_ctx_g = (const float*)d_in[4];
    const float* ca_q     = (const float*)d_in[5];
    const float* ca_kv    = (const float*)d_in[6];
    const float* ca_ow    = (const float*)d_in[7];
    const float* ca_ob    = (const float*)d_in[8];
    const float* cf_g     = (const float*)d_in[9];
    const float* cf_w1    = (const float*)d_in[10];
    const float* cf_b1    = (const float*)d_in[11];
    const float* cf_w2    = (const float*)d_in[12];
    const float* cf_b2    = (const float*)d_in[13];
    const float* la_g     = (const float*)d_in[14];
    const float* la_q     = (const float*)d_in[15];
    const float* la_kv    = (const float*)d_in[16];
    const float* la_ow    = (const float*)d_in[17];
    const float* la_ob    = (const float*)d_in[18];
    const float* lf_g     = (const float*)d_in[19];
    const float* lf_w1    = (const float*)d_in[20];
    const float* lf_b1    = (const float*)d_in[21];
    const float* lf_w2    = (const float*)d_in[22];
    const float* lf_b2    = (const float*)d_in[23];
    const float* logits_w = (const float*)d_in[24];
    const float* logits_b = (const float*)d_in[25];
    float* out = (float*)d_out;
    (void)ws_size; (void)n_in; (void)in_sizes; (void)out_size;

    // workspace carve (~152 MB)
    char* w = (char*)d_ws;
    auto alloc = [&](size_t bytes) { void* p = (void*)w; w += (bytes + 255) & ~(size_t)255; return p; };
    int* perm        = (int*)alloc((size_t)BATCH * NVOX * 4);
    int* Kc          = (int*)alloc(64);
    unsigned char* mask = (unsigned char*)alloc((size_t)BATCH * NVOX);
    float* lat       = (float*)alloc((size_t)BATCH * NL * LD * 4);
    u16* latn_bf     = (u16*)alloc((size_t)BATCH * NL * LD * 2);
    u16* qg_bf       = (u16*)alloc((size_t)BATCH * NL * INNER * 2);
    u16* qkv_bf      = (u16*)alloc((size_t)BATCH * NL * 3 * INNER * 2);
    u16* attn_bf     = (u16*)alloc((size_t)BATCH * NL * INNERP * 2);
    u16* ffb_bf      = (u16*)alloc((size_t)BATCH * NL * FFD * 2);
    float* outtmp    = (float*)alloc((size_t)BATCH * NL * OC * 4);
    u16* q_bf        = (u16*)alloc((size_t)BATCH * HEADS * NL * DHP * 2);
    u16* ks_bf       = (u16*)alloc((size_t)BATCH * HEADS * NL * DHP * 2);
    u16* vs_t        = (u16*)alloc((size_t)BATCH * HEADS * DH * NL * 2);
    alloc(64 * 1024);  // pad: B over-read slack behind vs_t
    float* SVpart    = (float*)alloc((size_t)2 * SVSPLIT * 16 * NL * DH * 4);   // 19.7 MB
    // per-layer transposed bf16 weights
    u16* wq_t    = (u16*)alloc((size_t)INNER * LD * 2);
    u16* wkv_t   = (u16*)alloc((size_t)2 * INNER * IDP * 2);
    u16* wow_t   = (u16*)alloc((size_t)LD * INNERP * 2);
    u16* wf1_t   = (u16*)alloc((size_t)FFD * LD * 2);
    u16* wf2_t   = (u16*)alloc((size_t)LD * FFD * 2);
    u16* wlqkv_t = (u16*)alloc((size_t)3 * INNER * LD * 2);   // lq rows 0-599, lkv rows 600-1799
    u16* wlow_t  = (u16*)alloc((size_t)LD * INNERP * 2);
    u16* wlf1_t  = (u16*)alloc((size_t)FFD * LD * 2);
    u16* wlf2_t  = (u16*)alloc((size_t)LD * FFD * 2);
    u16* wlog_t  = (u16*)alloc((size_t)OC * LD * 2);
    u16* normed  = (u16*)alloc((size_t)BATCH * NVOX * IDP * 2);                 // 29.4 MB persistent
    u16* E       = (u16*)alloc((size_t)16 * NL * NVOX * 2);                     // 33.6 MB (S scores)
    u16* k_bf    = (u16*)alloc((size_t)16 * NVOX * DHP * 2);                    // 25.2 MB
    u16* v_t     = (u16*)alloc((size_t)16 * DH * NVOX * 2);                     // 19.7 MB
    alloc((size_t)1 * 1024 * 1024);  // pad: v_t over-read slack

    const float scaleS = 1.0f / sqrtf((float)DH);
    const int M4 = BATCH * NL;

    auto G = [&](const u16* A, const u16* B, void* D, const float* aP, int aI, float aC,
                 int M, int N, int K, int lda, int ldb, int ldd, int nh, int nb,
                 ll sAo, ll sAi, ll sBo, ll sBi, ll sDo, ll sDi,
                 int splitK, int mode, const float* bias = nullptr, float biasScale = 1.f,
                 int act = 0, ll sKp = 0, u16* kd = nullptr, u16* vd = nullptr) {
        dim3 g((M + 127) / 128, (N + 127) / 128, nb * splitK);
        hipLaunchKernelGGL(gemm_bf16, g, dim3(256), 0, stream, A, B, D, aP, aI, aC,
                           M, N, K, lda, ldb, ldd, nh, sAo, sAi, sBo, sBi, sDo, sDi,
                           splitK, mode, bias, biasScale, act, sKp, kd, vd);
    };

    hipLaunchKernelGGL(mask_kernel, dim3((BATCH * NVOX + 255) / 256), dim3(256), 0, stream, input, mask);
    hipLaunchKernelGGL(compact_kernel, dim3(BATCH), dim3(64), 0, stream, mask, perm, Kc);
    hipLaunchKernelGGL(lat_init, dim3((BATCH * NL * LD + 255) / 256), dim3(256), 0, stream, latents, pos_emb, lat);
    // zero k_bf once (scatter never writes dd in [75,96); avoids NaN garbage in MFMA B)
    hipLaunchKernelGGL(fill_kernel, dim3(((16 * NVOX * DHP / 2) + 255) / 256), dim3(256), 0, stream,
                       (float*)k_bf, (long long)(16 * NVOX * DHP / 2), 0.f);
    hipLaunchKernelGGL(build_all, dim3(BATCH * NVOX), dim3(256), 0, stream, input, perm, Kc, normed);

    for (int d = 0; d < DEPTH; ++d) {
        // ---- all weight transposes for this layer in ONE launch ----
        TJobs J;
        int t = 0;
        auto addJob = [&](const float* s, u16* ds, int R, int C, int Rp) {
            int j = J.njobs = (t + 1);
            J.src[t] = s; J.dst[t] = ds; J.R[t] = R; J.C[t] = C; J.Rp[t] = Rp;
            J.tstart[t] = (t == 0) ? 0 : J.tstart[t - 1] +
                          (J.Rp[t - 1] >> 5) * ((J.C[t - 1] + 31) >> 5);
            (void)j; ++t;
        };
        addJob(ca_q  + (size_t)d * LD * INNER,     wq_t,            LD,  INNER,     LD);
        addJob(ca_kv + (size_t)d * ID * 2 * INNER, wkv_t,           ID,  2 * INNER, IDP);
        addJob(ca_ow + (size_t)d * INNER * LD,     wow_t,           INNER, LD,      INNERP);
        addJob(cf_w1 + (size_t)d * LD * FFD,       wf1_t,           LD,  FFD,       LD);
        addJob(cf_w2 + (size_t)d * FFD * LD,       wf2_t,           FFD, LD,        FFD);
        addJob(la_q  + (size_t)d * LD * INNER,     wlqkv_t,         LD,  INNER,     LD);
        addJob(la_kv + (size_t)d * LD * 2 * INNER, wlqkv_t + (size_t)INNER * LD, LD, 2 * INNER, LD);
        addJob(la_ow + (size_t)d * INNER * LD,     wlow_t,          INNER, LD,      INNERP);
        addJob(lf_w1 + (size_t)d * LD * FFD,       wlf1_t,          LD,  FFD,       LD);
        addJob(lf_w2 + (size_t)d * FFD * LD,       wlf2_t,          FFD, LD,        FFD);
        if (d == 0) addJob(logits_w,               wlog_t,          LD,  OC,        LD);
        J.njobs = t;
        J.tstart[t] = J.tstart[t - 1] + (J.Rp[t - 1] >> 5) * ((J.C[t - 1] + 31) >> 5);
        hipLaunchKernelGGL(transpose_multi, dim3(J.tstart[t]), dim3(256), 0, stream, J);

        // ---- cross attention ----
        hipLaunchKernelGGL(scale_norm_bf, dim3(M4), dim3(256), 0, stream, lat, latn_bf, ca_g, d, LD);
        G(latn_bf, wq_t, qg_bf, nullptr, 0, 1.f, M4, INNER, LD, LD, LD, INNER, 1, 1,
          0, 0, 0, 0, 0, 0, 1, 2);
        hipLaunchKernelGGL(pack_heads_u16, dim3((BATCH * HEADS * NL * DHP + 255) / 256), dim3(256), 0, stream,
                           qg_bf, q_bf, INNER);
        for (int hf = 0; hf < 2; ++hf) {
            // KV projection: 16384 x 1200, scatter into k_bf / v_t
            G(normed + (size_t)hf * 2 * NVOX * IDP, wkv_t, nullptr, ca_ctx_g, d, 1.f,
              2 * NVOX, 2 * INNER, IDP, IDP, IDP, 0, 1, 1,
              0, 0, 0, 0, 0, 0, 1, 3, nullptr, 1.f, 0, 0, k_bf, v_t);
            // S = q k^T * scale -> bf16 into E   (z = b2*8+h, 16)
            G(q_bf + (size_t)hf * 2 * HEADS * NL * DHP, k_bf, E, nullptr, 0, scaleS,
              NL, NVOX, DHP, DHP, DHP, NVOX, 16, 16,
              0, (ll)NL * DHP, 0, (ll)NVOX * DHP, 0, (ll)NL * NVOX, 1, 2);
            hipLaunchKernelGGL(softmax_u16, dim3(16 * NL), dim3(256), 0, stream,
                               E, NVOX, Kc, hf * 2, HEADS * NL);
            // S @ V -> fp32 partials (per z, per kc slab), no atomics
            G(E, v_t, SVpart + (size_t)hf * SVSPLIT * 16 * NL * DH, nullptr, 0, 1.f,
              NL, DH, NVOX, NVOX, NVOX, DH, 16, 16,
              0, (ll)NL * NVOX, 0, (ll)DH * NVOX, 0, (ll)NL * DH,
              SVSPLIT, 0, nullptr, 1.f, 0, (ll)16 * NL * DH);
        }
        hipLaunchKernelGGL(reduce_attn, dim3((M4 * INNERP + 255) / 256), dim3(256), 0, stream,
                           SVpart, attn_bf);
        G(attn_bf, wow_t, lat, nullptr, 0, 1.f, M4, LD, INNERP, INNERP, INNERP, LD, 1, 1,
          0, 0, 0, 0, 0, 0, 2, 1, ca_ob + (size_t)d * LD, 0.5f);

        // ---- FF (cf) ----
        hipLaunchKernelGGL(scale_norm_bf, dim3(M4), dim3(256), 0, stream, lat, latn_bf, cf_g, d, LD);
        G(latn_bf, wf1_t, ffb_bf, nullptr, 0, 1.f, M4, FFD, LD, LD, LD, FFD, 1, 1,
          0, 0, 0, 0, 0, 0, 1, 2, cf_b1 + (size_t)d * FFD, 1.f, 1);
        G(ffb_bf, wf2_t, lat, nullptr, 0, 1.f, M4, LD, FFD, FFD, FFD, LD, 1, 1,
          0, 0, 0, 0, 0, 0, 8, 1, cf_b2 + (size_t)d * LD, 0.125f);

        // ---- latent self attention ----
        hipLaunchKernelGGL(scale_norm_bf, dim3(M4), dim3(256), 0, stream, lat, latn_bf, la_g, d, LD);
        G(latn_bf, wlqkv_t, qkv_bf, nullptr, 0, 1.f, M4, 3 * INNER, LD, LD, LD, 3 * INNER, 1, 1,
          0, 0, 0, 0, 0, 0, 1, 2);
        hipLaunchKernelGGL(pack3_self,
                           dim3((2 * BATCH * HEADS * NL * DHP + BATCH * HEADS * DH * NL + 255) / 256),
                           dim3(256), 0, stream, qkv_bf, q_bf, ks_bf, vs_t);
        G(q_bf, ks_bf, E, nullptr, 0, scaleS, NL, NL, DHP, DHP, DHP, NL, 32, 32,
          0, (ll)NL * DHP, 0, (ll)NL * DHP, 0, (ll)NL * NL, 1, 2);
        hipLaunchKernelGGL(softmax_u16, dim3(BATCH * HEADS * NL), dim3(256), 0, stream,
                           E, NL, (const int*)nullptr, 0, HEADS * NL);
        // S_self @ V_self -> bf16 directly into attn_bf (strided per head)
        G(E, vs_t, attn_bf, nullptr, 0, 1.f, NL, DH, NL, NL, NL, INNERP, 8, 32,
          (ll)HEADS * NL * NL, (ll)NL * NL, (ll)HEADS * DH * NL, (ll)DH * NL,
          (ll)NL * INNERP, (ll)DH, 1, 2);
        G(attn_bf, wlow_t, lat, nullptr, 0, 1.f, M4, LD, INNERP, INNERP, INNERP, LD, 1, 1,
          0, 0, 0, 0, 0, 0, 2, 1, la_ob + (size_t)d * LD, 0.5f);

        // ---- FF (lf) ----
        hipLaunchKernelGGL(scale_norm_bf, dim3(M4), dim3(256), 0, stream, lat, latn_bf, lf_g, d, LD);
        G(latn_bf, wlf1_t, ffb_bf, nullptr, 0, 1.f, M4, FFD, LD, LD, LD, FFD, 1, 1,
          0, 0, 0, 0, 0, 0, 1, 2, lf_b1 + (size_t)d * FFD, 1.f, 1);
        G(ffb_bf, wlf2_t, lat, nullptr, 0, 1.f, M4, LD, FFD, FFD, FFD, LD, 1, 1,
          0, 0, 0, 0, 0, 0, 8, 1, lf_b2 + (size_t)d * LD, 0.125f);
    }

    // logits + reorder
    hipLaunchKernelGGL(conv_bf, dim3((M4 * LD + 255) / 256), dim3(256), 0, stream, lat, latn_bf, M4 * LD);
    hipLaunchKernelGGL(fill_kernel, dim3((M4 * OC + 255) / 256), dim3(256), 0, stream,
                       outtmp, (long long)M4 * OC, 0.f);
    G(latn_bf, wlog_t, outtmp, nullptr, 0, 1.f, M4, OC, LD, LD, LD, OC, 1, 1,
      0, 0, 0, 0, 0, 0, 4, 1, logits_b, 0.25f);
    hipLaunchKernelGGL(reorder_kernel, dim3((TBINS * BATCH * (NL / TBINS) * OC + 255) / 256), dim3(256), 0,
                       stream, outtmp, out);
}

// Round 6
// 2267.878 us; speedup vs baseline: 5.1858x; 1.2507x over previous
//
#include <hip/hip_runtime.h>
#include <math.h>

typedef unsigned short u16;
typedef long long ll;
typedef __attribute__((ext_vector_type(8))) short short8;
typedef __attribute__((ext_vector_type(4))) float f32x4;

// Problem constants
#define TBINS 8
#define BATCH 4
#define CIN 3
#define WIMG 128
#define PC 48
#define NVOX 8192
#define ID 435
#define IDP 448      // ceil32(435)
#define LD 512
#define INNER 600
#define INNERP 608   // ceil32(600)
#define FFD 2048
#define NL 128
#define OC 64
#define DEPTH 5
#define HEADS 8
#define DH 75
#define DHP 96       // ceil32(75)
#define BK 32
#define NCH 16       // flash chunks over 8192 vox
#define FCH 512      // vox per chunk
#define FKT 64       // flash k-tile

static __device__ __forceinline__ u16 f2bf(float f) {
    unsigned x = __float_as_uint(f);
    unsigned r = (x + 0x7fffu + ((x >> 16) & 1u)) >> 16;
    return (u16)r;
}
static __device__ __forceinline__ float bf2f(u16 v) {
    return __uint_as_float(((unsigned)v) << 16);
}
static __device__ __forceinline__ void gload_lds16(const u16* g, u16* l) {
    __builtin_amdgcn_global_load_lds(
        (const __attribute__((address_space(1))) unsigned int*)g,
        (__attribute__((address_space(3))) unsigned int*)l, 16, 0, 0);
}

// ---------------------------------------------------------------------------
__global__ __launch_bounds__(256) void mask_kernel(const float* __restrict__ input,
                                                   unsigned char* __restrict__ mask) {
    int idx = blockIdx.x * 256 + threadIdx.x;
    if (idx >= BATCH * NVOX) return;
    int b = idx >> 13, i = idx & (NVOX - 1);
    int tt = i & 7, wx = (i >> 3) & 31, hy = i >> 8;
    float mx = -3.4e38f;
    for (int ch = 0; ch < PC; ++ch) {
        int py = ch / 12, px = (ch / 3) & 3, cc = ch % 3;
        float v = input[((size_t)((tt * BATCH + b) * CIN + cc) << 14) +
                        (hy * 4 + py) * WIMG + (wx * 4 + px)];
        mx = fmaxf(mx, v);
    }
    mask[idx] = (fabsf(mx) > 0.3f) ? 1 : 0;
}

__global__ __launch_bounds__(64) void compact_kernel(const unsigned char* __restrict__ mask,
                                                     int* __restrict__ perm,
                                                     int* __restrict__ Kc) {
    int b = blockIdx.x, lane = threadIdx.x;
    int offs = 0;
    for (int c = 0; c < NVOX / 64; ++c) {
        int i = c * 64 + lane;
        int m = mask[(b << 13) + i];
        unsigned long long bal = __ballot(m != 0);
        int excl = __popcll(bal & ((1ull << lane) - 1ull));
        if (m) perm[(b << 13) + offs + excl] = i;
        offs += __popcll(bal);
    }
    if (lane == 0) Kc[b] = offs;
}

// build normalized data rows (bf16, ld IDP) for ALL batches, one launch
__global__ __launch_bounds__(256) void build_all(const float* __restrict__ input,
                                                 const int* __restrict__ perm,
                                                 const int* __restrict__ Kc,
                                                 u16* __restrict__ normed) {
    int blk = blockIdx.x;             // b*8192 + r
    int b = blk >> 13, r = blk & (NVOX - 1);
    int tid = threadIdx.x;
    u16* out = normed + (size_t)blk * IDP;
    int Kb = Kc[b];
    if (r >= Kb) {
        for (int e = tid; e < IDP; e += 256) out[e] = 0;
        return;
    }
    __shared__ float row[IDP];
    __shared__ float red[256];
    int i = perm[(b << 13) + r];
    int tt = i & 7, wx = (i >> 3) & 31, hy = i >> 8;
    float pos0 = 2.f * hy / 32.f - 1.f;
    float pos1 = 2.f * wx / 32.f - 1.f;
    float pos2 = 2.f * tt / 8.f - 1.f;
    for (int e = tid; e < IDP; e += 256) {
        float v = 0.f;
        if (e < PC) {
            int py = e / 12, px = (e / 3) & 3, cc = e % 3;
            v = input[((size_t)((tt * BATCH + b) * CIN + cc) << 14) +
                      (hy * 4 + py) * WIMG + (wx * 4 + px)];
        } else if (e < ID) {
            int e2 = e - PC;
            int dim = e2 / 129, rem = e2 - dim * 129;
            float pp = (dim == 0) ? pos0 : (dim == 1 ? pos1 : pos2);
            if (rem < 64)       v = sinf(ldexpf(pp, -rem));
            else if (rem < 128) v = cosf(ldexpf(pp, -(rem - 64)));
            else                v = pp;
        }
        row[e] = v;
    }
    __syncthreads();
    float ss = 0.f;
    for (int e = tid; e < ID; e += 256) ss += row[e] * row[e];
    red[tid] = ss; __syncthreads();
    for (int s = 128; s > 0; s >>= 1) { if (tid < s) red[tid] += red[tid + s]; __syncthreads(); }
    float scale = 1.f / fmaxf(sqrtf(red[0]), 1e-5f);
    for (int e = tid; e < IDP; e += 256) out[e] = f2bf(row[e] * scale);
}

__global__ __launch_bounds__(256) void lat_init(const float* __restrict__ latents,
                                                const float* __restrict__ pos_emb,
                                                float* __restrict__ lat) {
    int idx = blockIdx.x * 256 + threadIdx.x;
    if (idx >= BATCH * NL * LD) return;
    int rem = idx & (NL * LD - 1);
    lat[idx] = latents[rem] + pos_emb[rem];
}

__global__ __launch_bounds__(256) void scale_norm_bf(const float* __restrict__ x,
                                                     u16* __restrict__ o,
                                                     const float* __restrict__ g, int gi,
                                                     int cols) {
    int rowi = blockIdx.x, tid = threadIdx.x;
    const float* xr = x + (size_t)rowi * cols;
    u16* orow = o + (size_t)rowi * cols;
    __shared__ float red[256];
    float ss = 0.f;
    for (int c = tid; c < cols; c += 256) { float v = xr[c]; ss += v * v; }
    red[tid] = ss; __syncthreads();
    for (int s = 128; s > 0; s >>= 1) { if (tid < s) red[tid] += red[tid + s]; __syncthreads(); }
    float scale = g[gi] / fmaxf(sqrtf(red[0]), 1e-5f);
    for (int c = tid; c < cols; c += 256) orow[c] = f2bf(xr[c] * scale);
}

__global__ __launch_bounds__(256) void fill_kernel(float* __restrict__ p, long long n, float v) {
    long long idx = (long long)blockIdx.x * 256 + threadIdx.x;
    if (idx < n) p[idx] = v;
}

__global__ __launch_bounds__(256) void conv_bf(const float* __restrict__ src, u16* __restrict__ dst, int n) {
    int idx = blockIdx.x * 256 + threadIdx.x;
    if (idx < n) dst[idx] = f2bf(src[idx]);
}

// batched transpose: fp32 (R x C) -> bf16 (C x Rp) per job; one launch
struct TJobs {
    const float* src[11];
    u16* dst[11];
    int R[11], C[11], Rp[11];
    int tstart[12];
    int njobs;
};
__global__ __launch_bounds__(256) void transpose_multi(TJobs J) {
    int bx = blockIdx.x;
    int j = 0;
    while (j + 1 < J.njobs && bx >= J.tstart[j + 1]) ++j;
    int lt = bx - J.tstart[j];
    int tilesX = J.Rp[j] >> 5;
    int tx = lt % tilesX, ty = lt / tilesX;
    const float* src = J.src[j];
    u16* dst = J.dst[j];
    int R = J.R[j], C = J.C[j], Rp = J.Rp[j];
    __shared__ float t[32][33];
    int bx0 = tx * 32, by0 = ty * 32;
    int ttx = threadIdx.x & 31, tty = threadIdx.x >> 5;
#pragma unroll
    for (int p = 0; p < 4; ++p) {
        int r = bx0 + tty + p * 8, c = by0 + ttx;
        t[tty + p * 8][ttx] = (r < R && c < C) ? src[(size_t)r * C + c] : 0.f;
    }
    __syncthreads();
#pragma unroll
    for (int p = 0; p < 4; ++p) {
        int c = by0 + tty + p * 8, r = bx0 + ttx;
        if (c < C && r < Rp) dst[(size_t)c * Rp + r] = f2bf(t[ttx][tty + p * 8]);
    }
}

// u16 (BATCH*128 x srcld) head-split -> bf16 (b*8+h, 128, DHP) zero-padded
__global__ __launch_bounds__(256) void pack_heads_u16(const u16* __restrict__ src, u16* __restrict__ dst,
                                                      int srcld) {
    int idx = blockIdx.x * 256 + threadIdx.x;
    if (idx >= BATCH * HEADS * NL * DHP) return;
    int dd = idx % DHP;
    int l = (idx / DHP) & (NL - 1);
    int bh = idx / (DHP * NL);
    int b = bh >> 3, h = bh & 7;
    dst[idx] = (dd < DH) ? src[(size_t)(b * NL + l) * srcld + h * DH + dd] : 0;
}

// split fused qkv (512 x 1800) into q_bf, ks_bf (bh,128,DHP) and vs_t (bh,DH,128)
__global__ __launch_bounds__(256) void pack3_self(const u16* __restrict__ qkv,
                                                  u16* __restrict__ qd, u16* __restrict__ kd,
                                                  u16* __restrict__ vd) {
    const int R0 = BATCH * HEADS * NL * DHP;
    const int R2 = BATCH * HEADS * DH * NL;
    int idx = blockIdx.x * 256 + threadIdx.x;
    if (idx < 2 * R0) {
        int which = idx >= R0;
        int k = which ? idx - R0 : idx;
        int dd = k % DHP;
        int l = (k / DHP) & (NL - 1);
        int bh = k / (DHP * NL);
        int b = bh >> 3, h = bh & 7;
        u16 v = 0;
        if (dd < DH) v = qkv[(size_t)(b * NL + l) * (3 * INNER) + which * INNER + h * DH + dd];
        (which ? kd : qd)[k] = v;
    } else if (idx < 2 * R0 + R2) {
        int k = idx - 2 * R0;
        int l = k & (NL - 1);
        int dd = (k >> 7) % DH;
        int bh = k / (DH * NL);
        int b = bh >> 3, h = bh & 7;
        vd[k] = qkv[(size_t)(b * NL + l) * (3 * INNER) + 2 * INNER + h * DH + dd];
    }
}

// masked softmax on bf16 in place (used for self-attn scores, cols=128)
__global__ __launch_bounds__(256) void softmax_u16(u16* __restrict__ S, int cols,
                                                   const int* __restrict__ Kc, int b0,
                                                   int rows_per_b) {
    int rowi = blockIdx.x, tid = threadIdx.x;
    u16* p = S + (size_t)rowi * cols;
    int lim = Kc ? Kc[b0 + rowi / rows_per_b] : cols;
    __shared__ float red[256];
    if (lim <= 0) { for (int j = tid; j < cols; j += 256) p[j] = 0; return; }
    float v[32];
    int nit = (lim + 255) >> 8;
    float mx = -3.4e38f;
    for (int s = 0; s < nit; ++s) {
        int j = s * 256 + tid;
        float x = (j < lim) ? bf2f(p[j]) : -3.4e38f;
        v[s] = x;
        mx = fmaxf(mx, x);
    }
    red[tid] = mx; __syncthreads();
    for (int s = 128; s > 0; s >>= 1) { if (tid < s) red[tid] = fmaxf(red[tid], red[tid + s]); __syncthreads(); }
    mx = red[0]; __syncthreads();
    float sum = 0.f;
    for (int s = 0; s < nit; ++s) {
        int j = s * 256 + tid;
        float e = (j < lim) ? expf(v[s] - mx) : 0.f;
        v[s] = e; sum += e;
    }
    red[tid] = sum; __syncthreads();
    for (int s = 128; s > 0; s >>= 1) { if (tid < s) red[tid] += red[tid + s]; __syncthreads(); }
    float inv = (red[0] > 0.f) ? 1.f / red[0] : 0.f;
    int nco = (cols + 255) >> 8;
    for (int s = 0; s < nco; ++s) {
        int j = s * 256 + tid;
        if (j < cols) p[j] = f2bf((s < nit && j < lim) ? v[s] * inv : 0.f);
    }
}

// ---------------------------------------------------------------------------
// Flash cross-attention: per block (chunk c, bh): Q(128xDHP) vs K/V chunk of FCH.
// Emits unnormalized O-partials (bh,c,128,80) fp32 + (m,l) stats (bh,c,128,2).
#define KS_LD 104
__global__ __launch_bounds__(256) void flash_ctx(
    const u16* __restrict__ qbf,   // (32,128,DHP)
    const u16* __restrict__ kbf,   // (32,NVOX,DHP)
    const u16* __restrict__ vtg,   // (32,DH,NVOX)
    const int* __restrict__ Kc,
    float* __restrict__ Opart,     // (32,NCH,128,80)
    float* __restrict__ mlb,       // (32,NCH,128,2)
    float scale) {
    int ch = blockIdx.x, bh = blockIdx.y;
    int b = bh >> 3;
    int lim = Kc[b];
    int v0 = ch * FCH;
    int nval = min(FCH, lim - v0);
    int tid = threadIdx.x, wv = tid >> 6, lane = tid & 63;
    int fr = lane & 15, fc = lane >> 4;
    float* Op = Opart + ((size_t)bh * NCH + ch) * (128 * 80);
    float* mlp = mlb + ((size_t)bh * NCH + ch) * 256;
    if (nval <= 0) {
        for (int i = tid; i < 128 * 80; i += 256) Op[i] = 0.f;
        for (int i = tid; i < 128; i += 256) { mlp[2 * i] = -3.4e38f; mlp[2 * i + 1] = 0.f; }
        return;
    }
    __shared__ __align__(16) u16 Ks[FKT * KS_LD];   // 13.3 KB
    __shared__ __align__(16) u16 Vt[80 * 72];       // 11.3 KB
    __shared__ __align__(16) u16 Ps[4 * 32 * 72];   // 18 KB
    // Q fragments (wave rows wv*32..wv*32+31)
    short8 qf[2][3];
    const u16* qb = qbf + ((size_t)bh * 128 + wv * 32) * DHP;
#pragma unroll
    for (int i = 0; i < 2; ++i)
#pragma unroll
        for (int kk = 0; kk < 3; ++kk)
            qf[i][kk] = *(const short8*)(qb + (i * 16 + fr) * DHP + kk * 32 + fc * 8);
    float m_run[2][4], l_run[2][4];
#pragma unroll
    for (int i = 0; i < 2; ++i)
#pragma unroll
        for (int r = 0; r < 4; ++r) { m_run[i][r] = -3.4e38f; l_run[i][r] = 0.f; }
    f32x4 o[2][5] = {};
    u16* Pw = Ps + wv * (32 * 72);
    int ktiles = (nval + FKT - 1) / FKT;
    for (int kt = 0; kt < ktiles; ++kt) {
        int kvox = v0 + kt * FKT;
        // stage K tile: 64 rows x 96 (LDS ld 104)
        for (int t = 0; t < 3; ++t) {
            int idx = t * 256 + tid;                 // 768 chunks of 8 u16
            int row = idx / 12, cc = idx - row * 12;
            short8 v = *(const short8*)(kbf + ((size_t)bh * NVOX + kvox + row) * DHP + cc * 8);
            *(short8*)(Ks + row * KS_LD + cc * 8) = v;
        }
        // stage V^T tile: 80 rows (dd) x 64 vox (LDS ld 72); rows >= DH read pad garbage
        for (int t = 0; t < 3; ++t) {
            int idx = t * 256 + tid;                 // 640 chunks
            if (idx < 640) {
                int row = idx >> 3, cc = idx & 7;
                short8 v = *(const short8*)(vtg + ((size_t)bh * DH + row) * NVOX + kvox + cc * 8);
                *(short8*)(Vt + row * 72 + cc * 8) = v;
            }
        }
        __syncthreads();
        // S = Q K^T  (m=32 rows of this wave, n=64)
        f32x4 sc[2][4] = {};
#pragma unroll
        for (int kk = 0; kk < 3; ++kk) {
            short8 bf[4];
#pragma unroll
            for (int j = 0; j < 4; ++j)
                bf[j] = *(const short8*)(Ks + (j * 16 + fr) * KS_LD + kk * 32 + fc * 8);
#pragma unroll
            for (int i = 0; i < 2; ++i)
#pragma unroll
                for (int j = 0; j < 4; ++j)
                    sc[i][j] = __builtin_amdgcn_mfma_f32_16x16x32_bf16(qf[i][kk], bf[j], sc[i][j], 0, 0, 0);
        }
        // online softmax per row (C-layout: col=fr within frag j, row=fc*4+r within frag i)
        float alpha[2][4];
#pragma unroll
        for (int i = 0; i < 2; ++i) {
#pragma unroll
            for (int r = 0; r < 4; ++r) {
                float mt = -3.4e38f;
#pragma unroll
                for (int j = 0; j < 4; ++j) {
                    int cl = kt * FKT + j * 16 + fr;
                    float s = (cl < nval) ? sc[i][j][r] * scale : -3.4e38f;
                    sc[i][j][r] = s;
                    mt = fmaxf(mt, s);
                }
                for (int sft = 1; sft < 16; sft <<= 1) mt = fmaxf(mt, __shfl_xor(mt, sft, 16));
                float mn = fmaxf(m_run[i][r], mt);
                float al = __expf(m_run[i][r] - mn);
                m_run[i][r] = mn;
                float lt = 0.f;
#pragma unroll
                for (int j = 0; j < 4; ++j) {
                    float p = __expf(sc[i][j][r] - mn);
                    sc[i][j][r] = p;
                    lt += p;
                }
                for (int sft = 1; sft < 16; sft <<= 1) lt += __shfl_xor(lt, sft, 16);
                l_run[i][r] = l_run[i][r] * al + lt;
                alpha[i][r] = al;
            }
        }
        // P -> LDS (per-wave region), rescale O
#pragma unroll
        for (int i = 0; i < 2; ++i)
#pragma unroll
            for (int j = 0; j < 4; ++j)
#pragma unroll
                for (int r = 0; r < 4; ++r)
                    Pw[(i * 16 + fc * 4 + r) * 72 + j * 16 + fr] = f2bf(sc[i][j][r]);
#pragma unroll
        for (int i = 0; i < 2; ++i)
#pragma unroll
            for (int n = 0; n < 5; ++n)
#pragma unroll
                for (int r = 0; r < 4; ++r)
                    o[i][n][r] *= alpha[i][r];
        __syncthreads();
        // O += P @ V   (A = P (32x64), B^T-layout = Vt (dd rows, vox cols))
#pragma unroll
        for (int kk = 0; kk < 2; ++kk) {
            short8 pf[2], vf[5];
#pragma unroll
            for (int i = 0; i < 2; ++i)
                pf[i] = *(const short8*)(Pw + (i * 16 + fr) * 72 + kk * 32 + fc * 8);
#pragma unroll
            for (int n = 0; n < 5; ++n)
                vf[n] = *(const short8*)(Vt + (n * 16 + fr) * 72 + kk * 32 + fc * 8);
#pragma unroll
            for (int i = 0; i < 2; ++i)
#pragma unroll
                for (int n = 0; n < 5; ++n)
                    o[i][n] = __builtin_amdgcn_mfma_f32_16x16x32_bf16(pf[i], vf[n], o[i][n], 0, 0, 0);
        }
        __syncthreads();
    }
    // epilogue: unnormalized O + stats
#pragma unroll
    for (int i = 0; i < 2; ++i) {
#pragma unroll
        for (int n = 0; n < 5; ++n) {
#pragma unroll
            for (int r = 0; r < 4; ++r) {
                int row = wv * 32 + i * 16 + fc * 4 + r;
                int col = n * 16 + fr;
                Op[row * 80 + col] = o[i][n][r];
            }
        }
        if (fr == 0) {
#pragma unroll
            for (int r = 0; r < 4; ++r) {
                int row = wv * 32 + i * 16 + fc * 4 + r;
                mlp[2 * row] = m_run[i][r];
                mlp[2 * row + 1] = l_run[i][r];
            }
        }
    }
}

// combine flash partials -> attn_bf (512 x INNERP bf16, pad-zeroed)
__global__ __launch_bounds__(128) void combine_ctx(const float* __restrict__ Opart,
                                                   const float* __restrict__ mlb,
                                                   u16* __restrict__ attn_bf) {
    int blk = blockIdx.x;                // bh*128 + row
    int bh = blk >> 7, row = blk & 127;
    int b = bh >> 3, h = bh & 7;
    int tid = threadIdx.x;
    float mc[NCH], lc[NCH];
    float mstar = -3.4e38f;
    for (int c = 0; c < NCH; ++c) {
        const float* mlp = mlb + ((size_t)bh * NCH + c) * 256 + 2 * row;
        mc[c] = mlp[0]; lc[c] = mlp[1];
        mstar = fmaxf(mstar, mc[c]);
    }
    float L = 0.f;
    float wc[NCH];
    for (int c = 0; c < NCH; ++c) {
        float ww = __expf(mc[c] - mstar);
        wc[c] = ww; L += ww * lc[c];
    }
    float invL = (L > 0.f) ? 1.f / L : 0.f;
    if (tid < DH) {
        float s = 0.f;
        for (int c = 0; c < NCH; ++c)
            s += Opart[(((size_t)bh * NCH + c) * 128 + row) * 80 + tid] * wc[c];
        attn_bf[((size_t)(b * 128 + row)) * INNERP + h * DH + tid] = f2bf(s * invL);
    }
    if (h == 7 && tid >= DH && tid < DH + (INNERP - INNER))
        attn_bf[((size_t)(b * 128 + row)) * INNERP + INNER + (tid - DH)] = 0;
}

// ---------------------------------------------------------------------------
// bf16 MFMA GEMM with global_load_lds staging. D = alpha * A @ B^T_layout (+bias, act).
// modes: 0 = f32 store (Db += kc*sKp), 1 = f32 atomicAdd, 2 = bf16 store,
// 3 = ctx-KV scatter (kdst (b*8+h,vox,DHP), vdst (b*8+h,dd,vox)), b = gm>>13.
__global__ __launch_bounds__(256) void gemm_bf16(
    const u16* __restrict__ A, const u16* __restrict__ B, void* __restrict__ Dv,
    const float* __restrict__ alphaPtr, int alphaIdx, float alphaConst,
    int M, int N, int K, int lda, int ldb, int ldd, int nh,
    ll sAo, ll sAi, ll sBo, ll sBi, ll sDo, ll sDi,
    int splitK, int mode, const float* __restrict__ bias, float biasScale, int act,
    ll sKp, u16* __restrict__ kdst, u16* __restrict__ vdst) {
    __shared__ __align__(16) u16 As[128 * BK];
    __shared__ __align__(16) u16 Bs[128 * BK];
    const int tid = threadIdx.x;
    int zb = blockIdx.z / splitK, kc = blockIdx.z - zb * splitK;
    int zo = zb / nh, zi = zb - zo * nh;
    const u16* Ab = A + (size_t)zo * sAo + (size_t)zi * sAi;
    const u16* Bb = B + (size_t)zo * sBo + (size_t)zi * sBi;
    const int bm = blockIdx.x * 128, bn = blockIdx.y * 128;
    int nk = K >> 5;
    int per = (nk + splitK - 1) / splitK;
    int k0 = kc * per * BK;
    int k1 = min(K, k0 + per * BK);

    const int wv = tid >> 6, lane = tid & 63;
    const int wm = (wv & 1) << 6, wn = (wv >> 1) << 6;
    const int fr = lane & 15, fc = lane >> 4;
    f32x4 acc[4][4] = {};

    const int lr = lane >> 2, lc = (lane & 3) << 3;
    const u16* ga0 = Ab + (size_t)(bm + wv * 16 + lr) * lda + k0 + lc;
    const u16* ga1 = ga0 + (size_t)64 * lda;
    const u16* gb0 = Bb + (size_t)(bn + wv * 16 + lr) * ldb + k0 + lc;
    const u16* gb1 = gb0 + (size_t)64 * ldb;
    u16* la0 = As + (wv * 16) * BK;
    u16* la1 = As + (wv * 16 + 64) * BK;
    u16* lb0 = Bs + (wv * 16) * BK;
    u16* lb1 = Bs + (wv * 16 + 64) * BK;

    for (int kb = k0; kb < k1; kb += BK) {
        gload_lds16(ga0, la0);
        gload_lds16(ga1, la1);
        gload_lds16(gb0, lb0);
        gload_lds16(gb1, lb1);
        ga0 += BK; ga1 += BK; gb0 += BK; gb1 += BK;
        __syncthreads();
        short8 af[4], bfr[4];
#pragma unroll
        for (int i = 0; i < 4; ++i)
            af[i] = *(const short8*)(As + (wm + i * 16 + fr) * BK + fc * 8);
#pragma unroll
        for (int j = 0; j < 4; ++j)
            bfr[j] = *(const short8*)(Bs + (wn + j * 16 + fr) * BK + fc * 8);
#pragma unroll
        for (int i = 0; i < 4; ++i)
#pragma unroll
            for (int j = 0; j < 4; ++j)
                acc[i][j] = __builtin_amdgcn_mfma_f32_16x16x32_bf16(af[i], bfr[j], acc[i][j], 0, 0, 0);
        __syncthreads();
    }
    float alpha = alphaConst * (alphaPtr ? alphaPtr[alphaIdx] : 1.f);
    if (mode == 3) {
#pragma unroll
        for (int i = 0; i < 4; ++i) {
#pragma unroll
            for (int j = 0; j < 4; ++j) {
                int gn = bn + wn + j * 16 + fr;
                if (gn >= 2 * INNER) continue;
                int isV = gn >= INNER;
                int gnn = isV ? gn - INNER : gn;
                int h = gnn / DH, dd = gnn - h * DH;
                int gm0 = bm + wm + i * 16 + fc * 4;
#pragma unroll
                for (int r = 0; r < 4; ++r) {
                    int gm = gm0 + r;
                    int b2 = gm >> 13, vox = gm & (NVOX - 1);
                    u16 v = f2bf(acc[i][j][r] * alpha);
                    if (!isV) kdst[(((size_t)(b2 * 8 + h)) * NVOX + vox) * DHP + dd] = v;
                    else      vdst[((size_t)(b2 * 8 + h) * DH + dd) * NVOX + vox] = v;
                }
            }
        }
        return;
    }
    float* Db = (float*)Dv + (size_t)zo * sDo + (size_t)zi * sDi;
    u16* Du = (u16*)Dv + (size_t)zo * sDo + (size_t)zi * sDi;
    if (mode == 0) Db += (size_t)kc * sKp;
#pragma unroll
    for (int i = 0; i < 4; ++i) {
#pragma unroll
        for (int j = 0; j < 4; ++j) {
            int gn = bn + wn + j * 16 + fr;
            if (gn >= N) continue;
            float bv = bias ? bias[gn] * biasScale : 0.f;
            int gm0 = bm + wm + i * 16 + fc * 4;
#pragma unroll
            for (int r = 0; r < 4; ++r) {
                int gm = gm0 + r;
                if (gm >= M) continue;
                float v = acc[i][j][r] * alpha + bv;
                if (act) v = 0.5f * v * (1.f + erff(v * 0.70710678118654752f));
                size_t di = (size_t)gm * ldd + gn;
                if (mode == 2)      Du[di] = f2bf(v);
                else if (mode == 1) atomicAdd(&Db[di], v);
                else                Db[di] = v;
            }
        }
    }
}

// final permute: outtmp (b,128,64) -> d_out (t,b,n,64), latent = n*8 + t
__global__ __launch_bounds__(256) void reorder_kernel(const float* __restrict__ outtmp,
                                                      float* __restrict__ out) {
    int idx = blockIdx.x * 256 + threadIdx.x;
    if (idx >= TBINS * BATCH * (NL / TBINS) * OC) return;
    int oc = idx & 63, n = (idx >> 6) & 15, b = (idx >> 10) & 3, t = idx >> 12;
    out[idx] = outtmp[((size_t)(b * NL + n * TBINS + t)) * OC + oc];
}

// ---------------------------------------------------------------------------
extern "C" void kernel_launch(void* const* d_in, const int* in_sizes, int n_in,
                              void* d_out, int out_size, void* d_ws, size_t ws_size,
                              hipStream_t stream) {
    const float* input    = (const float*)d_in[0];
    const float* latents  = (const float*)d_in[1];
    const float* pos_emb  = (const float*)d_in[2];
    const float* ca_g     = (const float*)d_in[3];
    const float* ca_ctx_g = (const float*)d_in[4];
    const float* ca_q     = (const float*)d_in[5];
    const float* ca_kv    = (const float*)d_in[6];
    const float* ca_ow    = (const float*)d_in[7];
    const float* ca_ob    = (const float*)d_in[8];
    const float* cf_g     = (const float*)d_in[9];
    const float* cf_w1    = (const float*)d_in[10];
    const float* cf_b1    = (const float*)d_in[11];
    const float* cf_w2    = (const float*)d_in[12];
    const float* cf_b2    = (const float*)d_in[13];
    const float* la_g     = (const float*)d_in[14];
    const float* la_q     = (const float*)d_in[15];
    const float* la_kv    = (const float*)d_in[16];
    const float* la_ow    = (const float*)d_in[17];
    const float* la_ob    = (const float*)d_in[18];
    const float* lf_g     = (const float*)d_in[19];
    const float* lf_w1    = (const float*)d_in[20];
    const float* lf_b1    = (const float*)d_in[21];
    const float* lf_w2    = (const float*)d_in[22];
    const float* lf_b2    = (const float*)d_in[23];
    const float* logits_w = (const float*)d_in[24];
    const float* logits_b = (const float*)d_in[25];
    float* out = (float*)d_out;
    (void)ws_size; (void)n_in; (void)in_sizes; (void)out_size;

    // workspace carve (~167 MB)
    char* w = (char*)d_ws;
    auto alloc = [&](size_t bytes) { void* p = (void*)w; w += (bytes + 255) & ~(size_t)255; return p; };
    int* perm        = (int*)alloc((size_t)BATCH * NVOX * 4);
    int* Kc          = (int*)alloc(64);
    unsigned char* mask = (unsigned char*)alloc((size_t)BATCH * NVOX);
    float* lat       = (float*)alloc((size_t)BATCH * NL * LD * 4);
    u16* latn_bf     = (u16*)alloc((size_t)BATCH * NL * LD * 2);
    u16* qg_bf       = (u16*)alloc((size_t)BATCH * NL * INNER * 2);
    u16* qkv_bf      = (u16*)alloc((size_t)BATCH * NL * 3 * INNER * 2);
    u16* attn_bf     = (u16*)alloc((size_t)BATCH * NL * INNERP * 2);
    u16* ffb_bf      = (u16*)alloc((size_t)BATCH * NL * FFD * 2);
    float* outtmp    = (float*)alloc((size_t)BATCH * NL * OC * 4);
    u16* q_bf        = (u16*)alloc((size_t)BATCH * HEADS * NL * DHP * 2);
    u16* ks_bf       = (u16*)alloc((size_t)BATCH * HEADS * NL * DHP * 2);
    u16* vs_t        = (u16*)alloc((size_t)BATCH * HEADS * DH * NL * 2);
    alloc(64 * 1024);  // pad: B over-read slack behind vs_t
    // per-layer transposed bf16 weights
    u16* wq_t    = (u16*)alloc((size_t)INNER * LD * 2);
    u16* wkv_t   = (u16*)alloc((size_t)2 * INNER * IDP * 2);
    u16* wow_t   = (u16*)alloc((size_t)LD * INNERP * 2);
    u16* wf1_t   = (u16*)alloc((size_t)FFD * LD * 2);
    u16* wf2_t   = (u16*)alloc((size_t)LD * FFD * 2);
    u16* wlqkv_t = (u16*)alloc((size_t)3 * INNER * LD * 2);
    u16* wlow_t  = (u16*)alloc((size_t)LD * INNERP * 2);
    u16* wlf1_t  = (u16*)alloc((size_t)FFD * LD * 2);
    u16* wlf2_t  = (u16*)alloc((size_t)LD * FFD * 2);
    u16* wlog_t  = (u16*)alloc((size_t)OC * LD * 2);
    u16* normed  = (u16*)alloc((size_t)BATCH * NVOX * IDP * 2);          // 29.4 MB
    u16* E       = (u16*)alloc((size_t)2 * 1024 * 1024);                 // self scores (1 MB used)
    u16* k_bf    = (u16*)alloc((size_t)32 * NVOX * DHP * 2);             // 50.3 MB
    u16* v_t     = (u16*)alloc((size_t)32 * DH * NVOX * 2);              // 39.3 MB
    alloc((size_t)1 * 1024 * 1024);  // pad: flash V rows [75,80) over-read slack
    float* Opart = (float*)alloc((size_t)32 * NCH * 128 * 80 * 4);       // 21 MB
    float* mlb   = (float*)alloc((size_t)32 * NCH * 128 * 2 * 4);        // 0.5 MB

    const float scaleS = 1.0f / sqrtf((float)DH);
    const int M4 = BATCH * NL;

    auto G = [&](const u16* A, const u16* B, void* D, const float* aP, int aI, float aC,
                 int M, int N, int K, int lda, int ldb, int ldd, int nh, int nb,
                 ll sAo, ll sAi, ll sBo, ll sBi, ll sDo, ll sDi,
                 int splitK, int mode, const float* bias = nullptr, float biasScale = 1.f,
                 int act = 0, ll sKp = 0, u16* kd = nullptr, u16* vd = nullptr) {
        dim3 g((M + 127) / 128, (N + 127) / 128, nb * splitK);
        hipLaunchKernelGGL(gemm_bf16, g, dim3(256), 0, stream, A, B, D, aP, aI, aC,
                           M, N, K, lda, ldb, ldd, nh, sAo, sAi, sBo, sBi, sDo, sDi,
                           splitK, mode, bias, biasScale, act, sKp, kd, vd);
    };

    hipLaunchKernelGGL(mask_kernel, dim3((BATCH * NVOX + 255) / 256), dim3(256), 0, stream, input, mask);
    hipLaunchKernelGGL(compact_kernel, dim3(BATCH), dim3(64), 0, stream, mask, perm, Kc);
    hipLaunchKernelGGL(lat_init, dim3((BATCH * NL * LD + 255) / 256), dim3(256), 0, stream, latents, pos_emb, lat);
    // zero k_bf once (scatter never writes dd in [75,96))
    hipLaunchKernelGGL(fill_kernel, dim3((((ll)32 * NVOX * DHP / 2) + 255) / 256), dim3(256), 0, stream,
                       (float*)k_bf, (ll)32 * NVOX * DHP / 2, 0.f);
    hipLaunchKernelGGL(build_all, dim3(BATCH * NVOX), dim3(256), 0, stream, input, perm, Kc, normed);

    for (int d = 0; d < DEPTH; ++d) {
        // ---- all weight transposes for this layer in ONE launch ----
        TJobs J;
        int t = 0;
        auto addJob = [&](const float* s, u16* ds, int R, int C, int Rp) {
            J.src[t] = s; J.dst[t] = ds; J.R[t] = R; J.C[t] = C; J.Rp[t] = Rp;
            J.tstart[t] = (t == 0) ? 0 : J.tstart[t - 1] +
                          (J.Rp[t - 1] >> 5) * ((J.C[t - 1] + 31) >> 5);
            ++t;
        };
        addJob(ca_q  + (size_t)d * LD * INNER,     wq_t,            LD,  INNER,     LD);
        addJob(ca_kv + (size_t)d * ID * 2 * INNER, wkv_t,           ID,  2 * INNER, IDP);
        addJob(ca_ow + (size_t)d * INNER * LD,     wow_t,           INNER, LD,      INNERP);
        addJob(cf_w1 + (size_t)d * LD * FFD,       wf1_t,           LD,  FFD,       LD);
        addJob(cf_w2 + (size_t)d * FFD * LD,       wf2_t,           FFD, LD,        FFD);
        addJob(la_q  + (size_t)d * LD * INNER,     wlqkv_t,         LD,  INNER,     LD);
        addJob(la_kv + (size_t)d * LD * 2 * INNER, wlqkv_t + (size_t)INNER * LD, LD, 2 * INNER, LD);
        addJob(la_ow + (size_t)d * INNER * LD,     wlow_t,          INNER, LD,      INNERP);
        addJob(lf_w1 + (size_t)d * LD * FFD,       wlf1_t,          LD,  FFD,       LD);
        addJob(lf_w2 + (size_t)d * FFD * LD,       wlf2_t,          FFD, LD,        FFD);
        if (d == 0) addJob(logits_w,               wlog_t,          LD,  OC,        LD);
        J.njobs = t;
        J.tstart[t] = J.tstart[t - 1] + (J.Rp[t - 1] >> 5) * ((J.C[t - 1] + 31) >> 5);
        hipLaunchKernelGGL(transpose_multi, dim3(J.tstart[t]), dim3(256), 0, stream, J);

        // ---- cross attention (flash) ----
        hipLaunchKernelGGL(scale_norm_bf, dim3(M4), dim3(256), 0, stream, lat, latn_bf, ca_g, d, LD);
        G(latn_bf, wq_t, qg_bf, nullptr, 0, 1.f, M4, INNER, LD, LD, LD, INNER, 1, 1,
          0, 0, 0, 0, 0, 0, 1, 2);
        hipLaunchKernelGGL(pack_heads_u16, dim3((BATCH * HEADS * NL * DHP + 255) / 256), dim3(256), 0, stream,
                           qg_bf, q_bf, INNER);
        // KV projection for all 4 batches: 32768 x 1200, scatter into k_bf / v_t
        G(normed, wkv_t, nullptr, ca_ctx_g, d, 1.f, BATCH * NVOX, 2 * INNER, IDP, IDP, IDP, 0, 1, 1,
          0, 0, 0, 0, 0, 0, 1, 3, nullptr, 1.f, 0, 0, k_bf, v_t);
        hipLaunchKernelGGL(flash_ctx, dim3(NCH, 32), dim3(256), 0, stream,
                           q_bf, k_bf, v_t, Kc, Opart, mlb, scaleS);
        hipLaunchKernelGGL(combine_ctx, dim3(32 * 128), dim3(128), 0, stream, Opart, mlb, attn_bf);
        G(attn_bf, wow_t, lat, nullptr, 0, 1.f, M4, LD, INNERP, INNERP, INNERP, LD, 1, 1,
          0, 0, 0, 0, 0, 0, 2, 1, ca_ob + (size_t)d * LD, 0.5f);

        // ---- FF (cf) ----
        hipLaunchKernelGGL(scale_norm_bf, dim3(M4), dim3(256), 0, stream, lat, latn_bf, cf_g, d, LD);
        G(latn_bf, wf1_t, ffb_bf, nullptr, 0, 1.f, M4, FFD, LD, LD, LD, FFD, 1, 1,
          0, 0, 0, 0, 0, 0, 1, 2, cf_b1 + (size_t)d * FFD, 1.f, 1);
        G(ffb_bf, wf2_t, lat, nullptr, 0, 1.f, M4, LD, FFD, FFD, FFD, LD, 1, 1,
          0, 0, 0, 0, 0, 0, 8, 1, cf_b2 + (size_t)d * LD, 0.125f);

        // ---- latent self attention ----
        hipLaunchKernelGGL(scale_norm_bf, dim3(M4), dim3(256), 0, stream, lat, latn_bf, la_g, d, LD);
        G(latn_bf, wlqkv_t, qkv_bf, nullptr, 0, 1.f, M4, 3 * INNER, LD, LD, LD, 3 * INNER, 1, 1,
          0, 0, 0, 0, 0, 0, 1, 2);
        hipLaunchKernelGGL(pack3_self,
                           dim3((2 * BATCH * HEADS * NL * DHP + BATCH * HEADS * DH * NL + 255) / 256),
                           dim3(256), 0, stream, qkv_bf, q_bf, ks_bf, vs_t);
        G(q_bf, ks_bf, E, nullptr, 0, scaleS, NL, NL, DHP, DHP, DHP, NL, 32, 32,
          0, (ll)NL * DHP, 0, (ll)NL * DHP, 0, (ll)NL * NL, 1, 2);
        hipLaunchKernelGGL(softmax_u16, dim3(BATCH * HEADS * NL), dim3(256), 0, stream,
                           E, NL, (const int*)nullptr, 0, HEADS * NL);
        G(E, vs_t, attn_bf, nullptr, 0, 1.f, NL, DH, NL, NL, NL, INNERP, 8, 32,
          (ll)HEADS * NL * NL, (ll)NL * NL, (ll)HEADS * DH * NL, (ll)DH * NL,
          (ll)NL * INNERP, (ll)DH, 1, 2);
        G(attn_bf, wlow_t, lat, nullptr, 0, 1.f, M4, LD, INNERP, INNERP, INNERP, LD, 1, 1,
          0, 0, 0, 0, 0, 0, 2, 1, la_ob + (size_t)d * LD, 0.5f);

        // ---- FF (lf) ----
        hipLaunchKernelGGL(scale_norm_bf, dim3(M4), dim3(256), 0, stream, lat, latn_bf, lf_g, d, LD);
        G(latn_bf, wlf1_t, ffb_bf, nullptr, 0, 1.f, M4, FFD, LD, LD, LD, FFD, 1, 1,
          0, 0, 0, 0, 0, 0, 1, 2, lf_b1 + (size_t)d * FFD, 1.f, 1);
        G(ffb_bf, wlf2_t, lat, nullptr, 0, 1.f, M4, LD, FFD, FFD, FFD, LD, 1, 1,
          0, 0, 0, 0, 0, 0, 8, 1, lf_b2 + (size_t)d * LD, 0.125f);
    }

    // logits + reorder
    hipLaunchKernelGGL(conv_bf, dim3((M4 * LD + 255) / 256), dim3(256), 0, stream, lat, latn_bf, M4 * LD);
    hipLaunchKernelGGL(fill_kernel, dim3((M4 * OC + 255) / 256), dim3(256), 0, stream,
                       outtmp, (ll)M4 * OC, 0.f);
    G(latn_bf, wlog_t, outtmp, nullptr, 0, 1.f, M4, OC, LD, LD, LD, OC, 1, 1,
      0, 0, 0, 0, 0, 0, 4, 1, logits_b, 0.25f);
    hipLaunchKernelGGL(reorder_kernel, dim3((TBINS * BATCH * (NL / TBINS) * OC + 255) / 256), dim3(256), 0,
                       stream, outtmp, out);
}

// Round 7
// 2131.019 us; speedup vs baseline: 5.5188x; 1.0642x over previous
//
#include <hip/hip_runtime.h>
#include <math.h>

typedef unsigned short u16;
typedef long long ll;
typedef __attribute__((ext_vector_type(8))) short short8;
typedef __attribute__((ext_vector_type(4))) float f32x4;

// Problem constants
#define TBINS 8
#define BATCH 4
#define CIN 3
#define WIMG 128
#define PC 48
#define NVOX 8192
#define ID 435
#define IDP 448      // ceil32(435)
#define LD 512
#define INNER 600
#define INNERP 608   // ceil32(600)
#define FFD 2048
#define NL 128
#define OC 64
#define DEPTH 5
#define HEADS 8
#define DH 75
#define DHP 96       // ceil32(75)
#define BK 32
#define NCH 16       // flash chunks over 8192 vox
#define FCH 512      // vox per chunk
#define FKT 64       // flash k-tile
#define KVLD 1536    // kv projection padded width (2*8*96)
#define QLD 768      // q padded width (8*96)
#define QKVLD 2304   // self qkv padded width (3*8*96)

static __device__ __forceinline__ u16 f2bf(float f) {
    unsigned x = __float_as_uint(f);
    unsigned r = (x + 0x7fffu + ((x >> 16) & 1u)) >> 16;
    return (u16)r;
}
static __device__ __forceinline__ float bf2f(u16 v) {
    return __uint_as_float(((unsigned)v) << 16);
}
static __device__ __forceinline__ void gload_lds16(const u16* g, u16* l) {
    __builtin_amdgcn_global_load_lds(
        (const __attribute__((address_space(1))) unsigned int*)g,
        (__attribute__((address_space(3))) unsigned int*)l, 16, 0, 0);
}

// ---------------------------------------------------------------------------
__global__ __launch_bounds__(256) void mask_kernel(const float* __restrict__ input,
                                                   unsigned char* __restrict__ mask) {
    int idx = blockIdx.x * 256 + threadIdx.x;
    if (idx >= BATCH * NVOX) return;
    int b = idx >> 13, i = idx & (NVOX - 1);
    int tt = i & 7, wx = (i >> 3) & 31, hy = i >> 8;
    float mx = -3.4e38f;
    for (int ch = 0; ch < PC; ++ch) {
        int py = ch / 12, px = (ch / 3) & 3, cc = ch % 3;
        float v = input[((size_t)((tt * BATCH + b) * CIN + cc) << 14) +
                        (hy * 4 + py) * WIMG + (wx * 4 + px)];
        mx = fmaxf(mx, v);
    }
    mask[idx] = (fabsf(mx) > 0.3f) ? 1 : 0;
}

__global__ __launch_bounds__(64) void compact_kernel(const unsigned char* __restrict__ mask,
                                                     int* __restrict__ perm,
                                                     int* __restrict__ Kc) {
    int b = blockIdx.x, lane = threadIdx.x;
    int offs = 0;
    for (int c = 0; c < NVOX / 64; ++c) {
        int i = c * 64 + lane;
        int m = mask[(b << 13) + i];
        unsigned long long bal = __ballot(m != 0);
        int excl = __popcll(bal & ((1ull << lane) - 1ull));
        if (m) perm[(b << 13) + offs + excl] = i;
        offs += __popcll(bal);
    }
    if (lane == 0) Kc[b] = offs;
}

// build normalized data rows (bf16, ld IDP) for ALL batches, one launch
__global__ __launch_bounds__(256) void build_all(const float* __restrict__ input,
                                                 const int* __restrict__ perm,
                                                 const int* __restrict__ Kc,
                                                 u16* __restrict__ normed) {
    int blk = blockIdx.x;             // b*8192 + r
    int b = blk >> 13, r = blk & (NVOX - 1);
    int tid = threadIdx.x;
    u16* out = normed + (size_t)blk * IDP;
    int Kb = Kc[b];
    if (r >= Kb) {
        for (int e = tid; e < IDP; e += 256) out[e] = 0;
        return;
    }
    __shared__ float row[IDP];
    __shared__ float red[256];
    int i = perm[(b << 13) + r];
    int tt = i & 7, wx = (i >> 3) & 31, hy = i >> 8;
    float pos0 = 2.f * hy / 32.f - 1.f;
    float pos1 = 2.f * wx / 32.f - 1.f;
    float pos2 = 2.f * tt / 8.f - 1.f;
    for (int e = tid; e < IDP; e += 256) {
        float v = 0.f;
        if (e < PC) {
            int py = e / 12, px = (e / 3) & 3, cc = e % 3;
            v = input[((size_t)((tt * BATCH + b) * CIN + cc) << 14) +
                      (hy * 4 + py) * WIMG + (wx * 4 + px)];
        } else if (e < ID) {
            int e2 = e - PC;
            int dim = e2 / 129, rem = e2 - dim * 129;
            float pp = (dim == 0) ? pos0 : (dim == 1 ? pos1 : pos2);
            if (rem < 64)       v = sinf(ldexpf(pp, -rem));
            else if (rem < 128) v = cosf(ldexpf(pp, -(rem - 64)));
            else                v = pp;
        }
        row[e] = v;
    }
    __syncthreads();
    float ss = 0.f;
    for (int e = tid; e < ID; e += 256) ss += row[e] * row[e];
    red[tid] = ss; __syncthreads();
    for (int s = 128; s > 0; s >>= 1) { if (tid < s) red[tid] += red[tid + s]; __syncthreads(); }
    float scale = 1.f / fmaxf(sqrtf(red[0]), 1e-5f);
    for (int e = tid; e < IDP; e += 256) out[e] = f2bf(row[e] * scale);
}

__global__ __launch_bounds__(256) void lat_init(const float* __restrict__ latents,
                                                const float* __restrict__ pos_emb,
                                                float* __restrict__ lat) {
    int idx = blockIdx.x * 256 + threadIdx.x;
    if (idx >= BATCH * NL * LD) return;
    int rem = idx & (NL * LD - 1);
    lat[idx] = latents[rem] + pos_emb[rem];
}

__global__ __launch_bounds__(256) void scale_norm_bf(const float* __restrict__ x,
                                                     u16* __restrict__ o,
                                                     const float* __restrict__ g, int gi,
                                                     int cols) {
    int rowi = blockIdx.x, tid = threadIdx.x;
    const float* xr = x + (size_t)rowi * cols;
    u16* orow = o + (size_t)rowi * cols;
    __shared__ float red[256];
    float ss = 0.f;
    for (int c = tid; c < cols; c += 256) { float v = xr[c]; ss += v * v; }
    red[tid] = ss; __syncthreads();
    for (int s = 128; s > 0; s >>= 1) { if (tid < s) red[tid] += red[tid + s]; __syncthreads(); }
    float scale = g[gi] / fmaxf(sqrtf(red[0]), 1e-5f);
    for (int c = tid; c < cols; c += 256) orow[c] = f2bf(xr[c] * scale);
}

__global__ __launch_bounds__(256) void fill_kernel(float* __restrict__ p, long long n, float v) {
    long long idx = (long long)blockIdx.x * 256 + threadIdx.x;
    if (idx < n) p[idx] = v;
}

__global__ __launch_bounds__(256) void conv_bf(const float* __restrict__ src, u16* __restrict__ dst, int n) {
    int idx = blockIdx.x * 256 + threadIdx.x;
    if (idx < n) dst[idx] = f2bf(src[idx]);
}

// batched transpose: fp32 (R x C) -> bf16 (cp(c) x Rp) per job; one launch
// flag 0: cp=c. flag 1: cp=(c/75)*96+c%75. flag 2: cp=(c/600)*768+((c%600)/75)*96+(c%600)%75.
struct TJobs {
    const float* src[11];
    u16* dst[11];
    int R[11], C[11], Rp[11], flag[11];
    int tstart[12];
    int njobs;
};
__global__ __launch_bounds__(256) void transpose_multi(TJobs J) {
    int bx = blockIdx.x;
    int j = 0;
    while (j + 1 < J.njobs && bx >= J.tstart[j + 1]) ++j;
    int lt = bx - J.tstart[j];
    int tilesX = J.Rp[j] >> 5;
    int tx = lt % tilesX, ty = lt / tilesX;
    const float* src = J.src[j];
    u16* dst = J.dst[j];
    int R = J.R[j], C = J.C[j], Rp = J.Rp[j], fl = J.flag[j];
    __shared__ float t[32][33];
    int bx0 = tx * 32, by0 = ty * 32;
    int ttx = threadIdx.x & 31, tty = threadIdx.x >> 5;
#pragma unroll
    for (int p = 0; p < 4; ++p) {
        int r = bx0 + tty + p * 8, c = by0 + ttx;
        t[tty + p * 8][ttx] = (r < R && c < C) ? src[(size_t)r * C + c] : 0.f;
    }
    __syncthreads();
#pragma unroll
    for (int p = 0; p < 4; ++p) {
        int c = by0 + tty + p * 8, r = bx0 + ttx;
        if (c < C && r < Rp) {
            int cp = c;
            if (fl == 1)      cp = (c / 75) * 96 + c % 75;
            else if (fl == 2) { int sec = c / 600, rem = c - sec * 600;
                                cp = sec * 768 + (rem / 75) * 96 + rem % 75; }
            dst[(size_t)cp * Rp + r] = f2bf(t[ttx][tty + p * 8]);
        }
    }
}

// vs_t (bh,DH,NL) from qkvs (512 x QKVLD) V section
__global__ __launch_bounds__(256) void pack_vt_self(const u16* __restrict__ qkvs, u16* __restrict__ vt) {
    int idx = blockIdx.x * 256 + threadIdx.x;
    if (idx >= BATCH * HEADS * DH * NL) return;
    int l = idx & (NL - 1);
    int dd = (idx >> 7) % DH;
    int bh = idx / (DH * NL);
    int b = bh >> 3, h = bh & 7;
    vt[idx] = qkvs[(size_t)(b * NL + l) * QKVLD + 2 * QLD + h * DHP + dd];
}

// masked softmax on bf16 in place (self-attn scores, cols=128)
__global__ __launch_bounds__(256) void softmax_u16(u16* __restrict__ S, int cols,
                                                   const int* __restrict__ Kc, int b0,
                                                   int rows_per_b) {
    int rowi = blockIdx.x, tid = threadIdx.x;
    u16* p = S + (size_t)rowi * cols;
    int lim = Kc ? Kc[b0 + rowi / rows_per_b] : cols;
    __shared__ float red[256];
    if (lim <= 0) { for (int j = tid; j < cols; j += 256) p[j] = 0; return; }
    float v[32];
    int nit = (lim + 255) >> 8;
    float mx = -3.4e38f;
    for (int s = 0; s < nit; ++s) {
        int j = s * 256 + tid;
        float x = (j < lim) ? bf2f(p[j]) : -3.4e38f;
        v[s] = x;
        mx = fmaxf(mx, x);
    }
    red[tid] = mx; __syncthreads();
    for (int s = 128; s > 0; s >>= 1) { if (tid < s) red[tid] = fmaxf(red[tid], red[tid + s]); __syncthreads(); }
    mx = red[0]; __syncthreads();
    float sum = 0.f;
    for (int s = 0; s < nit; ++s) {
        int j = s * 256 + tid;
        float e = (j < lim) ? expf(v[s] - mx) : 0.f;
        v[s] = e; sum += e;
    }
    red[tid] = sum; __syncthreads();
    for (int s = 128; s > 0; s >>= 1) { if (tid < s) red[tid] += red[tid + s]; __syncthreads(); }
    float inv = (red[0] > 0.f) ? 1.f / red[0] : 0.f;
    int nco = (cols + 255) >> 8;
    for (int s = 0; s < nco; ++s) {
        int j = s * 256 + tid;
        if (j < cols) p[j] = f2bf((s < nit && j < lim) ? v[s] * inv : 0.f);
    }
}

// ---------------------------------------------------------------------------
// Flash cross-attention. Q: qg (512 x QLD head-padded). KV: kvn (32768 x KVLD):
// K col = h*96+dd, V col = 768+h*96+dd (dd pads zero). Emits unnormalized
// O-partials (bh,c,128,80) fp32 + (m,l) stats (bh,c,128,2).
#define KS_LD 104
__global__ __launch_bounds__(256) void flash_ctx(
    const u16* __restrict__ qg,    // (512, QLD)
    const u16* __restrict__ kvn,   // (32768, KVLD)
    const int* __restrict__ Kc,
    float* __restrict__ Opart,     // (32,NCH,128,80)
    float* __restrict__ mlb,       // (32,NCH,128,2)
    float scale) {
    int ch = blockIdx.x, bh = blockIdx.y;
    int b = bh >> 3, h = bh & 7;
    int lim = Kc[b];
    int v0 = ch * FCH;
    int nval = min(FCH, lim - v0);
    int tid = threadIdx.x, wv = tid >> 6, lane = tid & 63;
    int fr = lane & 15, fc = lane >> 4;
    float* Op = Opart + ((size_t)bh * NCH + ch) * (128 * 80);
    float* mlp = mlb + ((size_t)bh * NCH + ch) * 256;
    if (nval <= 0) {
        for (int i = tid; i < 128 * 80; i += 256) Op[i] = 0.f;
        for (int i = tid; i < 128; i += 256) { mlp[2 * i] = -3.4e38f; mlp[2 * i + 1] = 0.f; }
        return;
    }
    __shared__ __align__(16) u16 Ks[FKT * KS_LD];   // 13.3 KB
    __shared__ __align__(16) u16 Vt[80 * 72];       // 11.3 KB
    __shared__ __align__(16) u16 Ps[4 * 32 * 72];   // 18 KB
    const u16* kbase = kvn + ((size_t)b * NVOX) * KVLD + h * DHP;
    const u16* vbase = kbase + QLD;
    // Q fragments (wave rows wv*32..wv*32+31)
    short8 qf[2][3];
    const u16* qb = qg + ((size_t)(b * NL) + wv * 32) * QLD + h * DHP;
#pragma unroll
    for (int i = 0; i < 2; ++i)
#pragma unroll
        for (int kk = 0; kk < 3; ++kk)
            qf[i][kk] = *(const short8*)(qb + (size_t)(i * 16 + fr) * QLD + kk * 32 + fc * 8);
    float m_run[2][4], l_run[2][4];
#pragma unroll
    for (int i = 0; i < 2; ++i)
#pragma unroll
        for (int r = 0; r < 4; ++r) { m_run[i][r] = -3.4e38f; l_run[i][r] = 0.f; }
    f32x4 o[2][5] = {};
    u16* Pw = Ps + wv * (32 * 72);
    int ktiles = (nval + FKT - 1) / FKT;
    for (int kt = 0; kt < ktiles; ++kt) {
        int kvox = v0 + kt * FKT;
        // stage K tile: 64 rows x 96 (LDS ld 104)
        for (int t = 0; t < 3; ++t) {
            int idx = t * 256 + tid;                 // 768 chunks of 8 u16
            int row = idx / 12, cc = idx - row * 12;
            short8 v = *(const short8*)(kbase + (size_t)(kvox + row) * KVLD + cc * 8);
            *(short8*)(Ks + row * KS_LD + cc * 8) = v;
        }
        // stage V^T tile: read V rows (vox, 80 dd), transpose into Vt (80 x 72)
        for (int t = 0; t < 3; ++t) {
            int idx = t * 256 + tid;                 // 640 chunks
            if (idx < 640) {
                int row = idx / 10, c8 = idx - row * 10;
                short8 v = *(const short8*)(vbase + (size_t)(kvox + row) * KVLD + c8 * 8);
#pragma unroll
                for (int e = 0; e < 8; ++e)
                    Vt[(c8 * 8 + e) * 72 + row] = (u16)v[e];
            }
        }
        __syncthreads();
        // S = Q K^T  (m=32 rows of this wave, n=64)
        f32x4 sc[2][4] = {};
#pragma unroll
        for (int kk = 0; kk < 3; ++kk) {
            short8 bf[4];
#pragma unroll
            for (int j = 0; j < 4; ++j)
                bf[j] = *(const short8*)(Ks + (j * 16 + fr) * KS_LD + kk * 32 + fc * 8);
#pragma unroll
            for (int i = 0; i < 2; ++i)
#pragma unroll
                for (int j = 0; j < 4; ++j)
                    sc[i][j] = __builtin_amdgcn_mfma_f32_16x16x32_bf16(qf[i][kk], bf[j], sc[i][j], 0, 0, 0);
        }
        // online softmax per row (C-layout: col=fr in frag j, row=fc*4+r in frag i)
        float alpha[2][4];
#pragma unroll
        for (int i = 0; i < 2; ++i) {
#pragma unroll
            for (int r = 0; r < 4; ++r) {
                float mt = -3.4e38f;
#pragma unroll
                for (int j = 0; j < 4; ++j) {
                    int cl = kt * FKT + j * 16 + fr;
                    float s = (cl < nval) ? sc[i][j][r] * scale : -3.4e38f;
                    sc[i][j][r] = s;
                    mt = fmaxf(mt, s);
                }
                for (int sft = 1; sft < 16; sft <<= 1) mt = fmaxf(mt, __shfl_xor(mt, sft, 16));
                float mn = fmaxf(m_run[i][r], mt);
                float al = __expf(m_run[i][r] - mn);
                m_run[i][r] = mn;
                float lt = 0.f;
#pragma unroll
                for (int j = 0; j < 4; ++j) {
                    float p = __expf(sc[i][j][r] - mn);
                    sc[i][j][r] = p;
                    lt += p;
                }
                for (int sft = 1; sft < 16; sft <<= 1) lt += __shfl_xor(lt, sft, 16);
                l_run[i][r] = l_run[i][r] * al + lt;
                alpha[i][r] = al;
            }
        }
        // P -> LDS (per-wave region), rescale O
#pragma unroll
        for (int i = 0; i < 2; ++i)
#pragma unroll
            for (int j = 0; j < 4; ++j)
#pragma unroll
                for (int r = 0; r < 4; ++r)
                    Pw[(i * 16 + fc * 4 + r) * 72 + j * 16 + fr] = f2bf(sc[i][j][r]);
#pragma unroll
        for (int i = 0; i < 2; ++i)
#pragma unroll
            for (int n = 0; n < 5; ++n)
#pragma unroll
                for (int r = 0; r < 4; ++r)
                    o[i][n][r] *= alpha[i][r];
        __syncthreads();
        // O += P @ V
#pragma unroll
        for (int kk = 0; kk < 2; ++kk) {
            short8 pf[2], vf[5];
#pragma unroll
            for (int i = 0; i < 2; ++i)
                pf[i] = *(const short8*)(Pw + (i * 16 + fr) * 72 + kk * 32 + fc * 8);
#pragma unroll
            for (int n = 0; n < 5; ++n)
                vf[n] = *(const short8*)(Vt + (n * 16 + fr) * 72 + kk * 32 + fc * 8);
#pragma unroll
            for (int i = 0; i < 2; ++i)
#pragma unroll
                for (int n = 0; n < 5; ++n)
                    o[i][n] = __builtin_amdgcn_mfma_f32_16x16x32_bf16(pf[i], vf[n], o[i][n], 0, 0, 0);
        }
        __syncthreads();
    }
#pragma unroll
    for (int i = 0; i < 2; ++i) {
#pragma unroll
        for (int n = 0; n < 5; ++n)
#pragma unroll
            for (int r = 0; r < 4; ++r) {
                int row = wv * 32 + i * 16 + fc * 4 + r;
                Op[row * 80 + n * 16 + fr] = o[i][n][r];
            }
        if (fr == 0) {
#pragma unroll
            for (int r = 0; r < 4; ++r) {
                int row = wv * 32 + i * 16 + fc * 4 + r;
                mlp[2 * row] = m_run[i][r];
                mlp[2 * row + 1] = l_run[i][r];
            }
        }
    }
}

// combine flash partials -> attn_bf (512 x INNERP bf16, pad-zeroed)
__global__ __launch_bounds__(128) void combine_ctx(const float* __restrict__ Opart,
                                                   const float* __restrict__ mlb,
                                                   u16* __restrict__ attn_bf) {
    int blk = blockIdx.x;                // bh*128 + row
    int bh = blk >> 7, row = blk & 127;
    int b = bh >> 3, h = bh & 7;
    int tid = threadIdx.x;
    float mc[NCH], lc[NCH];
    float mstar = -3.4e38f;
    for (int c = 0; c < NCH; ++c) {
        const float* mlp = mlb + ((size_t)bh * NCH + c) * 256 + 2 * row;
        mc[c] = mlp[0]; lc[c] = mlp[1];
        mstar = fmaxf(mstar, mc[c]);
    }
    float L = 0.f;
    float wc[NCH];
    for (int c = 0; c < NCH; ++c) {
        float ww = __expf(mc[c] - mstar);
        wc[c] = ww; L += ww * lc[c];
    }
    float invL = (L > 0.f) ? 1.f / L : 0.f;
    if (tid < DH) {
        float s = 0.f;
        for (int c = 0; c < NCH; ++c)
            s += Opart[(((size_t)bh * NCH + c) * 128 + row) * 80 + tid] * wc[c];
        attn_bf[((size_t)(b * 128 + row)) * INNERP + h * DH + tid] = f2bf(s * invL);
    }
    if (h == 7 && tid >= DH && tid < DH + (INNERP - INNER))
        attn_bf[((size_t)(b * 128 + row)) * INNERP + INNER + (tid - DH)] = 0;
}

// ---------------------------------------------------------------------------
// bf16 MFMA GEMM with global_load_lds staging. D = alpha * A @ B^T_layout (+bias, act).
// A: M x K bf16 (lda), M % 128 == 0. B: N x K bf16 (ldb); rows past N must be readable.
// modes: 1 = f32 atomicAdd, 2 = bf16 store, 6 = fused logits->d_out permute atomicAdd.
__global__ __launch_bounds__(256) void gemm_bf16(
    const u16* __restrict__ A, const u16* __restrict__ B, void* __restrict__ Dv,
    const float* __restrict__ alphaPtr, int alphaIdx, float alphaConst,
    int M, int N, int K, int lda, int ldb, int ldd, int nh,
    ll sAo, ll sAi, ll sBo, ll sBi, ll sDo, ll sDi,
    int splitK, int mode, const float* __restrict__ bias, float biasScale, int act) {
    __shared__ __align__(16) u16 As[128 * BK];
    __shared__ __align__(16) u16 Bs[128 * BK];
    const int tid = threadIdx.x;
    int zb = blockIdx.z / splitK, kc = blockIdx.z - zb * splitK;
    int zo = zb / nh, zi = zb - zo * nh;
    const u16* Ab = A + (size_t)zo * sAo + (size_t)zi * sAi;
    const u16* Bb = B + (size_t)zo * sBo + (size_t)zi * sBi;
    const int bm = blockIdx.x * 128, bn = blockIdx.y * 128;
    int nk = K >> 5;
    int per = (nk + splitK - 1) / splitK;
    int k0 = kc * per * BK;
    int k1 = min(K, k0 + per * BK);

    const int wv = tid >> 6, lane = tid & 63;
    const int wm = (wv & 1) << 6, wn = (wv >> 1) << 6;
    const int fr = lane & 15, fc = lane >> 4;
    f32x4 acc[4][4] = {};

    const int lr = lane >> 2, lc = (lane & 3) << 3;
    const u16* ga0 = Ab + (size_t)(bm + wv * 16 + lr) * lda + k0 + lc;
    const u16* ga1 = ga0 + (size_t)64 * lda;
    const u16* gb0 = Bb + (size_t)(bn + wv * 16 + lr) * ldb + k0 + lc;
    const u16* gb1 = gb0 + (size_t)64 * ldb;
    u16* la0 = As + (wv * 16) * BK;
    u16* la1 = As + (wv * 16 + 64) * BK;
    u16* lb0 = Bs + (wv * 16) * BK;
    u16* lb1 = Bs + (wv * 16 + 64) * BK;

    for (int kb = k0; kb < k1; kb += BK) {
        gload_lds16(ga0, la0);
        gload_lds16(ga1, la1);
        gload_lds16(gb0, lb0);
        gload_lds16(gb1, lb1);
        ga0 += BK; ga1 += BK; gb0 += BK; gb1 += BK;
        __syncthreads();
        short8 af[4], bfr[4];
#pragma unroll
        for (int i = 0; i < 4; ++i)
            af[i] = *(const short8*)(As + (wm + i * 16 + fr) * BK + fc * 8);
#pragma unroll
        for (int j = 0; j < 4; ++j)
            bfr[j] = *(const short8*)(Bs + (wn + j * 16 + fr) * BK + fc * 8);
#pragma unroll
        for (int i = 0; i < 4; ++i)
#pragma unroll
            for (int j = 0; j < 4; ++j)
                acc[i][j] = __builtin_amdgcn_mfma_f32_16x16x32_bf16(af[i], bfr[j], acc[i][j], 0, 0, 0);
        __syncthreads();
    }
    float alpha = alphaConst * (alphaPtr ? alphaPtr[alphaIdx] : 1.f);
    if (mode == 6) {
        float* Do = (float*)Dv;
#pragma unroll
        for (int i = 0; i < 4; ++i)
#pragma unroll
            for (int j = 0; j < 4; ++j) {
                int gn = bn + wn + j * 16 + fr;
                if (gn >= N) continue;
                float bv = bias ? bias[gn] * biasScale : 0.f;
                int gm0 = bm + wm + i * 16 + fc * 4;
#pragma unroll
                for (int r = 0; r < 4; ++r) {
                    int gm = gm0 + r;
                    if (gm >= M) continue;
                    int b = gm >> 7, l = gm & 127;
                    int tt = l & 7, nn = l >> 3;
                    atomicAdd(&Do[(((size_t)(tt * BATCH + b)) * 16 + nn) * 64 + gn],
                              acc[i][j][r] * alpha + bv);
                }
            }
        return;
    }
    float* Db = (float*)Dv + (size_t)zo * sDo + (size_t)zi * sDi;
    u16* Du = (u16*)Dv + (size_t)zo * sDo + (size_t)zi * sDi;
#pragma unroll
    for (int i = 0; i < 4; ++i) {
#pragma unroll
        for (int j = 0; j < 4; ++j) {
            int gn = bn + wn + j * 16 + fr;
            if (gn >= N) continue;
            float bv = bias ? bias[gn] * biasScale : 0.f;
            int gm0 = bm + wm + i * 16 + fc * 4;
#pragma unroll
            for (int r = 0; r < 4; ++r) {
                int gm = gm0 + r;
                if (gm >= M) continue;
                float v = acc[i][j][r] * alpha + bv;
                if (act) v = 0.5f * v * (1.f + erff(v * 0.70710678118654752f));
                size_t di = (size_t)gm * ldd + gn;
                if (mode == 2) Du[di] = f2bf(v);
                else           atomicAdd(&Db[di], v);
            }
        }
    }
}

// ---------------------------------------------------------------------------
extern "C" void kernel_launch(void* const* d_in, const int* in_sizes, int n_in,
                              void* d_out, int out_size, void* d_ws, size_t ws_size,
                              hipStream_t stream) {
    const float* input    = (const float*)d_in[0];
    const float* latents  = (const float*)d_in[1];
    const float* pos_emb  = (const float*)d_in[2];
    const float* ca_g     = (const float*)d_in[3];
    const float* ca_ctx_g = (const float*)d_in[4];
    const float* ca_q     = (const float*)d_in[5];
    const float* ca_kv    = (const float*)d_in[6];
    const float* ca_ow    = (const float*)d_in[7];
    const float* ca_ob    = (const float*)d_in[8];
    const float* cf_g     = (const float*)d_in[9];
    const float* cf_w1    = (const float*)d_in[10];
    const float* cf_b1    = (const float*)d_in[11];
    const float* cf_w2    = (const float*)d_in[12];
    const float* cf_b2    = (const float*)d_in[13];
    const float* la_g     = (const float*)d_in[14];
    const float* la_q     = (const float*)d_in[15];
    const float* la_kv    = (const float*)d_in[16];
    const float* la_ow    = (const float*)d_in[17];
    const float* la_ob    = (const float*)d_in[18];
    const float* lf_g     = (const float*)d_in[19];
    const float* lf_w1    = (const float*)d_in[20];
    const float* lf_b1    = (const float*)d_in[21];
    const float* lf_w2    = (const float*)d_in[22];
    const float* lf_b2    = (const float*)d_in[23];
    const float* logits_w = (const float*)d_in[24];
    const float* logits_b = (const float*)d_in[25];
    float* out = (float*)d_out;
    (void)ws_size; (void)n_in; (void)in_sizes; (void)out_size;

    // workspace carve (~177 MB)
    char* w = (char*)d_ws;
    auto alloc = [&](size_t bytes) { void* p = (void*)w; w += (bytes + 255) & ~(size_t)255; return p; };
    int* perm        = (int*)alloc((size_t)BATCH * NVOX * 4);
    int* Kc          = (int*)alloc(64);
    unsigned char* mask = (unsigned char*)alloc((size_t)BATCH * NVOX);
    float* lat       = (float*)alloc((size_t)BATCH * NL * LD * 4);
    u16* latn_bf     = (u16*)alloc((size_t)BATCH * NL * LD * 2);
    u16* qg          = (u16*)alloc((size_t)BATCH * NL * QLD * 2);      // ctx Q, head-padded
    u16* qkvs        = (u16*)alloc((size_t)BATCH * NL * QKVLD * 2);    // self QKV, head-padded
    u16* attn_bf     = (u16*)alloc((size_t)BATCH * NL * INNERP * 2);
    u16* ffb_bf      = (u16*)alloc((size_t)BATCH * NL * FFD * 2);
    u16* vs_t        = (u16*)alloc((size_t)BATCH * HEADS * DH * NL * 2);
    alloc(64 * 1024);  // pad: B over-read slack behind vs_t
    // padded-layout weights (zero-filled once; pad rows never rewritten)
    u16* wqp_t   = (u16*)alloc((size_t)QLD * LD * 2);
    u16* wkv_t   = (u16*)alloc((size_t)KVLD * IDP * 2);
    u16* wlqkv_t = (u16*)alloc((size_t)QKVLD * LD * 2);
    size_t padw_f32 = ((size_t)QLD * LD + (size_t)KVLD * IDP + (size_t)QKVLD * LD) / 2;
    // plain transposed weights
    u16* wow_t   = (u16*)alloc((size_t)LD * INNERP * 2);
    u16* wf1_t   = (u16*)alloc((size_t)FFD * LD * 2);
    u16* wf2_t   = (u16*)alloc((size_t)LD * FFD * 2);
    u16* wlow_t  = (u16*)alloc((size_t)LD * INNERP * 2);
    u16* wlf1_t  = (u16*)alloc((size_t)FFD * LD * 2);
    u16* wlf2_t  = (u16*)alloc((size_t)LD * FFD * 2);
    u16* wlog_t  = (u16*)alloc((size_t)OC * LD * 2);
    u16* normed  = (u16*)alloc((size_t)BATCH * NVOX * IDP * 2);        // 29.4 MB
    u16* E       = (u16*)alloc((size_t)2 * 1024 * 1024);               // self scores
    u16* kvn     = (u16*)alloc((size_t)BATCH * NVOX * KVLD * 2);       // 100.7 MB
    alloc((size_t)64 * 1024);
    float* Opart = (float*)alloc((size_t)32 * NCH * 128 * 80 * 4);     // 21 MB
    float* mlb   = (float*)alloc((size_t)32 * NCH * 128 * 2 * 4);

    const float scaleS = 1.0f / sqrtf((float)DH);
    const int M4 = BATCH * NL;

    auto G = [&](const u16* A, const u16* B, void* D, const float* aP, int aI, float aC,
                 int M, int N, int K, int lda, int ldb, int ldd, int nh, int nb,
                 ll sAo, ll sAi, ll sBo, ll sBi, ll sDo, ll sDi,
                 int splitK, int mode, const float* bias = nullptr, float biasScale = 1.f,
                 int act = 0) {
        dim3 g((M + 127) / 128, (N + 127) / 128, nb * splitK);
        hipLaunchKernelGGL(gemm_bf16, g, dim3(256), 0, stream, A, B, D, aP, aI, aC,
                           M, N, K, lda, ldb, ldd, nh, sAo, sAi, sBo, sBi, sDo, sDi,
                           splitK, mode, bias, biasScale, act);
    };

    hipLaunchKernelGGL(mask_kernel, dim3((BATCH * NVOX + 255) / 256), dim3(256), 0, stream, input, mask);
    hipLaunchKernelGGL(compact_kernel, dim3(BATCH), dim3(64), 0, stream, mask, perm, Kc);
    hipLaunchKernelGGL(lat_init, dim3((BATCH * NL * LD + 255) / 256), dim3(256), 0, stream, latents, pos_emb, lat);
    // zero the padded weight buffers once (pad rows stay zero across layers)
    hipLaunchKernelGGL(fill_kernel, dim3(((ll)padw_f32 + 255) / 256), dim3(256), 0, stream,
                       (float*)wqp_t, (ll)padw_f32, 0.f);
    hipLaunchKernelGGL(build_all, dim3(BATCH * NVOX), dim3(256), 0, stream, input, perm, Kc, normed);

    for (int d = 0; d < DEPTH; ++d) {
        // ---- all weight transposes for this layer in ONE launch ----
        TJobs J;
        int t = 0;
        auto addJob = [&](const float* s, u16* ds, int R, int C, int Rp, int fl) {
            J.src[t] = s; J.dst[t] = ds; J.R[t] = R; J.C[t] = C; J.Rp[t] = Rp; J.flag[t] = fl;
            J.tstart[t] = (t == 0) ? 0 : J.tstart[t - 1] +
                          (J.Rp[t - 1] >> 5) * ((J.C[t - 1] + 31) >> 5);
            ++t;
        };
        addJob(ca_q  + (size_t)d * LD * INNER,     wqp_t,   LD,  INNER,     LD,     1);
        addJob(ca_kv + (size_t)d * ID * 2 * INNER, wkv_t,   ID,  2 * INNER, IDP,    2);
        addJob(ca_ow + (size_t)d * INNER * LD,     wow_t,   INNER, LD,      INNERP, 0);
        addJob(cf_w1 + (size_t)d * LD * FFD,       wf1_t,   LD,  FFD,       LD,     0);
        addJob(cf_w2 + (size_t)d * FFD * LD,       wf2_t,   FFD, LD,        FFD,    0);
        addJob(la_q  + (size_t)d * LD * INNER,     wlqkv_t, LD,  INNER,     LD,     1);
        addJob(la_kv + (size_t)d * LD * 2 * INNER, wlqkv_t + (size_t)QLD * LD, LD, 2 * INNER, LD, 2);
        addJob(la_ow + (size_t)d * INNER * LD,     wlow_t,  INNER, LD,      INNERP, 0);
        addJob(lf_w1 + (size_t)d * LD * FFD,       wlf1_t,  LD,  FFD,       LD,     0);
        addJob(lf_w2 + (size_t)d * FFD * LD,       wlf2_t,  FFD, LD,        FFD,    0);
        if (d == 0) addJob(logits_w,               wlog_t,  LD,  OC,        LD,     0);
        J.njobs = t;
        J.tstart[t] = J.tstart[t - 1] + (J.Rp[t - 1] >> 5) * ((J.C[t - 1] + 31) >> 5);
        hipLaunchKernelGGL(transpose_multi, dim3(J.tstart[t]), dim3(256), 0, stream, J);

        // ---- cross attention (flash) ----
        hipLaunchKernelGGL(scale_norm_bf, dim3(M4), dim3(256), 0, stream, lat, latn_bf, ca_g, d, LD);
        G(latn_bf, wqp_t, qg, nullptr, 0, 1.f, M4, QLD, LD, LD, LD, QLD, 1, 1,
          0, 0, 0, 0, 0, 0, 1, 2);
        // KV projection all batches: 32768 x 1536, coalesced head-padded store
        G(normed, wkv_t, kvn, ca_ctx_g, d, 1.f, BATCH * NVOX, KVLD, IDP, IDP, IDP, KVLD, 1, 1,
          0, 0, 0, 0, 0, 0, 1, 2);
        hipLaunchKernelGGL(flash_ctx, dim3(NCH, 32), dim3(256), 0, stream,
                           qg, kvn, Kc, Opart, mlb, scaleS);
        hipLaunchKernelGGL(combine_ctx, dim3(32 * 128), dim3(128), 0, stream, Opart, mlb, attn_bf);
        G(attn_bf, wow_t, lat, nullptr, 0, 1.f, M4, LD, INNERP, INNERP, INNERP, LD, 1, 1,
          0, 0, 0, 0, 0, 0, 2, 1, ca_ob + (size_t)d * LD, 0.5f);

        // ---- FF (cf) ----
        hipLaunchKernelGGL(scale_norm_bf, dim3(M4), dim3(256), 0, stream, lat, latn_bf, cf_g, d, LD);
        G(latn_bf, wf1_t, ffb_bf, nullptr, 0, 1.f, M4, FFD, LD, LD, LD, FFD, 1, 1,
          0, 0, 0, 0, 0, 0, 1, 2, cf_b1 + (size_t)d * FFD, 1.f, 1);
        G(ffb_bf, wf2_t, lat, nullptr, 0, 1.f, M4, LD, FFD, FFD, FFD, LD, 1, 1,
          0, 0, 0, 0, 0, 0, 8, 1, cf_b2 + (size_t)d * LD, 0.125f);

        // ---- latent self attention ----
        hipLaunchKernelGGL(scale_norm_bf, dim3(M4), dim3(256), 0, stream, lat, latn_bf, la_g, d, LD);
        G(latn_bf, wlqkv_t, qkvs, nullptr, 0, 1.f, M4, QKVLD, LD, LD, LD, QKVLD, 1, 1,
          0, 0, 0, 0, 0, 0, 1, 2);
        hipLaunchKernelGGL(pack_vt_self, dim3((BATCH * HEADS * DH * NL + 255) / 256), dim3(256), 0, stream,
                           qkvs, vs_t);
        // S_self: A=Q section, B=K section, read in place via (b,h) strides
        G(qkvs, qkvs + QLD, E, nullptr, 0, scaleS, NL, NL, DHP, QKVLD, QKVLD, NL, 8, 32,
          (ll)NL * QKVLD, (ll)DHP, (ll)NL * QKVLD, (ll)DHP,
          (ll)HEADS * NL * NL, (ll)NL * NL, 1, 2);
        hipLaunchKernelGGL(softmax_u16, dim3(BATCH * HEADS * NL), dim3(256), 0, stream,
                           E, NL, (const int*)nullptr, 0, HEADS * NL);
        G(E, vs_t, attn_bf, nullptr, 0, 1.f, NL, DH, NL, NL, NL, INNERP, 8, 32,
          (ll)HEADS * NL * NL, (ll)NL * NL, (ll)HEADS * DH * NL, (ll)DH * NL,
          (ll)NL * INNERP, (ll)DH, 1, 2);
        G(attn_bf, wlow_t, lat, nullptr, 0, 1.f, M4, LD, INNERP, INNERP, INNERP, LD, 1, 1,
          0, 0, 0, 0, 0, 0, 2, 1, la_ob + (size_t)d * LD, 0.5f);

        // ---- FF (lf) ----
        hipLaunchKernelGGL(scale_norm_bf, dim3(M4), dim3(256), 0, stream, lat, latn_bf, lf_g, d, LD);
        G(latn_bf, wlf1_t, ffb_bf, nullptr, 0, 1.f, M4, FFD, LD, LD, LD, FFD, 1, 1,
          0, 0, 0, 0, 0, 0, 1, 2, lf_b1 + (size_t)d * FFD, 1.f, 1);
        G(ffb_bf, wlf2_t, lat, nullptr, 0, 1.f, M4, LD, FFD, FFD, FFD, LD, 1, 1,
          0, 0, 0, 0, 0, 0, 8, 1, lf_b2 + (size_t)d * LD, 0.125f);
    }

    // logits fused with output permute
    hipLaunchKernelGGL(conv_bf, dim3((M4 * LD + 255) / 256), dim3(256), 0, stream, lat, latn_bf, M4 * LD);
    hipLaunchKernelGGL(fill_kernel, dim3((TBINS * BATCH * 16 * OC + 255) / 256), dim3(256), 0, stream,
                       out, (ll)TBINS * BATCH * 16 * OC, 0.f);
    G(latn_bf, wlog_t, out, nullptr, 0, 1.f, M4, OC, LD, LD, LD, 0, 1, 1,
      0, 0, 0, 0, 0, 0, 4, 6, logits_b, 0.25f);
}